// Round 8
// baseline (600.571 us; speedup 1.0000x reference)
//
#include <hip/hip_runtime.h>
#include <math.h>

#define SS 256
#define BB 4
#define HH 256
#define LE 2994
#define LEB (LE*BB)
#define SCALE 0.08838834764831845f  // 1/sqrt(128)

typedef __attribute__((ext_vector_type(8))) short bf16x8;
typedef __attribute__((ext_vector_type(4))) float f32x4;

__device__ inline ushort f2b(float f) {   // fp32 -> bf16 RNE
    unsigned u = __float_as_uint(f);
    u += 0x7FFFu + ((u >> 16) & 1u);
    return (ushort)(u >> 16);
}

__device__ inline float qred(float x) {   // sum across 16 lanes of a quarter-wave
    x += __shfl_xor(x, 1); x += __shfl_xor(x, 2);
    x += __shfl_xor(x, 4); x += __shfl_xor(x, 8);
    return x;
}

// ---------------- init ----------------

__global__ void k_init(float* __restrict__ out, float* __restrict__ bnsums,
                       int* __restrict__ grp, int* __restrict__ idxt) {
    int bid = blockIdx.x, t = threadIdx.x;
    if (bid == 0) {
        if (t == 0) out[0] = 0.f;
        bnsums[t] = 0.f; bnsums[256 + t] = 0.f;
        return;
    }
    int e = (bid - 1) * 256 + t;
    if (e >= LE) return;
    int g, pos;
    if (e < 78) {
        g = (int)((1.0f + sqrtf(8.0f * (float)e + 1.0f)) * 0.5f);
        while (g * (g - 1) / 2 > e) g--;
        while ((g + 1) * g / 2 <= e) g++;
        pos = e - g * (g - 1) / 2;
        idxt[e] = pos;
    } else {
        int r = e - 78;
        g = 13 + r / 12;
        pos = r % 12;
        idxt[e] = g - 12 + pos;
    }
    grp[e] = g;
}

// ---------------- weight pre-pack ----------------

#define NPACK 14
#define TOTFRAG 2816
struct PackArgs { const float* src[NPACK]; int fs[NPACK + 1]; };

__global__ __launch_bounds__(256) void k_prep(PackArgs pa, ushort* __restrict__ dst) {
    int wid = (blockIdx.x * 256 + threadIdx.x) >> 6;
    int lane = threadIdx.x & 63;
    if (wid >= TOTFRAG) return;
    int i = 0;
    while (pa.fs[i + 1] <= wid) i++;
    int f = wid - pa.fs[i];
    int tn = f >> 3, tk = f & 7;
    int q = lane >> 4, p = lane & 15;
    const float* s = pa.src[i] + (size_t)(tn * 16 + p) * 256 + tk * 32 + q * 8;
    float4 a0 = *(const float4*)s, a1 = *(const float4*)(s + 4);
    uint4 o = make_uint4(f2b(a0.x) | ((unsigned)f2b(a0.y) << 16),
                         f2b(a0.z) | ((unsigned)f2b(a0.w) << 16),
                         f2b(a1.x) | ((unsigned)f2b(a1.y) << 16),
                         f2b(a1.z) | ((unsigned)f2b(a1.w) << 16));
    *(uint4*)&dst[(size_t)wid * 512 + lane * 8] = o;
}

// ---------------- unified bf16 GEMM with packed W, K=256 ----------------
// Block tile 64 rows x 256 cols, 4 waves. grid (N/256, ceil(M/64)).
// mode 0: C = A@W^T + bias (+relu)
// mode 1: C = LN(res + A@W^T + bias)                 (gridDim.x==1, N=256)
// mode 2: C = LN2(LN(res + A@W^T + bias))            (gridDim.x==1, N=256)
// mode 3: node QKV: N=768; cols<512 -> C (stride 768), cols>=512 -> Vt[z][dh][s]
// mode 4: Q-proj + edge 2-key cross-attn -> C        (gridDim.x==1, N=256)
// mode 5: mode 2 + edge CE, no C store               (gridDim.x==1, N=256)

__global__ __launch_bounds__(256) void k_gemm_w(
    const float* __restrict__ A, const ushort* __restrict__ Wp,
    const float* __restrict__ bias, const float* __restrict__ res,
    const float* __restrict__ g1, const float* __restrict__ b1,
    const float* __restrict__ g2, const float* __restrict__ b2,
    float* __restrict__ C, float* __restrict__ Vt,
    const float* __restrict__ KV, const int* __restrict__ grp,
    const int* __restrict__ ydata,
    const float* __restrict__ cw0, const float* __restrict__ cb0,
    const float* __restrict__ cw1, const float* __restrict__ cb1,
    float* __restrict__ lossOut, float invM,
    int M, int N, int mode, int relu)
{
    __shared__ ushort As[32 * 512];   // 32 KB
    int tid = threadIdx.x;
    int w = tid >> 6, lane = tid & 63;
    int q = lane >> 4, p = lane & 15;
    int m0 = blockIdx.y * 64, n0 = blockIdx.x * 256;

    // ---- stage A once: fp32 -> bf16 fragment layout ----
    {
        int r = tid >> 2;
        int cbase = (tid & 3) * 64;
        int gm = m0 + r;
        const float* Ar = A + (size_t)gm * 256 + cbase;
        bool ok = gm < M;
        #pragma unroll
        for (int j = 0; j < 8; j++) {
            int c = cbase + j * 8;
            float4 a0, a1;
            if (ok) { a0 = *(const float4*)(Ar + j * 8); a1 = *(const float4*)(Ar + j * 8 + 4); }
            else { a0 = make_float4(0.f, 0.f, 0.f, 0.f); a1 = a0; }
            uint4 o = make_uint4(f2b(a0.x) | ((unsigned)f2b(a0.y) << 16),
                                 f2b(a0.z) | ((unsigned)f2b(a0.w) << 16),
                                 f2b(a1.x) | ((unsigned)f2b(a1.y) << 16),
                                 f2b(a1.z) | ((unsigned)f2b(a1.w) << 16));
            int frag = (r >> 4) * 8 + (c >> 5);
            int fl = ((c >> 3) & 3) * 16 + (r & 15);
            *(uint4*)&As[frag * 512 + fl * 8] = o;
        }
    }
    __syncthreads();

    f32x4 acc[4][4];
    #pragma unroll
    for (int i = 0; i < 4; i++)
        #pragma unroll
        for (int j = 0; j < 4; j++) acc[i][j] = (f32x4){0.f, 0.f, 0.f, 0.f};

    int nw = n0 + w * 64;
    const ushort* Wb = Wp + (size_t)(nw >> 4) * 4096;

    #pragma unroll
    for (int kt = 0; kt < 8; kt++) {
        bf16x8 afr[4], wfr[4];
        #pragma unroll
        for (int mt = 0; mt < 4; mt++)
            afr[mt] = *(const bf16x8*)&As[(mt * 8 + kt) * 512 + lane * 8];
        #pragma unroll
        for (int nt = 0; nt < 4; nt++)
            wfr[nt] = *(const bf16x8*)&Wb[(size_t)(nt * 8 + kt) * 512 + lane * 8];
        #pragma unroll
        for (int mt = 0; mt < 4; mt++)
            #pragma unroll
            for (int nt = 0; nt < 4; nt++)
                acc[mt][nt] = __builtin_amdgcn_mfma_f32_16x16x32_bf16(afr[mt], wfr[nt], acc[mt][nt], 0, 0, 0);
    }

    if (mode == 0 || mode == 3) {
        float bi[4]; int col[4];
        #pragma unroll
        for (int nt = 0; nt < 4; nt++) { col[nt] = nw + nt * 16 + p; bi[nt] = bias[col[nt]]; }
        #pragma unroll
        for (int mt = 0; mt < 4; mt++)
            #pragma unroll
            for (int reg = 0; reg < 4; reg++) {
                int grow = m0 + mt * 16 + q * 4 + reg;
                if (grow >= M) continue;
                #pragma unroll
                for (int nt = 0; nt < 4; nt++) {
                    float v = acc[mt][nt][reg] + bi[nt];
                    if (relu) v = fmaxf(v, 0.f);
                    if (mode == 3) {
                        if (col[nt] < 512) {
                            C[(size_t)grow * 768 + col[nt]] = v;
                        } else {
                            int hh = (col[nt] - 512) >> 7, dh = (col[nt] - 512) & 127;
                            int zz = (grow & 3) * 2 + hh;
                            Vt[(size_t)zz * 32768 + (size_t)dh * 256 + (grow >> 2)] = v;
                        }
                    } else {
                        C[(size_t)grow * N + col[nt]] = v;
                    }
                }
            }
        return;
    }

    if (mode == 4) {
        // edge 2-key cross attention fused into Q projection.
        // wave w: head h = w>>1, within-head dim base dbase = (w&1)*64.
        int col[4]; float bi[4];
        #pragma unroll
        for (int nt = 0; nt < 4; nt++) { col[nt] = w * 64 + nt * 16 + p; bi[nt] = bias[col[nt]]; }
        #pragma unroll
        for (int mt = 0; mt < 4; mt++)
            #pragma unroll
            for (int reg = 0; reg < 4; reg++)
                #pragma unroll
                for (int nt = 0; nt < 4; nt++)
                    acc[mt][nt][reg] += bi[nt];
        int h = w >> 1, dbase = (w & 1) * 64;
        float* red = (float*)As;   // [0..511] partials, [512..767] softmax weights
        __syncthreads();
        #pragma unroll
        for (int mt = 0; mt < 4; mt++)
            #pragma unroll
            for (int reg = 0; reg < 4; reg++) {
                int lr = mt * 16 + q * 4 + reg;
                int grow = m0 + lr;
                bool ok = grow < M;
                int b = grow & 3;
                int g = ok ? grp[grow >> 2] : 0;
                const float* K0 = KV + (size_t)b * 512 + h * 128 + dbase;
                const float* K1 = KV + ((size_t)(g + 1) * 4 + b) * 512 + h * 128 + dbase;
                float s0 = 0.f, s1 = 0.f;
                #pragma unroll
                for (int nt = 0; nt < 4; nt++) {
                    int d = nt * 16 + p;
                    float qv = acc[mt][nt][reg];
                    s0 += qv * K0[d]; s1 += qv * K1[d];
                }
                s0 = qred(s0); s1 = qred(s1);
                if (p == 0) { red[(w * 64 + lr) * 2 + 0] = s0; red[(w * 64 + lr) * 2 + 1] = s1; }
            }
        __syncthreads();
        if (tid < 128) {
            int hh = tid >> 6, lr = tid & 63;
            float p0 = (red[((2 * hh) * 64 + lr) * 2 + 0] + red[((2 * hh + 1) * 64 + lr) * 2 + 0]) * SCALE;
            float p1 = (red[((2 * hh) * 64 + lr) * 2 + 1] + red[((2 * hh + 1) * 64 + lr) * 2 + 1]) * SCALE;
            float mx = fmaxf(p0, p1);
            float e0 = __expf(p0 - mx), e1 = __expf(p1 - mx);
            float inv = 1.f / (e0 + e1);
            red[512 + (hh * 64 + lr) * 2 + 0] = e0 * inv;
            red[512 + (hh * 64 + lr) * 2 + 1] = e1 * inv;
        }
        __syncthreads();
        #pragma unroll
        for (int mt = 0; mt < 4; mt++)
            #pragma unroll
            for (int reg = 0; reg < 4; reg++) {
                int lr = mt * 16 + q * 4 + reg;
                int grow = m0 + lr;
                if (grow >= M) continue;
                int b = grow & 3;
                int g = grp[grow >> 2];
                float e0 = red[512 + (h * 64 + lr) * 2 + 0];
                float e1 = red[512 + (h * 64 + lr) * 2 + 1];
                const float* V0 = KV + (size_t)b * 512 + 256 + h * 128 + dbase;
                const float* V1 = KV + ((size_t)(g + 1) * 4 + b) * 512 + 256 + h * 128 + dbase;
                #pragma unroll
                for (int nt = 0; nt < 4; nt++) {
                    int d = nt * 16 + p;
                    C[(size_t)grow * 256 + col[nt]] = e0 * V0[d] + e1 * V1[d];
                }
            }
        return;
    }

    // modes 1/2/5: residual + LayerNorm (gridDim.x==1, cols = w*64+nt*16+p)
    float bi[4], gg[4], bb[4]; int col[4];
    #pragma unroll
    for (int nt = 0; nt < 4; nt++) {
        col[nt] = w * 64 + nt * 16 + p;
        bi[nt] = bias[col[nt]]; gg[nt] = g1[col[nt]]; bb[nt] = b1[col[nt]];
    }
    #pragma unroll
    for (int mt = 0; mt < 4; mt++)
        #pragma unroll
        for (int reg = 0; reg < 4; reg++) {
            int grow = m0 + mt * 16 + q * 4 + reg;
            bool ok = grow < M;
            #pragma unroll
            for (int nt = 0; nt < 4; nt++)
                acc[mt][nt][reg] += bi[nt] + (ok ? res[(size_t)grow * 256 + col[nt]] : 0.f);
        }
    float* red = (float*)As;
    __syncthreads();
    int passes = (mode >= 2) ? 2 : 1;
    for (int pass = 0; pass < passes; pass++) {
        #pragma unroll
        for (int mt = 0; mt < 4; mt++)
            #pragma unroll
            for (int reg = 0; reg < 4; reg++) {
                float s = acc[mt][0][reg] + acc[mt][1][reg] + acc[mt][2][reg] + acc[mt][3][reg];
                s = qred(s);
                if (p == 0) red[w * 64 + mt * 16 + q * 4 + reg] = s;
            }
        __syncthreads();
        if (tid < 64) red[256 + tid] = (red[tid] + red[64 + tid] + red[128 + tid] + red[192 + tid]) * (1.f / 256.f);
        __syncthreads();
        #pragma unroll
        for (int mt = 0; mt < 4; mt++)
            #pragma unroll
            for (int reg = 0; reg < 4; reg++) {
                int lr = mt * 16 + q * 4 + reg;
                float mean = red[256 + lr];
                float sq = 0.f;
                #pragma unroll
                for (int nt = 0; nt < 4; nt++) {
                    acc[mt][nt][reg] -= mean;
                    sq += acc[mt][nt][reg] * acc[mt][nt][reg];
                }
                sq = qred(sq);
                if (p == 0) red[w * 64 + lr] = sq;
            }
        __syncthreads();
        if (tid < 64) red[256 + tid] = rsqrtf((red[tid] + red[64 + tid] + red[128 + tid] + red[192 + tid]) * (1.f / 256.f) + 1e-5f);
        __syncthreads();
        #pragma unroll
        for (int mt = 0; mt < 4; mt++)
            #pragma unroll
            for (int reg = 0; reg < 4; reg++) {
                float rstd = red[256 + mt * 16 + q * 4 + reg];
                #pragma unroll
                for (int nt = 0; nt < 4; nt++)
                    acc[mt][nt][reg] = acc[mt][nt][reg] * rstd * gg[nt] + bb[nt];
            }
        if (pass == 0 && passes == 2) {
            #pragma unroll
            for (int nt = 0; nt < 4; nt++) { gg[nt] = g2[col[nt]]; bb[nt] = b2[col[nt]]; }
            __syncthreads();
        }
    }

    if (mode == 5) {
        // edge CE epilogue: 9 classes (5 + 4), one loss atomic per block. No C store.
        __syncthreads();
        #pragma unroll
        for (int c = 0; c < 9; c++) {
            const float* wc = (c < 5) ? (cw0 + (size_t)c * 256) : (cw1 + (size_t)(c - 5) * 256);
            float wv[4];
            #pragma unroll
            for (int nt = 0; nt < 4; nt++) wv[nt] = wc[col[nt]];
            #pragma unroll
            for (int mt = 0; mt < 4; mt++)
                #pragma unroll
                for (int reg = 0; reg < 4; reg++) {
                    float s = acc[mt][0][reg] * wv[0] + acc[mt][1][reg] * wv[1]
                            + acc[mt][2][reg] * wv[2] + acc[mt][3][reg] * wv[3];
                    s = qred(s);
                    if (p == 0) red[(c * 4 + w) * 64 + mt * 16 + q * 4 + reg] = s;
                }
        }
        __syncthreads();
        if (tid < 64) {
            float local = 0.f;
            int grow = m0 + tid;
            if (grow < M) {
                float lg[9];
                #pragma unroll
                for (int c = 0; c < 9; c++)
                    lg[c] = red[(c * 4 + 0) * 64 + tid] + red[(c * 4 + 1) * 64 + tid]
                          + red[(c * 4 + 2) * 64 + tid] + red[(c * 4 + 3) * 64 + tid]
                          + ((c < 5) ? cb0[c] : cb1[c - 5]);
                int y0 = ydata[(size_t)grow * 2 + 0], y1 = ydata[(size_t)grow * 2 + 1];
                float mA = -1e30f, mB = -1e30f;
                for (int c = 0; c < 5; c++) mA = fmaxf(mA, lg[c]);
                for (int c = 5; c < 9; c++) mB = fmaxf(mB, lg[c]);
                float sA = 0.f, sB = 0.f;
                for (int c = 0; c < 5; c++) sA += __expf(lg[c] - mA);
                for (int c = 5; c < 9; c++) sB += __expf(lg[c] - mB);
                local = (mA + logf(sA) - lg[y0]) + (mB + logf(sB) - lg[5 + y1]);
            }
            for (int o = 32; o; o >>= 1) local += __shfl_down(local, o);
            if (tid == 0) atomicAdd(lossOut, local * invM);
        }
        return;
    }

    #pragma unroll
    for (int mt = 0; mt < 4; mt++)
        #pragma unroll
        for (int reg = 0; reg < 4; reg++) {
            int grow = m0 + mt * 16 + q * 4 + reg;
            if (grow >= M) continue;
            #pragma unroll
            for (int nt = 0; nt < 4; nt++)
                C[(size_t)grow * 256 + col[nt]] = acc[mt][nt][reg];
        }
}

// ---------------- fused QK^T + scale + causal mask + softmax -> bf16 P ----------------

__global__ __launch_bounds__(256) void k_attn_qks(
    const float* __restrict__ qkv, ushort* __restrict__ P)
{
    __shared__ ushort Qs[64 * 32];
    __shared__ ushort Ks[256 * 32];
    int tid = threadIdx.x;
    int wave = tid >> 6, lane = tid & 63;
    int q = lane >> 4, p = lane & 15;
    int m0 = blockIdx.x * 64;
    int z = blockIdx.y, b = z >> 1, h = z & 1;
    size_t qoff = (size_t)b * 768 + h * 128;

    f32x4 acc[16];
    #pragma unroll
    for (int i = 0; i < 16; i++) acc[i] = (f32x4){0.f, 0.f, 0.f, 0.f};

    int sra = tid >> 2, sca = (tid & 3) << 3;
    const float* Arow = qkv + (size_t)(m0 + sra) * 3072 + qoff + sca;
    const float* Wrow = qkv + (size_t)tid * 3072 + qoff + 256;
    ushort* asd = &Qs[sra * 32 + sca];
    ushort* wsd = &Ks[tid * 32];

    for (int k0 = 0; k0 < 128; k0 += 32) {
        float4 a0 = *(const float4*)(Arow + k0);
        float4 a1 = *(const float4*)(Arow + k0 + 4);
        float av[8] = {a0.x, a0.y, a0.z, a0.w, a1.x, a1.y, a1.z, a1.w};
        float wv[32];
        #pragma unroll
        for (int i = 0; i < 8; i++) {
            float4 w4 = *(const float4*)(Wrow + k0 + i * 4);
            wv[i*4+0] = w4.x; wv[i*4+1] = w4.y; wv[i*4+2] = w4.z; wv[i*4+3] = w4.w;
        }
        unsigned au[4], wu[16];
        #pragma unroll
        for (int i = 0; i < 4; i++) au[i] = (unsigned)f2b(av[2*i]) | ((unsigned)f2b(av[2*i+1]) << 16);
        #pragma unroll
        for (int i = 0; i < 16; i++) wu[i] = (unsigned)f2b(wv[2*i]) | ((unsigned)f2b(wv[2*i+1]) << 16);
        __syncthreads();
        ((uint4*)asd)[0] = make_uint4(au[0], au[1], au[2], au[3]);
        ((uint4*)wsd)[0] = make_uint4(wu[0], wu[1], wu[2], wu[3]);
        ((uint4*)(wsd + 8))[0] = make_uint4(wu[4], wu[5], wu[6], wu[7]);
        ((uint4*)(wsd + 16))[0] = make_uint4(wu[8], wu[9], wu[10], wu[11]);
        ((uint4*)(wsd + 24))[0] = make_uint4(wu[12], wu[13], wu[14], wu[15]);
        __syncthreads();

        bf16x8 af = *(const bf16x8*)&Qs[(wave * 16 + p) * 32 + q * 8];
        #pragma unroll
        for (int nt = 0; nt < 16; nt++) {
            bf16x8 bf = *(const bf16x8*)&Ks[(nt * 16 + p) * 32 + q * 8];
            acc[nt] = __builtin_amdgcn_mfma_f32_16x16x32_bf16(af, bf, acc[nt], 0, 0, 0);
        }
    }

    ushort* Pz = P + (size_t)z * 65536;
    #pragma unroll
    for (int reg = 0; reg < 4; reg++) {
        int row = m0 + wave * 16 + q * 4 + reg;
        float v[16]; float mx = -1e30f;
        #pragma unroll
        for (int nt = 0; nt < 16; nt++) {
            int colk = nt * 16 + p;
            float val = (colk <= row) ? acc[nt][reg] * SCALE : -1e30f;
            v[nt] = val; mx = fmaxf(mx, val);
        }
        mx = fmaxf(mx, __shfl_xor(mx, 1)); mx = fmaxf(mx, __shfl_xor(mx, 2));
        mx = fmaxf(mx, __shfl_xor(mx, 4)); mx = fmaxf(mx, __shfl_xor(mx, 8));
        float s = 0.f;
        #pragma unroll
        for (int nt = 0; nt < 16; nt++) {
            int colk = nt * 16 + p;
            float e = (colk <= row) ? __expf(v[nt] - mx) : 0.f;
            v[nt] = e; s += e;
        }
        s += __shfl_xor(s, 1); s += __shfl_xor(s, 2); s += __shfl_xor(s, 4); s += __shfl_xor(s, 8);
        float inv = 1.f / s;
        #pragma unroll
        for (int nt = 0; nt < 16; nt++)
            Pz[(size_t)row * 256 + nt * 16 + p] = f2b(v[nt] * inv);
    }
}

// ---------------- PV: O = P @ V ----------------

__global__ __launch_bounds__(256) void k_attn_pvt(
    const ushort* __restrict__ P, const float* __restrict__ Vt,
    float* __restrict__ out)
{
    __shared__ ushort As[64 * 32];
    __shared__ ushort Bs[128 * 32];
    int tid = threadIdx.x;
    int wave = tid >> 6, lane = tid & 63;
    int q = lane >> 4, p = lane & 15;
    int m0 = blockIdx.x * 64;
    int z = blockIdx.y, b = z >> 1, h = z & 1;

    f32x4 acc[8];
    #pragma unroll
    for (int i = 0; i < 8; i++) acc[i] = (f32x4){0.f, 0.f, 0.f, 0.f};

    int sra = tid >> 2, sca = (tid & 3) << 3;
    const ushort* Prow = P + (size_t)z * 65536 + (size_t)(m0 + sra) * 256 + sca;
    int srb = tid >> 1, scb = (tid & 1) << 4;
    const float* Vrow = Vt + (size_t)z * 32768 + (size_t)srb * 256 + scb;
    ushort* asd = &As[sra * 32 + sca];
    ushort* wsd = &Bs[srb * 32 + scb];

    for (int k0 = 0; k0 < 256; k0 += 32) {
        uint4 pa = *(const uint4*)(Prow + k0);
        float wv[16];
        #pragma unroll
        for (int i = 0; i < 4; i++) {
            float4 w4 = *(const float4*)(Vrow + k0 + i * 4);
            wv[i*4+0] = w4.x; wv[i*4+1] = w4.y; wv[i*4+2] = w4.z; wv[i*4+3] = w4.w;
        }
        unsigned wu[8];
        #pragma unroll
        for (int i = 0; i < 8; i++) wu[i] = (unsigned)f2b(wv[2*i]) | ((unsigned)f2b(wv[2*i+1]) << 16);
        __syncthreads();
        ((uint4*)asd)[0] = pa;
        ((uint4*)wsd)[0] = make_uint4(wu[0], wu[1], wu[2], wu[3]);
        ((uint4*)(wsd + 8))[0] = make_uint4(wu[4], wu[5], wu[6], wu[7]);
        __syncthreads();

        bf16x8 af = *(const bf16x8*)&As[(wave * 16 + p) * 32 + q * 8];
        #pragma unroll
        for (int nt = 0; nt < 8; nt++) {
            bf16x8 bf = *(const bf16x8*)&Bs[(nt * 16 + p) * 32 + q * 8];
            acc[nt] = __builtin_amdgcn_mfma_f32_16x16x32_bf16(af, bf, acc[nt], 0, 0, 0);
        }
    }

    #pragma unroll
    for (int reg = 0; reg < 4; reg++) {
        int s = m0 + wave * 16 + q * 4 + reg;
        #pragma unroll
        for (int nt = 0; nt < 8; nt++) {
            int dh = nt * 16 + p;
            out[(size_t)s * 1024 + (size_t)b * 256 + h * 128 + dh] = acc[nt][reg];
        }
    }
}

// ---------------- generic fp32 GEMM (input projection K=54 only) ----------------

__global__ __launch_bounds__(256) void k_gemm(
    const float* __restrict__ A, const float* __restrict__ W,
    const float* __restrict__ bias, float* __restrict__ C,
    int M, int N, int K, int relu)
{
    __shared__ __align__(16) float As[16][68];
    __shared__ __align__(16) float Ws[16][68];
    int tx = threadIdx.x, ty = threadIdx.y;
    int tid = ty * 16 + tx;
    int m0 = blockIdx.y * 64, n0 = blockIdx.x * 64;
    float acc[4][4] = {{0.f}};
    int r  = tid >> 2;
    int kk = (tid & 3) << 2;
    for (int k0 = 0; k0 < K; k0 += 16) {
        float4 av = make_float4(0.f, 0.f, 0.f, 0.f);
        float4 wv = make_float4(0.f, 0.f, 0.f, 0.f);
        int gm = m0 + r, gk = k0 + kk;
        if (gm < M) {
            float tv[4];
            for (int i = 0; i < 4; i++) tv[i] = (gk + i < K) ? A[(size_t)gm * K + gk + i] : 0.f;
            av = make_float4(tv[0], tv[1], tv[2], tv[3]);
        }
        int gn = n0 + r;
        if (gn < N) {
            float tv[4];
            for (int i = 0; i < 4; i++) tv[i] = (gk + i < K) ? W[(size_t)gn * K + gk + i] : 0.f;
            wv = make_float4(tv[0], tv[1], tv[2], tv[3]);
        }
        As[kk + 0][r] = av.x; As[kk + 1][r] = av.y; As[kk + 2][r] = av.z; As[kk + 3][r] = av.w;
        Ws[kk + 0][r] = wv.x; Ws[kk + 1][r] = wv.y; Ws[kk + 2][r] = wv.z; Ws[kk + 3][r] = wv.w;
        __syncthreads();
        #pragma unroll
        for (int k = 0; k < 16; k++) {
            float4 a4 = *(const float4*)&As[k][ty << 2];
            float4 b4 = *(const float4*)&Ws[k][tx << 2];
            float a[4] = {a4.x, a4.y, a4.z, a4.w};
            float b[4] = {b4.x, b4.y, b4.z, b4.w};
            #pragma unroll
            for (int i = 0; i < 4; i++)
                #pragma unroll
                for (int j = 0; j < 4; j++)
                    acc[i][j] = fmaf(a[i], b[j], acc[i][j]);
        }
        __syncthreads();
    }
    #pragma unroll
    for (int i = 0; i < 4; i++) {
        int gm = m0 + (ty << 2) + i;
        if (gm >= M) continue;
        #pragma unroll
        for (int j = 0; j < 4; j++) {
            int gn = n0 + (tx << 2) + j;
            if (gn >= N) continue;
            float v = acc[i][j] + bias[gn];
            if (relu) v = fmaxf(v, 0.f);
            C[(size_t)gm * N + gn] = v;
        }
    }
}

// ---------------- residual + LayerNorm (mode 1: broadcast delta) ----------------

__global__ __launch_bounds__(256) void k_add_ln(
    const float* __restrict__ x, const float* __restrict__ delta,
    const float* __restrict__ g, const float* __restrict__ bta,
    float* __restrict__ out, int M, int mode)
{
    int row = blockIdx.x * 4 + (threadIdx.x >> 6);
    int t = threadIdx.x & 63;
    if (row >= M) return;
    float4 v = ((const float4*)(x + (size_t)row * HH))[t];
    if (mode == 0) {
        float4 d = ((const float4*)(delta + (size_t)row * HH))[t];
        v.x += d.x; v.y += d.y; v.z += d.z; v.w += d.w;
    } else if (mode == 1) {
        float4 d = ((const float4*)(delta + (size_t)(row & 3) * HH))[t];
        v.x += d.x; v.y += d.y; v.z += d.z; v.w += d.w;
    }
    float s = v.x + v.y + v.z + v.w;
    for (int o = 32; o; o >>= 1) s += __shfl_down(s, o);
    float mean = __shfl(s, 0) * (1.f / 256.f);
    float cx = v.x - mean, cy = v.y - mean, cz = v.z - mean, cw = v.w - mean;
    float q = cx * cx + cy * cy + cz * cz + cw * cw;
    for (int o = 32; o; o >>= 1) q += __shfl_down(q, o);
    float rstd = rsqrtf(__shfl(q, 0) * (1.f / 256.f) + 1e-5f);
    float4 gg = ((const float4*)g)[t];
    float4 bb = ((const float4*)bta)[t];
    float4 o4;
    o4.x = cx * rstd * gg.x + bb.x;
    o4.y = cy * rstd * gg.y + bb.y;
    o4.z = cz * rstd * gg.z + bb.z;
    o4.w = cw * rstd * gg.w + bb.w;
    ((float4*)(out + (size_t)row * HH))[t] = o4;
}

// ---------------- BatchNorm partial sums ----------------

__global__ __launch_bounds__(256) void k_bn_part(const float* __restrict__ x, float* __restrict__ sums) {
    int t = threadIdx.x;
    int r0 = blockIdx.x * 16;
    float s = 0.f, s2 = 0.f;
    for (int r = r0; r < r0 + 16; r++) {
        float v = x[(size_t)r * 256 + t];
        s += v; s2 += v * v;
    }
    atomicAdd(&sums[t], s);
    atomicAdd(&sums[256 + t], s2);
}

// ---------------- BN-finalize + SELU + positional encoding ----------------

__global__ __launch_bounds__(256) void k_bn_selu_pe(
    const float* __restrict__ x0, const float* __restrict__ sums,
    const float* __restrict__ g, const float* __restrict__ b,
    const int* __restrict__ atom_i, float* __restrict__ out)
{
    int row = blockIdx.x, t = threadIdx.x;
    float m = sums[t] * (1.f / 1024.f);
    float var = sums[256 + t] * (1.f / 1024.f) - m * m;
    float rstd = rsqrtf(var + 1e-5f);
    float v = x0[(size_t)row * 256 + t];
    v = (v - m) * rstd * g[t] + b[t];
    const float SC = 1.0507009873554805f, AL = 1.6732632423543772f;
    v = SC * (v > 0.f ? v : AL * expm1f(v));
    float pos = (float)atom_i[row];
    float freq = expf(-(float)t * (9.210340371976184f / 256.f));
    float ang = pos * freq;
    float pe = (t & 1) ? cosf(ang) : sinf(ang);
    out[(size_t)row * 256 + t] = v + pe;
}

// ---------------- both-layer node cross-attn constant ----------------

__global__ __launch_bounds__(256) void k_cross2(
    const float* __restrict__ z, const float* __restrict__ cqkv_w, const float* __restrict__ cqkv_b,
    const float* __restrict__ co_w, const float* __restrict__ co_b, float* __restrict__ crO)
{
    int m = blockIdx.x, l = blockIdx.y;
    int t = threadIdx.x;
    __shared__ float zs[256], ct[256];
    zs[t] = z[m * 256 + t];
    __syncthreads();
    const float* wv = cqkv_w + (size_t)l * 768 * 256 + 512 * 256 + (size_t)t * 256;
    float a = cqkv_b[l * 768 + 512 + t];
    for (int d = 0; d < 256; d += 4) {
        float4 w4 = *(const float4*)(wv + d);
        a += zs[d] * w4.x + zs[d+1] * w4.y + zs[d+2] * w4.z + zs[d+3] * w4.w;
    }
    ct[t] = a;
    __syncthreads();
    const float* ow = co_w + (size_t)l * 65536 + (size_t)t * 256;
    float o = co_b[l * 256 + t];
    for (int d = 0; d < 256; d += 4) {
        float4 w4 = *(const float4*)(ow + d);
        o += ct[d] * w4.x + ct[d+1] * w4.y + ct[d+2] * w4.z + ct[d+3] * w4.w;
    }
    crO[l * 1024 + m * 256 + t] = o;
}

// ---------------- edge group self-attention ----------------

__global__ __launch_bounds__(256) void k_edge_self_attn(
    const float* __restrict__ qkv, float* __restrict__ out)
{
    int g = blockIdx.x + 1;
    int b = blockIdx.y;
    int gs = min(g, 12);
    int base = (g <= 13) ? g * (g - 1) / 2 : 78 + (g - 13) * 12;
    int h = threadIdx.x >> 7;
    int t = threadIdx.x & 127;
    __shared__ float qs[2][12][128], ks[2][12][128], vs[2][12][128];
    __shared__ float ps[2][12][12];
    for (int i = 0; i < gs; i++) {
        size_t row = ((size_t)(base + i) * BB + b) * 768 + h * 128 + t;
        qs[h][i][t] = qkv[row];
        ks[h][i][t] = qkv[row + 256];
        vs[h][i][t] = qkv[row + 512];
    }
    __syncthreads();
    for (int p = t; p < gs * gs; p += 128) {
        int i = p / gs, j = p - i * gs;
        float acc = 0.f;
        for (int d = 0; d < 128; d++) acc = fmaf(qs[h][i][d], ks[h][j][d], acc);
        ps[h][i][j] = acc * SCALE;
    }
    __syncthreads();
    if (t < gs) {
        float m = -1e30f;
        for (int j = 0; j < gs; j++) m = fmaxf(m, ps[h][t][j]);
        float e[12]; float s = 0.f;
        for (int j = 0; j < gs; j++) { e[j] = expf(ps[h][t][j] - m); s += e[j]; }
        float inv = 1.f / s;
        for (int j = 0; j < gs; j++) ps[h][t][j] = e[j] * inv;
    }
    __syncthreads();
    for (int i = 0; i < gs; i++) {
        float acc = 0.f;
        for (int j = 0; j < gs; j++) acc = fmaf(ps[h][i][j], vs[h][j][t], acc);
        out[((size_t)(base + i) * BB + b) * 256 + h * 128 + t] = acc;
    }
}

// ---------------- gather + build_mem fused ----------------

__global__ __launch_bounds__(256) void k_gather_mem(
    const float* __restrict__ z, const float* __restrict__ nemb,
    const int* __restrict__ idxt, float* __restrict__ etgt, float* __restrict__ memb)
{
    int r = blockIdx.x, t = threadIdx.x;
    if (r < LEB) {
        int e = r >> 2, b = r & 3;
        etgt[(size_t)r * 256 + t] = nemb[((size_t)idxt[e] * 4 + b) * 256 + t];
    } else {
        int rm = r - LEB;
        int m = rm >> 2, b = rm & 3;
        memb[(size_t)rm * 256 + t] = (m == 0) ? z[(size_t)b * 256 + t]
                                              : nemb[((size_t)(m - 1) * 4 + b) * 256 + t];
    }
}

// ---------------- fused node cross-entropy ----------------

__global__ __launch_bounds__(256) void k_ce_node(
    const float* __restrict__ emb,
    const float* __restrict__ w0, const float* __restrict__ b0,
    const float* __restrict__ w1, const float* __restrict__ b1,
    const float* __restrict__ w2, const float* __restrict__ b2,
    const int* __restrict__ y, int M, float invM, float* __restrict__ lossOut)
{
    int wave = threadIdx.x >> 6, lane = threadIdx.x & 63;
    int wid = blockIdx.x * 4 + wave;
    float local = 0.f;
    for (int r = wid; r < M; r += gridDim.x * 4) {
        float4 x = ((const float4*)(emb + (size_t)r * 256))[lane];
        float acc[54];
        #pragma unroll
        for (int c = 0; c < 40; c++) {
            float4 wv = ((const float4*)(w0 + (size_t)c * 256))[lane];
            acc[c] = x.x * wv.x + x.y * wv.y + x.z * wv.z + x.w * wv.w;
        }
        #pragma unroll
        for (int c = 0; c < 8; c++) {
            float4 wv = ((const float4*)(w1 + (size_t)c * 256))[lane];
            acc[40 + c] = x.x * wv.x + x.y * wv.y + x.z * wv.z + x.w * wv.w;
        }
        #pragma unroll
        for (int c = 0; c < 6; c++) {
            float4 wv = ((const float4*)(w2 + (size_t)c * 256))[lane];
            acc[48 + c] = x.x * wv.x + x.y * wv.y + x.z * wv.z + x.w * wv.w;
        }
        #pragma unroll
        for (int c = 0; c < 54; c++)
            for (int o = 32; o; o >>= 1) acc[c] += __shfl_down(acc[c], o);
        if (lane == 0) {
            int y0 = y[(size_t)r * 3 + 0], y1 = y[(size_t)r * 3 + 1], y2 = y[(size_t)r * 3 + 2];
            float m0 = -1e30f, m1 = -1e30f, m2 = -1e30f;
            float lg[54];
            for (int c = 0; c < 40; c++) { lg[c] = acc[c] + b0[c]; m0 = fmaxf(m0, lg[c]); }
            for (int c = 0; c < 8; c++)  { lg[40 + c] = acc[40 + c] + b1[c]; m1 = fmaxf(m1, lg[40 + c]); }
            for (int c = 0; c < 6; c++)  { lg[48 + c] = acc[48 + c] + b2[c]; m2 = fmaxf(m2, lg[48 + c]); }
            float s0 = 0.f, s1 = 0.f, s2 = 0.f;
            for (int c = 0; c < 40; c++) s0 += expf(lg[c] - m0);
            for (int c = 0; c < 8; c++)  s1 += expf(lg[40 + c] - m1);
            for (int c = 0; c < 6; c++)  s2 += expf(lg[48 + c] - m2);
            local += (m0 + logf(s0) - lg[y0]) + (m1 + logf(s1) - lg[40 + y1]) + (m2 + logf(s2) - lg[48 + y2]);
        }
    }
    __shared__ float ls[4];
    if (lane == 0) ls[wave] = local;
    __syncthreads();
    if (threadIdx.x == 0)
        atomicAdd(lossOut, (ls[0] + ls[1] + ls[2] + ls[3]) * invM);
}

// ---------------- host ----------------

extern "C" void kernel_launch(void* const* d_in, const int* in_sizes, int n_in,
                              void* d_out, int out_size, void* d_ws, size_t ws_size,
                              hipStream_t stream)
{
    (void)in_sizes; (void)n_in; (void)out_size; (void)ws_size;
    const float* zin      = (const float*)d_in[0];
    const int*   atom_i   = (const int*)d_in[1];
    const float* atom_x   = (const float*)d_in[2];
    const int*   atom_y   = (const int*)d_in[3];
    const int*   bond_y   = (const int*)d_in[4];
    const float* Wp       = (const float*)d_in[5];
    const float* bp       = (const float*)d_in[6];
    const float* bn_g     = (const float*)d_in[7];
    const float* bn_b     = (const float*)d_in[8];
    const float* nd_qkv_w = (const float*)d_in[9];
    const float* nd_qkv_b = (const float*)d_in[10];
    const float* nd_so_w  = (const float*)d_in[11];
    const float* nd_so_b  = (const float*)d_in[12];
    const float* nd_cqkv_w= (const float*)d_in[13];
    const float* nd_cqkv_b= (const float*)d_in[14];
    const float* nd_co_w  = (const float*)d_in[15];
    const float* nd_co_b  = (const float*)d_in[16];
    const float* nd_ff1_w = (const float*)d_in[17];
    const float* nd_ff1_b = (const float*)d_in[18];
    const float* nd_ff2_w = (const float*)d_in[19];
    const float* nd_ff2_b = (const float*)d_in[20];
    const float* nd_ln_g  = (const float*)d_in[21];
    const float* nd_ln_b  = (const float*)d_in[22];
    const float* nd_fn_g  = (const float*)d_in[23];
    const float* nd_fn_b  = (const float*)d_in[24];
    const float* ed_qkv_w = (const float*)d_in[25];
    const float* ed_qkv_b = (const float*)d_in[26];
    const float* ed_so_w  = (const float*)d_in[27];
    const float* ed_so_b  = (const float*)d_in[28];
    const float* ed_cqkv_w= (const float*)d_in[29];
    const float* ed_cqkv_b= (const float*)d_in[30];
    const float* ed_co_w  = (const float*)d_in[31];
    const float* ed_co_b  = (const float*)d_in[32];
    const float* ed_ff1_w = (const float*)d_in[33];
    const float* ed_ff1_b = (const float*)d_in[34];
    const float* ed_ff2_w = (const float*)d_in[35];
    const float* ed_ff2_b = (const float*)d_in[36];
    const float* ed_ln_g  = (const float*)d_in[37];
    const float* ed_ln_b  = (const float*)d_in[38];
    const float* ed_fn_g  = (const float*)d_in[39];
    const float* ed_fn_b  = (const float*)d_in[40];
    const float* nc0_w = (const float*)d_in[41]; const float* nc0_b = (const float*)d_in[42];
    const float* nc1_w = (const float*)d_in[43]; const float* nc1_b = (const float*)d_in[44];
    const float* nc2_w = (const float*)d_in[45]; const float* nc2_b = (const float*)d_in[46];
    const float* ec0_w = (const float*)d_in[47]; const float* ec0_b = (const float*)d_in[48];
    const float* ec1_w = (const float*)d_in[49]; const float* ec1_b = (const float*)d_in[50];

    float* out = (float*)d_out;

    char* wsb = (char*)d_ws;
    size_t off = 0;
    auto alloc = [&](size_t nbytes) -> void* {
        void* p = (void*)(wsb + off);
        off += (nbytes + 255) / 256 * 256;
        return p;
    };
    float* x0    = (float*)alloc(1024 * 256 * 4);
    float* tgt   = (float*)alloc(1024 * 256 * 4);
    float* nqkv  = (float*)alloc(1024 * 768 * 4);
    float* t1    = (float*)alloc(1024 * 256 * 4);
    float* nemb  = (float*)alloc(1024 * 256 * 4);
    float* bnsums= (float*)alloc(512 * 4);
    float* crO   = (float*)alloc(2 * 1024 * 4);
    float* memb  = (float*)alloc(1028 * 256 * 4);
    float* KV    = (float*)alloc(1028 * 512 * 4);
    ushort* Sb   = (ushort*)alloc(8 * 65536 * 2);
    float* Vt    = (float*)alloc(8 * 32768 * 4);
    float* etgt  = (float*)alloc((size_t)LEB * 256 * 4);
    float* eqkv  = (float*)alloc((size_t)LEB * 768 * 4);
    float* et1   = (float*)alloc((size_t)LEB * 256 * 4);
    int* grp   = (int*)alloc(LE * 4);
    int* idxt  = (int*)alloc(LE * 4);
    ushort* wpk = (ushort*)alloc((size_t)TOTFRAG * 512 * 2);

    PackArgs pa;
    pa.src[0] = nd_qkv_w;              pa.src[1] = nd_qkv_w + 768 * 256;
    pa.src[2] = nd_so_w;               pa.src[3] = nd_so_w + 65536;
    pa.src[4] = nd_ff1_w;              pa.src[5] = nd_ff1_w + 65536;
    pa.src[6] = nd_ff2_w;              pa.src[7] = nd_ff2_w + 65536;
    pa.src[8] = ed_qkv_w;              pa.src[9] = ed_cqkv_w;
    pa.src[10] = ed_so_w;              pa.src[11] = ed_co_w;
    pa.src[12] = ed_ff1_w;             pa.src[13] = ed_ff2_w;
    int fs[NPACK + 1] = {0, 384, 768, 896, 1024, 1152, 1280, 1408, 1536, 1920, 2304, 2432, 2560, 2688, 2816};
    for (int i = 0; i <= NPACK; i++) pa.fs[i] = fs[i];
    auto wp = [&](int i) -> const ushort* { return wpk + (size_t)fs[i] * 512; };

    // convenience wrapper for k_gemm_w
    auto G = [&](dim3 grid, const float* A, const ushort* Wq, const float* bi,
                 const float* res, const float* g1, const float* b1,
                 const float* g2, const float* b2, float* C, float* Vtp,
                 const float* KVp, const int* grpp,
                 const int* yd, const float* c0w, const float* c0b,
                 const float* c1w, const float* c1b, float* lo, float im,
                 int M, int N, int mode, int relu) {
        k_gemm_w<<<grid, 256, 0, stream>>>(A, Wq, bi, res, g1, b1, g2, b2, C, Vtp,
                                           KVp, grpp, yd, c0w, c0b, c1w, c1b, lo, im,
                                           M, N, mode, relu);
    };

    k_init<<<13, 256, 0, stream>>>(out, bnsums, grp, idxt);
    k_prep<<<(TOTFRAG * 64 + 255) / 256, 256, 0, stream>>>(pa, wpk);

    // node input: projection + BN + SELU + PE
    k_gemm<<<dim3(4, 16), dim3(16, 16), 0, stream>>>(atom_x, Wp, bp, x0, 1024, 256, 54, 0);
    k_bn_part<<<64, 256, 0, stream>>>(x0, bnsums);
    k_bn_selu_pe<<<1024, 256, 0, stream>>>(x0, bnsums, bn_g, bn_b, atom_i, tgt);

    // both layers' cross-attn constant
    k_cross2<<<dim3(4, 2), 256, 0, stream>>>(zin, nd_cqkv_w, nd_cqkv_b, nd_co_w, nd_co_b, crO);

    // node decoder: 2 layers
    for (int l = 0; l < 2; l++) {
        G(dim3(3, 16), tgt, wp(l), nd_qkv_b + l * 768,
          nullptr, nullptr, nullptr, nullptr, nullptr, nqkv, Vt,
          nullptr, nullptr, nullptr, nullptr, nullptr, nullptr, nullptr, nullptr, 0.f,
          1024, 768, 3, 0);
        k_attn_qks<<<dim3(4, 8), 256, 0, stream>>>(nqkv, Sb);
        k_attn_pvt<<<dim3(4, 8), 256, 0, stream>>>(Sb, Vt, t1);
        G(dim3(1, 16), t1, wp(2 + l), nd_so_b + l * 256,
          tgt, nd_ln_g + (l * 3 + 0) * 256, nd_ln_b + (l * 3 + 0) * 256,
          nullptr, nullptr, tgt, nullptr,
          nullptr, nullptr, nullptr, nullptr, nullptr, nullptr, nullptr, nullptr, 0.f,
          1024, 256, 1, 0);
        k_add_ln<<<256, 256, 0, stream>>>(tgt, crO + l * 1024,
                                          nd_ln_g + (l * 3 + 1) * 256, nd_ln_b + (l * 3 + 1) * 256,
                                          tgt, 1024, 1);
        G(dim3(1, 16), tgt, wp(4 + l), nd_ff1_b + l * 256,
          nullptr, nullptr, nullptr, nullptr, nullptr, t1, nullptr,
          nullptr, nullptr, nullptr, nullptr, nullptr, nullptr, nullptr, nullptr, 0.f,
          1024, 256, 0, 1);
        if (l == 0) {
            G(dim3(1, 16), t1, wp(6), nd_ff2_b,
              tgt, nd_ln_g + 2 * 256, nd_ln_b + 2 * 256,
              nullptr, nullptr, tgt, nullptr,
              nullptr, nullptr, nullptr, nullptr, nullptr, nullptr, nullptr, nullptr, 0.f,
              1024, 256, 1, 0);
        } else {
            G(dim3(1, 16), t1, wp(7), nd_ff2_b + 256,
              tgt, nd_ln_g + 5 * 256, nd_ln_b + 5 * 256,
              nd_fn_g, nd_fn_b, nemb, nullptr,
              nullptr, nullptr, nullptr, nullptr, nullptr, nullptr, nullptr, nullptr, 0.f,
              1024, 256, 2, 0);
        }
    }

    // node losses
    k_ce_node<<<128, 256, 0, stream>>>(nemb, nc0_w, nc0_b, nc1_w, nc1_b, nc2_w, nc2_b,
                                       atom_y, 1024, 1.f / 1024.f, out);

    // edge path
    k_gather_mem<<<LEB + 1028, 256, 0, stream>>>(zin, nemb, idxt, etgt, memb);
    // KV of edge memory (rows 256..767 of ed_cqkv -> frag offset 128)
    G(dim3(2, 17), memb, wp(9) + 128 * 512, ed_cqkv_b + 256,
      nullptr, nullptr, nullptr, nullptr, nullptr, KV, nullptr,
      nullptr, nullptr, nullptr, nullptr, nullptr, nullptr, nullptr, nullptr, 0.f,
      1028, 512, 0, 0);
    // edge self QKV
    G(dim3(3, 188), etgt, wp(8), ed_qkv_b,
      nullptr, nullptr, nullptr, nullptr, nullptr, eqkv, nullptr,
      nullptr, nullptr, nullptr, nullptr, nullptr, nullptr, nullptr, nullptr, 0.f,
      LEB, 768, 0, 0);
    k_edge_self_attn<<<dim3(255, 4), 256, 0, stream>>>(eqkv, et1);
    G(dim3(1, 188), et1, wp(10), ed_so_b,
      etgt, ed_ln_g, ed_ln_b, nullptr, nullptr, etgt, nullptr,
      nullptr, nullptr, nullptr, nullptr, nullptr, nullptr, nullptr, nullptr, 0.f,
      LEB, 256, 1, 0);
    // edge cross: q-projection + 2-key attention fused (mode 4) -> et1
    G(dim3(1, 188), etgt, wp(9), ed_cqkv_b,
      nullptr, nullptr, nullptr, nullptr, nullptr, et1, nullptr,
      KV, grp, nullptr, nullptr, nullptr, nullptr, nullptr, nullptr, 0.f,
      LEB, 256, 4, 0);
    G(dim3(1, 188), et1, wp(11), ed_co_b,
      etgt, ed_ln_g + 256, ed_ln_b + 256, nullptr, nullptr, etgt, nullptr,
      nullptr, nullptr, nullptr, nullptr, nullptr, nullptr, nullptr, nullptr, 0.f,
      LEB, 256, 1, 0);
    G(dim3(1, 188), etgt, wp(12), ed_ff1_b,
      nullptr, nullptr, nullptr, nullptr, nullptr, et1, nullptr,
      nullptr, nullptr, nullptr, nullptr, nullptr, nullptr, nullptr, nullptr, 0.f,
      LEB, 256, 0, 1);
    // edge FF2 + res + LN + final LN + CE (mode 5), no store
    G(dim3(1, 188), et1, wp(13), ed_ff2_b,
      etgt, ed_ln_g + 512, ed_ln_b + 512, ed_fn_g, ed_fn_b, nullptr, nullptr,
      nullptr, nullptr, bond_y, ec0_w, ec0_b, ec1_w, ec1_b, out, 1.f / (float)LEB,
      LEB, 256, 5, 0);
}

// Round 9
// 594.923 us; speedup vs baseline: 1.0095x; 1.0095x over previous
//
#include <hip/hip_runtime.h>
#include <math.h>

#define SS 256
#define BB 4
#define HH 256
#define LE 2994
#define LEB (LE*BB)
#define SCALE 0.08838834764831845f  // 1/sqrt(128)

typedef __attribute__((ext_vector_type(8))) short bf16x8;
typedef __attribute__((ext_vector_type(4))) float f32x4;

__device__ inline ushort f2b(float f) {   // fp32 -> bf16 RNE
    unsigned u = __float_as_uint(f);
    u += 0x7FFFu + ((u >> 16) & 1u);
    return (ushort)(u >> 16);
}

__device__ inline float qred(float x) {   // sum across 16 lanes of a quarter-wave (broadcast)
    x += __shfl_xor(x, 1); x += __shfl_xor(x, 2);
    x += __shfl_xor(x, 4); x += __shfl_xor(x, 8);
    return x;
}

// ---------------- init ----------------

__global__ void k_init(float* __restrict__ out, float* __restrict__ bnsums,
                       int* __restrict__ grp, int* __restrict__ idxt) {
    int bid = blockIdx.x, t = threadIdx.x;
    if (bid == 0) {
        if (t == 0) out[0] = 0.f;
        bnsums[t] = 0.f; bnsums[256 + t] = 0.f;
        return;
    }
    int e = (bid - 1) * 256 + t;
    if (e >= LE) return;
    int g, pos;
    if (e < 78) {
        g = (int)((1.0f + sqrtf(8.0f * (float)e + 1.0f)) * 0.5f);
        while (g * (g - 1) / 2 > e) g--;
        while ((g + 1) * g / 2 <= e) g++;
        pos = e - g * (g - 1) / 2;
        idxt[e] = pos;
    } else {
        int r = e - 78;
        g = 13 + r / 12;
        pos = r % 12;
        idxt[e] = g - 12 + pos;
    }
    grp[e] = g;
}

// ---------------- weight pre-pack ----------------

#define NPACK 14
#define TOTFRAG 2816
struct PackArgs { const float* src[NPACK]; int fs[NPACK + 1]; };

__global__ __launch_bounds__(256) void k_prep(PackArgs pa, ushort* __restrict__ dst) {
    int wid = (blockIdx.x * 256 + threadIdx.x) >> 6;
    int lane = threadIdx.x & 63;
    if (wid >= TOTFRAG) return;
    int i = 0;
    while (pa.fs[i + 1] <= wid) i++;
    int f = wid - pa.fs[i];
    int tn = f >> 3, tk = f & 7;
    int q = lane >> 4, p = lane & 15;
    const float* s = pa.src[i] + (size_t)(tn * 16 + p) * 256 + tk * 32 + q * 8;
    float4 a0 = *(const float4*)s, a1 = *(const float4*)(s + 4);
    uint4 o = make_uint4(f2b(a0.x) | ((unsigned)f2b(a0.y) << 16),
                         f2b(a0.z) | ((unsigned)f2b(a0.w) << 16),
                         f2b(a1.x) | ((unsigned)f2b(a1.y) << 16),
                         f2b(a1.z) | ((unsigned)f2b(a1.w) << 16));
    *(uint4*)&dst[(size_t)wid * 512 + lane * 8] = o;
}

// ---------------- plain bf16 GEMM with packed W (modes 0/3), 64-row x 256-col tiles ----------------

__global__ __launch_bounds__(256) void k_gemm_w(
    const float* __restrict__ A, const ushort* __restrict__ Wp,
    const float* __restrict__ bias, float* __restrict__ C, float* __restrict__ Vt,
    int M, int N, int mode, int relu)
{
    __shared__ ushort As[32 * 512];
    int tid = threadIdx.x;
    int w = tid >> 6, lane = tid & 63;
    int q = lane >> 4, p = lane & 15;
    int m0 = blockIdx.y * 64, n0 = blockIdx.x * 256;

    {
        int r = tid >> 2;
        int cbase = (tid & 3) * 64;
        int gm = m0 + r;
        const float* Ar = A + (size_t)gm * 256 + cbase;
        bool ok = gm < M;
        #pragma unroll
        for (int j = 0; j < 8; j++) {
            int c = cbase + j * 8;
            float4 a0, a1;
            if (ok) { a0 = *(const float4*)(Ar + j * 8); a1 = *(const float4*)(Ar + j * 8 + 4); }
            else { a0 = make_float4(0.f, 0.f, 0.f, 0.f); a1 = a0; }
            uint4 o = make_uint4(f2b(a0.x) | ((unsigned)f2b(a0.y) << 16),
                                 f2b(a0.z) | ((unsigned)f2b(a0.w) << 16),
                                 f2b(a1.x) | ((unsigned)f2b(a1.y) << 16),
                                 f2b(a1.z) | ((unsigned)f2b(a1.w) << 16));
            int frag = (r >> 4) * 8 + (c >> 5);
            int fl = ((c >> 3) & 3) * 16 + (r & 15);
            *(uint4*)&As[frag * 512 + fl * 8] = o;
        }
    }
    __syncthreads();

    f32x4 acc[4][4];
    #pragma unroll
    for (int i = 0; i < 4; i++)
        #pragma unroll
        for (int j = 0; j < 4; j++) acc[i][j] = (f32x4){0.f, 0.f, 0.f, 0.f};

    int nw = n0 + w * 64;
    const ushort* Wb = Wp + (size_t)(nw >> 4) * 4096;

    #pragma unroll
    for (int kt = 0; kt < 8; kt++) {
        bf16x8 afr[4], wfr[4];
        #pragma unroll
        for (int mt = 0; mt < 4; mt++)
            afr[mt] = *(const bf16x8*)&As[(mt * 8 + kt) * 512 + lane * 8];
        #pragma unroll
        for (int nt = 0; nt < 4; nt++)
            wfr[nt] = *(const bf16x8*)&Wb[(size_t)(nt * 8 + kt) * 512 + lane * 8];
        #pragma unroll
        for (int mt = 0; mt < 4; mt++)
            #pragma unroll
            for (int nt = 0; nt < 4; nt++)
                acc[mt][nt] = __builtin_amdgcn_mfma_f32_16x16x32_bf16(afr[mt], wfr[nt], acc[mt][nt], 0, 0, 0);
    }

    float bi[4]; int col[4];
    #pragma unroll
    for (int nt = 0; nt < 4; nt++) { col[nt] = nw + nt * 16 + p; bi[nt] = bias[col[nt]]; }
    #pragma unroll
    for (int mt = 0; mt < 4; mt++)
        #pragma unroll
        for (int reg = 0; reg < 4; reg++) {
            int grow = m0 + mt * 16 + q * 4 + reg;
            if (grow >= M) continue;
            #pragma unroll
            for (int nt = 0; nt < 4; nt++) {
                float v = acc[mt][nt][reg] + bi[nt];
                if (relu) v = fmaxf(v, 0.f);
                if (mode == 3) {
                    if (col[nt] < 512) {
                        C[(size_t)grow * 768 + col[nt]] = v;
                    } else {
                        int hh = (col[nt] - 512) >> 7, dh = (col[nt] - 512) & 127;
                        int zz = (grow & 3) * 2 + hh;
                        Vt[(size_t)zz * 32768 + (size_t)dh * 256 + (grow >> 2)] = v;
                    }
                } else {
                    C[(size_t)grow * N + col[nt]] = v;
                }
            }
        }
}

// ---------------- 32-row / 2-wave pipeline building blocks ----------------

__device__ inline void stage_globalA32(const float* __restrict__ A, int M, int m0, int tid,
                                       ushort* __restrict__ As) {
    int r = tid >> 2;
    int cbase = (tid & 3) * 64;
    int gm = m0 + r;
    const float* Ar = A + (size_t)gm * 256 + cbase;
    bool ok = gm < M;
    #pragma unroll
    for (int j = 0; j < 8; j++) {
        int c = cbase + j * 8;
        float4 a0, a1;
        if (ok) { a0 = *(const float4*)(Ar + j * 8); a1 = *(const float4*)(Ar + j * 8 + 4); }
        else { a0 = make_float4(0.f, 0.f, 0.f, 0.f); a1 = a0; }
        uint4 o = make_uint4(f2b(a0.x) | ((unsigned)f2b(a0.y) << 16),
                             f2b(a0.z) | ((unsigned)f2b(a0.w) << 16),
                             f2b(a1.x) | ((unsigned)f2b(a1.y) << 16),
                             f2b(a1.z) | ((unsigned)f2b(a1.w) << 16));
        int frag = (r >> 4) * 8 + (c >> 5);
        int fl = ((c >> 3) & 3) * 16 + (r & 15);
        *(uint4*)&As[frag * 512 + fl * 8] = o;
    }
    __syncthreads();
}

__device__ inline void gemm_pass32(const ushort* __restrict__ As, const ushort* __restrict__ Wq,
                                   int w, int lane, f32x4 (&acc)[2][8]) {
    #pragma unroll
    for (int mt = 0; mt < 2; mt++)
        #pragma unroll
        for (int nt = 0; nt < 8; nt++) acc[mt][nt] = (f32x4){0.f, 0.f, 0.f, 0.f};
    #pragma unroll
    for (int kt = 0; kt < 8; kt++) {
        bf16x8 a0 = *(const bf16x8*)&As[kt * 512 + lane * 8];
        bf16x8 a1 = *(const bf16x8*)&As[(8 + kt) * 512 + lane * 8];
        #pragma unroll
        for (int nt = 0; nt < 8; nt++) {
            bf16x8 wf = *(const bf16x8*)&Wq[(size_t)((w * 8 + nt) * 8 + kt) * 512 + lane * 8];
            acc[0][nt] = __builtin_amdgcn_mfma_f32_16x16x32_bf16(a0, wf, acc[0][nt], 0, 0, 0);
            acc[1][nt] = __builtin_amdgcn_mfma_f32_16x16x32_bf16(a1, wf, acc[1][nt], 0, 0, 0);
        }
    }
}

__device__ inline void stage_acc32(const f32x4 (&acc)[2][8], ushort* __restrict__ As,
                                   int w, int q, int p) {
    __syncthreads();   // all waves done reading As from previous pass
    #pragma unroll
    for (int mt = 0; mt < 2; mt++)
        #pragma unroll
        for (int nt = 0; nt < 8; nt++)
            #pragma unroll
            for (int reg = 0; reg < 4; reg++)
                As[(mt * 8 + w * 4 + (nt >> 1)) * 512 +
                   ((((nt * 2) + (p >> 3)) & 3) * 16 + q * 4 + reg) * 8 + (p & 7)] =
                    f2b(acc[mt][nt][reg]);
    __syncthreads();
}

__device__ inline void block_ln32(f32x4 (&acc)[2][8], float* __restrict__ red,
                                  int tid, int w, int q, int p,
                                  const float* __restrict__ g, const float* __restrict__ b) {
    float gg[8], bb[8];
    #pragma unroll
    for (int nt = 0; nt < 8; nt++) { int col = w * 128 + nt * 16 + p; gg[nt] = g[col]; bb[nt] = b[col]; }
    #pragma unroll
    for (int mt = 0; mt < 2; mt++)
        #pragma unroll
        for (int reg = 0; reg < 4; reg++) {
            float s = 0.f;
            #pragma unroll
            for (int nt = 0; nt < 8; nt++) s += acc[mt][nt][reg];
            s = qred(s);
            if (p == 0) red[w * 32 + mt * 16 + q * 4 + reg] = s;
        }
    __syncthreads();
    if (tid < 32) red[64 + tid] = (red[tid] + red[32 + tid]) * (1.f / 256.f);
    __syncthreads();
    #pragma unroll
    for (int mt = 0; mt < 2; mt++)
        #pragma unroll
        for (int reg = 0; reg < 4; reg++) {
            int lr = mt * 16 + q * 4 + reg;
            float mean = red[64 + lr];
            float sq = 0.f;
            #pragma unroll
            for (int nt = 0; nt < 8; nt++) {
                acc[mt][nt][reg] -= mean;
                sq += acc[mt][nt][reg] * acc[mt][nt][reg];
            }
            sq = qred(sq);
            if (p == 0) red[w * 32 + lr] = sq;
        }
    __syncthreads();
    if (tid < 32) red[64 + tid] = rsqrtf((red[tid] + red[32 + tid]) * (1.f / 256.f) + 1e-5f);
    __syncthreads();
    #pragma unroll
    for (int mt = 0; mt < 2; mt++)
        #pragma unroll
        for (int reg = 0; reg < 4; reg++) {
            float rstd = red[64 + mt * 16 + q * 4 + reg];
            #pragma unroll
            for (int nt = 0; nt < 8; nt++)
                acc[mt][nt][reg] = acc[mt][nt][reg] * rstd * gg[nt] + bb[nt];
        }
    __syncthreads();   // red reusable after this
}

// ---------------- node mega: so+LN, +crO+LN, ff1, ff2+LN(+final LN) ----------------

__global__ __launch_bounds__(128) void k_node_mega(
    const float* __restrict__ t1, const float* __restrict__ tgt,
    const float* __restrict__ crO,
    const ushort* __restrict__ Wso, const float* __restrict__ so_b,
    const float* __restrict__ ln0g, const float* __restrict__ ln0b,
    const float* __restrict__ ln1g, const float* __restrict__ ln1b,
    const ushort* __restrict__ Wff1, const float* __restrict__ ff1_b,
    const ushort* __restrict__ Wff2, const float* __restrict__ ff2_b,
    const float* __restrict__ ln2g, const float* __restrict__ ln2b,
    const float* __restrict__ fng, const float* __restrict__ fnb,
    float* __restrict__ outp, int M, int finalln)
{
    __shared__ ushort As[16 * 512];
    __shared__ float red[96];
    int tid = threadIdx.x;
    int w = tid >> 6, lane = tid & 63, q = lane >> 4, p = lane & 15;
    int m0 = blockIdx.x * 32;

    float x[2][8][4];
    f32x4 acc[2][8];

    stage_globalA32(t1, M, m0, tid, As);
    #pragma unroll
    for (int mt = 0; mt < 2; mt++)
        #pragma unroll
        for (int reg = 0; reg < 4; reg++) {
            int row = m0 + mt * 16 + q * 4 + reg;
            bool ok = row < M;
            #pragma unroll
            for (int nt = 0; nt < 8; nt++)
                x[mt][nt][reg] = ok ? tgt[(size_t)row * 256 + w * 128 + nt * 16 + p] : 0.f;
        }

    // pass 1: self-out + residual + LN
    gemm_pass32(As, Wso, w, lane, acc);
    {
        float bi[8];
        #pragma unroll
        for (int nt = 0; nt < 8; nt++) bi[nt] = so_b[w * 128 + nt * 16 + p];
        #pragma unroll
        for (int mt = 0; mt < 2; mt++)
            #pragma unroll
            for (int nt = 0; nt < 8; nt++)
                #pragma unroll
                for (int reg = 0; reg < 4; reg++)
                    acc[mt][nt][reg] += bi[nt] + x[mt][nt][reg];
    }
    block_ln32(acc, red, tid, w, q, p, ln0g, ln0b);

    // + crO (broadcast over batch) + LN
    #pragma unroll
    for (int mt = 0; mt < 2; mt++)
        #pragma unroll
        for (int reg = 0; reg < 4; reg++) {
            int row = m0 + mt * 16 + q * 4 + reg;
            int b = row & 3;
            #pragma unroll
            for (int nt = 0; nt < 8; nt++)
                acc[mt][nt][reg] += crO[b * 256 + w * 128 + nt * 16 + p];
        }
    block_ln32(acc, red, tid, w, q, p, ln1g, ln1b);

    // save x2 (residual for ff)
    #pragma unroll
    for (int mt = 0; mt < 2; mt++)
        #pragma unroll
        for (int nt = 0; nt < 8; nt++)
            #pragma unroll
            for (int reg = 0; reg < 4; reg++)
                x[mt][nt][reg] = acc[mt][nt][reg];

    // pass 2: ff1 + relu
    stage_acc32(acc, As, w, q, p);
    gemm_pass32(As, Wff1, w, lane, acc);
    {
        float bi[8];
        #pragma unroll
        for (int nt = 0; nt < 8; nt++) bi[nt] = ff1_b[w * 128 + nt * 16 + p];
        #pragma unroll
        for (int mt = 0; mt < 2; mt++)
            #pragma unroll
            for (int nt = 0; nt < 8; nt++)
                #pragma unroll
                for (int reg = 0; reg < 4; reg++)
                    acc[mt][nt][reg] = fmaxf(acc[mt][nt][reg] + bi[nt], 0.f);
    }

    // pass 3: ff2 + residual + LN (+final LN)
    stage_acc32(acc, As, w, q, p);
    gemm_pass32(As, Wff2, w, lane, acc);
    {
        float bi[8];
        #pragma unroll
        for (int nt = 0; nt < 8; nt++) bi[nt] = ff2_b[w * 128 + nt * 16 + p];
        #pragma unroll
        for (int mt = 0; mt < 2; mt++)
            #pragma unroll
            for (int nt = 0; nt < 8; nt++)
                #pragma unroll
                for (int reg = 0; reg < 4; reg++)
                    acc[mt][nt][reg] += bi[nt] + x[mt][nt][reg];
    }
    block_ln32(acc, red, tid, w, q, p, ln2g, ln2b);
    if (finalln) block_ln32(acc, red, tid, w, q, p, fng, fnb);

    #pragma unroll
    for (int mt = 0; mt < 2; mt++)
        #pragma unroll
        for (int reg = 0; reg < 4; reg++) {
            int row = m0 + mt * 16 + q * 4 + reg;
            if (row >= M) continue;
            #pragma unroll
            for (int nt = 0; nt < 8; nt++)
                outp[(size_t)row * 256 + w * 128 + nt * 16 + p] = acc[mt][nt][reg];
        }
}

// ---------------- edge mega: so+LN, crossQ+2key-attn, co+LN, ff1, ff2+LN+finalLN+CE ----------------

__global__ __launch_bounds__(128) void k_edge_mega(
    const float* __restrict__ et1, const float* __restrict__ etgt,
    const ushort* __restrict__ Wso, const float* __restrict__ so_b,
    const float* __restrict__ ln0g, const float* __restrict__ ln0b,
    const ushort* __restrict__ Wcq, const float* __restrict__ cq_b,
    const float* __restrict__ KV, const int* __restrict__ grp,
    const ushort* __restrict__ Wco, const float* __restrict__ co_b,
    const float* __restrict__ ln1g, const float* __restrict__ ln1b,
    const ushort* __restrict__ Wff1, const float* __restrict__ ff1_b,
    const ushort* __restrict__ Wff2, const float* __restrict__ ff2_b,
    const float* __restrict__ ln2g, const float* __restrict__ ln2b,
    const float* __restrict__ fng, const float* __restrict__ fnb,
    const int* __restrict__ ydata,
    const float* __restrict__ cw0, const float* __restrict__ cb0,
    const float* __restrict__ cw1, const float* __restrict__ cb1,
    float* __restrict__ lossOut, float invM, int M)
{
    __shared__ ushort As[16 * 512];
    __shared__ float red[640];
    int tid = threadIdx.x;
    int w = tid >> 6, lane = tid & 63, q = lane >> 4, p = lane & 15;
    int m0 = blockIdx.x * 32;

    float x[2][8][4];
    f32x4 acc[2][8];

    stage_globalA32(et1, M, m0, tid, As);
    #pragma unroll
    for (int mt = 0; mt < 2; mt++)
        #pragma unroll
        for (int reg = 0; reg < 4; reg++) {
            int row = m0 + mt * 16 + q * 4 + reg;
            bool ok = row < M;
            #pragma unroll
            for (int nt = 0; nt < 8; nt++)
                x[mt][nt][reg] = ok ? etgt[(size_t)row * 256 + w * 128 + nt * 16 + p] : 0.f;
        }

    // pass 1: self-out + residual + LN  -> x (tgt1)
    gemm_pass32(As, Wso, w, lane, acc);
    {
        float bi[8];
        #pragma unroll
        for (int nt = 0; nt < 8; nt++) bi[nt] = so_b[w * 128 + nt * 16 + p];
        #pragma unroll
        for (int mt = 0; mt < 2; mt++)
            #pragma unroll
            for (int nt = 0; nt < 8; nt++)
                #pragma unroll
                for (int reg = 0; reg < 4; reg++)
                    acc[mt][nt][reg] += bi[nt] + x[mt][nt][reg];
    }
    block_ln32(acc, red, tid, w, q, p, ln0g, ln0b);
    #pragma unroll
    for (int mt = 0; mt < 2; mt++)
        #pragma unroll
        for (int nt = 0; nt < 8; nt++)
            #pragma unroll
            for (int reg = 0; reg < 4; reg++)
                x[mt][nt][reg] = acc[mt][nt][reg];

    // pass 2: cross q projection + 2-key attention (head = w, fully within quarter-wave)
    stage_acc32(acc, As, w, q, p);
    gemm_pass32(As, Wcq, w, lane, acc);
    {
        float bi[8];
        #pragma unroll
        for (int nt = 0; nt < 8; nt++) bi[nt] = cq_b[w * 128 + nt * 16 + p];
        #pragma unroll
        for (int mt = 0; mt < 2; mt++)
            #pragma unroll
            for (int reg = 0; reg < 4; reg++) {
                int row = m0 + mt * 16 + q * 4 + reg;
                bool ok = row < M;
                int b = row & 3;
                int g = ok ? grp[row >> 2] : 0;
                const float* K0 = KV + (size_t)b * 512 + w * 128;
                const float* K1 = KV + ((size_t)(g + 1) * 4 + b) * 512 + w * 128;
                float s0 = 0.f, s1 = 0.f;
                #pragma unroll
                for (int nt = 0; nt < 8; nt++) {
                    float qv = acc[mt][nt][reg] + bi[nt];
                    int d = nt * 16 + p;
                    s0 += qv * K0[d]; s1 += qv * K1[d];
                }
                s0 = qred(s0) * SCALE;
                s1 = qred(s1) * SCALE;
                float mx = fmaxf(s0, s1);
                float e0 = __expf(s0 - mx), e1 = __expf(s1 - mx);
                float inv = 1.f / (e0 + e1);
                e0 *= inv; e1 *= inv;
                #pragma unroll
                for (int nt = 0; nt < 8; nt++) {
                    int d = nt * 16 + p;
                    acc[mt][nt][reg] = e0 * K0[256 + d] + e1 * K1[256 + d];
                }
            }
    }

    // pass 3: cross-out + residual + LN -> x (tgt2)
    stage_acc32(acc, As, w, q, p);
    gemm_pass32(As, Wco, w, lane, acc);
    {
        float bi[8];
        #pragma unroll
        for (int nt = 0; nt < 8; nt++) bi[nt] = co_b[w * 128 + nt * 16 + p];
        #pragma unroll
        for (int mt = 0; mt < 2; mt++)
            #pragma unroll
            for (int nt = 0; nt < 8; nt++)
                #pragma unroll
                for (int reg = 0; reg < 4; reg++)
                    acc[mt][nt][reg] += bi[nt] + x[mt][nt][reg];
    }
    block_ln32(acc, red, tid, w, q, p, ln1g, ln1b);
    #pragma unroll
    for (int mt = 0; mt < 2; mt++)
        #pragma unroll
        for (int nt = 0; nt < 8; nt++)
            #pragma unroll
            for (int reg = 0; reg < 4; reg++)
                x[mt][nt][reg] = acc[mt][nt][reg];

    // pass 4: ff1 + relu
    stage_acc32(acc, As, w, q, p);
    gemm_pass32(As, Wff1, w, lane, acc);
    {
        float bi[8];
        #pragma unroll
        for (int nt = 0; nt < 8; nt++) bi[nt] = ff1_b[w * 128 + nt * 16 + p];
        #pragma unroll
        for (int mt = 0; mt < 2; mt++)
            #pragma unroll
            for (int nt = 0; nt < 8; nt++)
                #pragma unroll
                for (int reg = 0; reg < 4; reg++)
                    acc[mt][nt][reg] = fmaxf(acc[mt][nt][reg] + bi[nt], 0.f);
    }

    // pass 5: ff2 + residual + LN + final LN
    stage_acc32(acc, As, w, q, p);
    gemm_pass32(As, Wff2, w, lane, acc);
    {
        float bi[8];
        #pragma unroll
        for (int nt = 0; nt < 8; nt++) bi[nt] = ff2_b[w * 128 + nt * 16 + p];
        #pragma unroll
        for (int mt = 0; mt < 2; mt++)
            #pragma unroll
            for (int nt = 0; nt < 8; nt++)
                #pragma unroll
                for (int reg = 0; reg < 4; reg++)
                    acc[mt][nt][reg] += bi[nt] + x[mt][nt][reg];
    }
    block_ln32(acc, red, tid, w, q, p, ln2g, ln2b);
    block_ln32(acc, red, tid, w, q, p, fng, fnb);

    // CE epilogue (9 classes: 5 + 4), one atomic per block
    #pragma unroll
    for (int c = 0; c < 9; c++) {
        const float* wc = (c < 5) ? (cw0 + (size_t)c * 256) : (cw1 + (size_t)(c - 5) * 256);
        float wv[8];
        #pragma unroll
        for (int nt = 0; nt < 8; nt++) wv[nt] = wc[w * 128 + nt * 16 + p];
        #pragma unroll
        for (int mt = 0; mt < 2; mt++)
            #pragma unroll
            for (int reg = 0; reg < 4; reg++) {
                float s = 0.f;
                #pragma unroll
                for (int nt = 0; nt < 8; nt++) s += acc[mt][nt][reg] * wv[nt];
                s = qred(s);
                if (p == 0) red[(c * 2 + w) * 32 + mt * 16 + q * 4 + reg] = s;
            }
    }
    __syncthreads();
    if (tid < 64) {
        float local = 0.f;
        int grow = m0 + tid;
        if (tid < 32 && grow < M) {
            int y0 = ydata[(size_t)grow * 2 + 0], y1 = ydata[(size_t)grow * 2 + 1];
            float lg[9];
            #pragma unroll
            for (int c = 0; c < 9; c++)
                lg[c] = red[(c * 2) * 32 + tid] + red[(c * 2 + 1) * 32 + tid]
                      + ((c < 5) ? cb0[c] : cb1[c - 5]);
            float mA = -1e30f, mB = -1e30f, tA = 0.f, tB = 0.f;
            #pragma unroll
            for (int c = 0; c < 5; c++) { mA = fmaxf(mA, lg[c]); if (c == y0) tA = lg[c]; }
            #pragma unroll
            for (int c = 0; c < 4; c++) { mB = fmaxf(mB, lg[5 + c]); if (c == y1) tB = lg[5 + c]; }
            float sA = 0.f, sB = 0.f;
            #pragma unroll
            for (int c = 0; c < 5; c++) sA += __expf(lg[c] - mA);
            #pragma unroll
            for (int c = 0; c < 4; c++) sB += __expf(lg[5 + c] - mB);
            local = (mA + logf(sA) - tA) + (mB + logf(sB) - tB);
        }
        for (int o = 32; o; o >>= 1) local += __shfl_down(local, o);
        if (tid == 0) atomicAdd(lossOut, local * invM);
    }
}

// ---------------- fused QK^T + softmax -> bf16 P ----------------

__global__ __launch_bounds__(256) void k_attn_qks(
    const float* __restrict__ qkv, ushort* __restrict__ P)
{
    __shared__ ushort Qs[64 * 32];
    __shared__ ushort Ks[256 * 32];
    int tid = threadIdx.x;
    int wave = tid >> 6, lane = tid & 63;
    int q = lane >> 4, p = lane & 15;
    int m0 = blockIdx.x * 64;
    int z = blockIdx.y, b = z >> 1, h = z & 1;
    size_t qoff = (size_t)b * 768 + h * 128;

    f32x4 acc[16];
    #pragma unroll
    for (int i = 0; i < 16; i++) acc[i] = (f32x4){0.f, 0.f, 0.f, 0.f};

    int sra = tid >> 2, sca = (tid & 3) << 3;
    const float* Arow = qkv + (size_t)(m0 + sra) * 3072 + qoff + sca;
    const float* Wrow = qkv + (size_t)tid * 3072 + qoff + 256;
    ushort* asd = &Qs[sra * 32 + sca];
    ushort* wsd = &Ks[tid * 32];

    for (int k0 = 0; k0 < 128; k0 += 32) {
        float4 a0 = *(const float4*)(Arow + k0);
        float4 a1 = *(const float4*)(Arow + k0 + 4);
        float av[8] = {a0.x, a0.y, a0.z, a0.w, a1.x, a1.y, a1.z, a1.w};
        float wv[32];
        #pragma unroll
        for (int i = 0; i < 8; i++) {
            float4 w4 = *(const float4*)(Wrow + k0 + i * 4);
            wv[i*4+0] = w4.x; wv[i*4+1] = w4.y; wv[i*4+2] = w4.z; wv[i*4+3] = w4.w;
        }
        unsigned au[4], wu[16];
        #pragma unroll
        for (int i = 0; i < 4; i++) au[i] = (unsigned)f2b(av[2*i]) | ((unsigned)f2b(av[2*i+1]) << 16);
        #pragma unroll
        for (int i = 0; i < 16; i++) wu[i] = (unsigned)f2b(wv[2*i]) | ((unsigned)f2b(wv[2*i+1]) << 16);
        __syncthreads();
        ((uint4*)asd)[0] = make_uint4(au[0], au[1], au[2], au[3]);
        ((uint4*)wsd)[0] = make_uint4(wu[0], wu[1], wu[2], wu[3]);
        ((uint4*)(wsd + 8))[0] = make_uint4(wu[4], wu[5], wu[6], wu[7]);
        ((uint4*)(wsd + 16))[0] = make_uint4(wu[8], wu[9], wu[10], wu[11]);
        ((uint4*)(wsd + 24))[0] = make_uint4(wu[12], wu[13], wu[14], wu[15]);
        __syncthreads();

        bf16x8 af = *(const bf16x8*)&Qs[(wave * 16 + p) * 32 + q * 8];
        #pragma unroll
        for (int nt = 0; nt < 16; nt++) {
            bf16x8 bf = *(const bf16x8*)&Ks[(nt * 16 + p) * 32 + q * 8];
            acc[nt] = __builtin_amdgcn_mfma_f32_16x16x32_bf16(af, bf, acc[nt], 0, 0, 0);
        }
    }

    ushort* Pz = P + (size_t)z * 65536;
    #pragma unroll
    for (int reg = 0; reg < 4; reg++) {
        int row = m0 + wave * 16 + q * 4 + reg;
        float v[16]; float mx = -1e30f;
        #pragma unroll
        for (int nt = 0; nt < 16; nt++) {
            int colk = nt * 16 + p;
            float val = (colk <= row) ? acc[nt][reg] * SCALE : -1e30f;
            v[nt] = val; mx = fmaxf(mx, val);
        }
        mx = fmaxf(mx, __shfl_xor(mx, 1)); mx = fmaxf(mx, __shfl_xor(mx, 2));
        mx = fmaxf(mx, __shfl_xor(mx, 4)); mx = fmaxf(mx, __shfl_xor(mx, 8));
        float s = 0.f;
        #pragma unroll
        for (int nt = 0; nt < 16; nt++) {
            int colk = nt * 16 + p;
            float e = (colk <= row) ? __expf(v[nt] - mx) : 0.f;
            v[nt] = e; s += e;
        }
        s += __shfl_xor(s, 1); s += __shfl_xor(s, 2); s += __shfl_xor(s, 4); s += __shfl_xor(s, 8);
        float inv = 1.f / s;
        #pragma unroll
        for (int nt = 0; nt < 16; nt++)
            Pz[(size_t)row * 256 + nt * 16 + p] = f2b(v[nt] * inv);
    }
}

// ---------------- PV: O = P @ V ----------------

__global__ __launch_bounds__(256) void k_attn_pvt(
    const ushort* __restrict__ P, const float* __restrict__ Vt,
    float* __restrict__ out)
{
    __shared__ ushort As[64 * 32];
    __shared__ ushort Bs[128 * 32];
    int tid = threadIdx.x;
    int wave = tid >> 6, lane = tid & 63;
    int q = lane >> 4, p = lane & 15;
    int m0 = blockIdx.x * 64;
    int z = blockIdx.y, b = z >> 1, h = z & 1;

    f32x4 acc[8];
    #pragma unroll
    for (int i = 0; i < 8; i++) acc[i] = (f32x4){0.f, 0.f, 0.f, 0.f};

    int sra = tid >> 2, sca = (tid & 3) << 3;
    const ushort* Prow = P + (size_t)z * 65536 + (size_t)(m0 + sra) * 256 + sca;
    int srb = tid >> 1, scb = (tid & 1) << 4;
    const float* Vrow = Vt + (size_t)z * 32768 + (size_t)srb * 256 + scb;
    ushort* asd = &As[sra * 32 + sca];
    ushort* wsd = &Bs[srb * 32 + scb];

    for (int k0 = 0; k0 < 256; k0 += 32) {
        uint4 pa = *(const uint4*)(Prow + k0);
        float wv[16];
        #pragma unroll
        for (int i = 0; i < 4; i++) {
            float4 w4 = *(const float4*)(Vrow + k0 + i * 4);
            wv[i*4+0] = w4.x; wv[i*4+1] = w4.y; wv[i*4+2] = w4.z; wv[i*4+3] = w4.w;
        }
        unsigned wu[8];
        #pragma unroll
        for (int i = 0; i < 8; i++) wu[i] = (unsigned)f2b(wv[2*i]) | ((unsigned)f2b(wv[2*i+1]) << 16);
        __syncthreads();
        ((uint4*)asd)[0] = pa;
        ((uint4*)wsd)[0] = make_uint4(wu[0], wu[1], wu[2], wu[3]);
        ((uint4*)(wsd + 8))[0] = make_uint4(wu[4], wu[5], wu[6], wu[7]);
        __syncthreads();

        bf16x8 af = *(const bf16x8*)&As[(wave * 16 + p) * 32 + q * 8];
        #pragma unroll
        for (int nt = 0; nt < 8; nt++) {
            bf16x8 bf = *(const bf16x8*)&Bs[(nt * 16 + p) * 32 + q * 8];
            acc[nt] = __builtin_amdgcn_mfma_f32_16x16x32_bf16(af, bf, acc[nt], 0, 0, 0);
        }
    }

    #pragma unroll
    for (int reg = 0; reg < 4; reg++) {
        int s = m0 + wave * 16 + q * 4 + reg;
        #pragma unroll
        for (int nt = 0; nt < 8; nt++) {
            int dh = nt * 16 + p;
            out[(size_t)s * 1024 + (size_t)b * 256 + h * 128 + dh] = acc[nt][reg];
        }
    }
}

// ---------------- generic fp32 GEMM (input projection K=54 only) ----------------

__global__ __launch_bounds__(256) void k_gemm(
    const float* __restrict__ A, const float* __restrict__ W,
    const float* __restrict__ bias, float* __restrict__ C,
    int M, int N, int K, int relu)
{
    __shared__ __align__(16) float As[16][68];
    __shared__ __align__(16) float Ws[16][68];
    int tx = threadIdx.x, ty = threadIdx.y;
    int tid = ty * 16 + tx;
    int m0 = blockIdx.y * 64, n0 = blockIdx.x * 64;
    float acc[4][4] = {{0.f}};
    int r  = tid >> 2;
    int kk = (tid & 3) << 2;
    for (int k0 = 0; k0 < K; k0 += 16) {
        float4 av = make_float4(0.f, 0.f, 0.f, 0.f);
        float4 wv = make_float4(0.f, 0.f, 0.f, 0.f);
        int gm = m0 + r, gk = k0 + kk;
        if (gm < M) {
            float tv[4];
            for (int i = 0; i < 4; i++) tv[i] = (gk + i < K) ? A[(size_t)gm * K + gk + i] : 0.f;
            av = make_float4(tv[0], tv[1], tv[2], tv[3]);
        }
        int gn = n0 + r;
        if (gn < N) {
            float tv[4];
            for (int i = 0; i < 4; i++) tv[i] = (gk + i < K) ? W[(size_t)gn * K + gk + i] : 0.f;
            wv = make_float4(tv[0], tv[1], tv[2], tv[3]);
        }
        As[kk + 0][r] = av.x; As[kk + 1][r] = av.y; As[kk + 2][r] = av.z; As[kk + 3][r] = av.w;
        Ws[kk + 0][r] = wv.x; Ws[kk + 1][r] = wv.y; Ws[kk + 2][r] = wv.z; Ws[kk + 3][r] = wv.w;
        __syncthreads();
        #pragma unroll
        for (int k = 0; k < 16; k++) {
            float4 a4 = *(const float4*)&As[k][ty << 2];
            float4 b4 = *(const float4*)&Ws[k][tx << 2];
            float a[4] = {a4.x, a4.y, a4.z, a4.w};
            float b[4] = {b4.x, b4.y, b4.z, b4.w};
            #pragma unroll
            for (int i = 0; i < 4; i++)
                #pragma unroll
                for (int j = 0; j < 4; j++)
                    acc[i][j] = fmaf(a[i], b[j], acc[i][j]);
        }
        __syncthreads();
    }
    #pragma unroll
    for (int i = 0; i < 4; i++) {
        int gm = m0 + (ty << 2) + i;
        if (gm >= M) continue;
        #pragma unroll
        for (int j = 0; j < 4; j++) {
            int gn = n0 + (tx << 2) + j;
            if (gn >= N) continue;
            float v = acc[i][j] + bias[gn];
            if (relu) v = fmaxf(v, 0.f);
            C[(size_t)gm * N + gn] = v;
        }
    }
}

// ---------------- BatchNorm partial sums ----------------

__global__ __launch_bounds__(256) void k_bn_part(const float* __restrict__ x, float* __restrict__ sums) {
    int t = threadIdx.x;
    int r0 = blockIdx.x * 16;
    float s = 0.f, s2 = 0.f;
    for (int r = r0; r < r0 + 16; r++) {
        float v = x[(size_t)r * 256 + t];
        s += v; s2 += v * v;
    }
    atomicAdd(&sums[t], s);
    atomicAdd(&sums[256 + t], s2);
}

// ---------------- BN-finalize + SELU + positional encoding ----------------

__global__ __launch_bounds__(256) void k_bn_selu_pe(
    const float* __restrict__ x0, const float* __restrict__ sums,
    const float* __restrict__ g, const float* __restrict__ b,
    const int* __restrict__ atom_i, float* __restrict__ out)
{
    int row = blockIdx.x, t = threadIdx.x;
    float m = sums[t] * (1.f / 1024.f);
    float var = sums[256 + t] * (1.f / 1024.f) - m * m;
    float rstd = rsqrtf(var + 1e-5f);
    float v = x0[(size_t)row * 256 + t];
    v = (v - m) * rstd * g[t] + b[t];
    const float SC = 1.0507009873554805f, AL = 1.6732632423543772f;
    v = SC * (v > 0.f ? v : AL * expm1f(v));
    float pos = (float)atom_i[row];
    float freq = expf(-(float)t * (9.210340371976184f / 256.f));
    float ang = pos * freq;
    float pe = (t & 1) ? cosf(ang) : sinf(ang);
    out[(size_t)row * 256 + t] = v + pe;
}

// ---------------- both-layer node cross-attn constant ----------------

__global__ __launch_bounds__(256) void k_cross2(
    const float* __restrict__ z, const float* __restrict__ cqkv_w, const float* __restrict__ cqkv_b,
    const float* __restrict__ co_w, const float* __restrict__ co_b, float* __restrict__ crO)
{
    int m = blockIdx.x, l = blockIdx.y;
    int t = threadIdx.x;
    __shared__ float zs[256], ct[256];
    zs[t] = z[m * 256 + t];
    __syncthreads();
    const float* wv = cqkv_w + (size_t)l * 768 * 256 + 512 * 256 + (size_t)t * 256;
    float a = cqkv_b[l * 768 + 512 + t];
    for (int d = 0; d < 256; d += 4) {
        float4 w4 = *(const float4*)(wv + d);
        a += zs[d] * w4.x + zs[d+1] * w4.y + zs[d+2] * w4.z + zs[d+3] * w4.w;
    }
    ct[t] = a;
    __syncthreads();
    const float* ow = co_w + (size_t)l * 65536 + (size_t)t * 256;
    float o = co_b[l * 256 + t];
    for (int d = 0; d < 256; d += 4) {
        float4 w4 = *(const float4*)(ow + d);
        o += ct[d] * w4.x + ct[d+1] * w4.y + ct[d+2] * w4.z + ct[d+3] * w4.w;
    }
    crO[l * 1024 + m * 256 + t] = o;
}

// ---------------- edge group self-attention ----------------

__global__ __launch_bounds__(256) void k_edge_self_attn(
    const float* __restrict__ qkv, float* __restrict__ out)
{
    int g = blockIdx.x + 1;
    int b = blockIdx.y;
    int gs = min(g, 12);
    int base = (g <= 13) ? g * (g - 1) / 2 : 78 + (g - 13) * 12;
    int h = threadIdx.x >> 7;
    int t = threadIdx.x & 127;
    __shared__ float qs[2][12][128], ks[2][12][128], vs[2][12][128];
    __shared__ float ps[2][12][12];
    for (int i = 0; i < gs; i++) {
        size_t row = ((size_t)(base + i) * BB + b) * 768 + h * 128 + t;
        qs[h][i][t] = qkv[row];
        ks[h][i][t] = qkv[row + 256];
        vs[h][i][t] = qkv[row + 512];
    }
    __syncthreads();
    for (int p = t; p < gs * gs; p += 128) {
        int i = p / gs, j = p - i * gs;
        float acc = 0.f;
        for (int d = 0; d < 128; d++) acc = fmaf(qs[h][i][d], ks[h][j][d], acc);
        ps[h][i][j] = acc * SCALE;
    }
    __syncthreads();
    if (t < gs) {
        float m = -1e30f;
        for (int j = 0; j < gs; j++) m = fmaxf(m, ps[h][t][j]);
        float e[12]; float s = 0.f;
        for (int j = 0; j < gs; j++) { e[j] = expf(ps[h][t][j] - m); s += e[j]; }
        float inv = 1.f / s;
        for (int j = 0; j < gs; j++) ps[h][t][j] = e[j] * inv;
    }
    __syncthreads();
    for (int i = 0; i < gs; i++) {
        float acc = 0.f;
        for (int j = 0; j < gs; j++) acc = fmaf(ps[h][i][j], vs[h][j][t], acc);
        out[((size_t)(base + i) * BB + b) * 256 + h * 128 + t] = acc;
    }
}

// ---------------- gather + build_mem fused ----------------

__global__ __launch_bounds__(256) void k_gather_mem(
    const float* __restrict__ z, const float* __restrict__ nemb,
    const int* __restrict__ idxt, float* __restrict__ etgt, float* __restrict__ memb)
{
    int r = blockIdx.x, t = threadIdx.x;
    if (r < LEB) {
        int e = r >> 2, b = r & 3;
        etgt[(size_t)r * 256 + t] = nemb[((size_t)idxt[e] * 4 + b) * 256 + t];
    } else {
        int rm = r - LEB;
        int m = rm >> 2, b = rm & 3;
        memb[(size_t)rm * 256 + t] = (m == 0) ? z[(size_t)b * 256 + t]
                                              : nemb[((size_t)(m - 1) * 4 + b) * 256 + t];
    }
}

// ---------------- fused node cross-entropy (no dynamic-indexed arrays) ----------------

__global__ __launch_bounds__(256) void k_ce_node(
    const float* __restrict__ emb,
    const float* __restrict__ w0, const float* __restrict__ b0,
    const float* __restrict__ w1, const float* __restrict__ b1,
    const float* __restrict__ w2, const float* __restrict__ b2,
    const int* __restrict__ y, int M, float invM, float* __restrict__ lossOut)
{
    int wave = threadIdx.x >> 6, lane = threadIdx.x & 63;
    int wid = blockIdx.x * 4 + wave;
    float local = 0.f;
    for (int r = wid; r < M; r += gridDim.x * 4) {
        float4 x = ((const float4*)(emb + (size_t)r * 256))[lane];
        float acc[54];
        #pragma unroll
        for (int c = 0; c < 40; c++) {
            float4 wv = ((const float4*)(w0 + (size_t)c * 256))[lane];
            acc[c] = x.x * wv.x + x.y * wv.y + x.z * wv.z + x.w * wv.w;
        }
        #pragma unroll
        for (int c = 0; c < 8; c++) {
            float4 wv = ((const float4*)(w1 + (size_t)c * 256))[lane];
            acc[40 + c] = x.x * wv.x + x.y * wv.y + x.z * wv.z + x.w * wv.w;
        }
        #pragma unroll
        for (int c = 0; c < 6; c++) {
            float4 wv = ((const float4*)(w2 + (size_t)c * 256))[lane];
            acc[48 + c] = x.x * wv.x + x.y * wv.y + x.z * wv.z + x.w * wv.w;
        }
        #pragma unroll
        for (int c = 0; c < 54; c++)
            for (int o = 32; o; o >>= 1) acc[c] += __shfl_down(acc[c], o);
        if (lane == 0) {
            int y0 = y[(size_t)r * 3 + 0], y1 = y[(size_t)r * 3 + 1], y2 = y[(size_t)r * 3 + 2];
            float m0v = -1e30f, m1v = -1e30f, m2v = -1e30f;
            float t0 = 0.f, t1v = 0.f, t2v = 0.f;
            #pragma unroll
            for (int c = 0; c < 40; c++) {
                float v = acc[c] + b0[c];
                acc[c] = v; m0v = fmaxf(m0v, v);
                if (c == y0) t0 = v;
            }
            #pragma unroll
            for (int c = 0; c < 8; c++) {
                float v = acc[40 + c] + b1[c];
                acc[40 + c] = v; m1v = fmaxf(m1v, v);
                if (c == y1) t1v = v;
            }
            #pragma unroll
            for (int c = 0; c < 6; c++) {
                float v = acc[48 + c] + b2[c];
                acc[48 + c] = v; m2v = fmaxf(m2v, v);
                if (c == y2) t2v = v;
            }
            float s0 = 0.f, s1 = 0.f, s2 = 0.f;
            #pragma unroll
            for (int c = 0; c < 40; c++) s0 += __expf(acc[c] - m0v);
            #pragma unroll
            for (int c = 0; c < 8; c++)  s1 += __expf(acc[40 + c] - m1v);
            #pragma unroll
            for (int c = 0; c < 6; c++)  s2 += __expf(acc[48 + c] - m2v);
            local += (m0v + logf(s0) - t0) + (m1v + logf(s1) - t1v) + (m2v + logf(s2) - t2v);
        }
    }
    __shared__ float ls[4];
    if (lane == 0) ls[wave] = local;
    __syncthreads();
    if (threadIdx.x == 0)
        atomicAdd(lossOut, (ls[0] + ls[1] + ls[2] + ls[3]) * invM);
}

// ---------------- host ----------------

extern "C" void kernel_launch(void* const* d_in, const int* in_sizes, int n_in,
                              void* d_out, int out_size, void* d_ws, size_t ws_size,
                              hipStream_t stream)
{
    (void)in_sizes; (void)n_in; (void)out_size; (void)ws_size;
    const float* zin      = (const float*)d_in[0];
    const int*   atom_i   = (const int*)d_in[1];
    const float* atom_x   = (const float*)d_in[2];
    const int*   atom_y   = (const int*)d_in[3];
    const int*   bond_y   = (const int*)d_in[4];
    const float* Wp       = (const float*)d_in[5];
    const float* bp       = (const float*)d_in[6];
    const float* bn_g     = (const float*)d_in[7];
    const float* bn_b     = (const float*)d_in[8];
    const float* nd_qkv_w = (const float*)d_in[9];
    const float* nd_qkv_b = (const float*)d_in[10];
    const float* nd_so_w  = (const float*)d_in[11];
    const float* nd_so_b  = (const float*)d_in[12];
    const float* nd_cqkv_w= (const float*)d_in[13];
    const float* nd_cqkv_b= (const float*)d_in[14];
    const float* nd_co_w  = (const float*)d_in[15];
    const float* nd_co_b  = (const float*)d_in[16];
    const float* nd_ff1_w = (const float*)d_in[17];
    const float* nd_ff1_b = (const float*)d_in[18];
    const float* nd_ff2_w = (const float*)d_in[19];
    const float* nd_ff2_b = (const float*)d_in[20];
    const float* nd_ln_g  = (const float*)d_in[21];
    const float* nd_ln_b  = (const float*)d_in[22];
    const float* nd_fn_g  = (const float*)d_in[23];
    const float* nd_fn_b  = (const float*)d_in[24];
    const float* ed_qkv_w = (const float*)d_in[25];
    const float* ed_qkv_b = (const float*)d_in[26];
    const float* ed_so_w  = (const float*)d_in[27];
    const float* ed_so_b  = (const float*)d_in[28];
    const float* ed_cqkv_w= (const float*)d_in[29];
    const float* ed_cqkv_b= (const float*)d_in[30];
    const float* ed_co_w  = (const float*)d_in[31];
    const float* ed_co_b  = (const float*)d_in[32];
    const float* ed_ff1_w = (const float*)d_in[33];
    const float* ed_ff1_b = (const float*)d_in[34];
    const float* ed_ff2_w = (const float*)d_in[35];
    const float* ed_ff2_b = (const float*)d_in[36];
    const float* ed_ln_g  = (const float*)d_in[37];
    const float* ed_ln_b  = (const float*)d_in[38];
    const float* ed_fn_g  = (const float*)d_in[39];
    const float* ed_fn_b  = (const float*)d_in[40];
    const float* nc0_w = (const float*)d_in[41]; const float* nc0_b = (const float*)d_in[42];
    const float* nc1_w = (const float*)d_in[43]; const float* nc1_b = (const float*)d_in[44];
    const float* nc2_w = (const float*)d_in[45]; const float* nc2_b = (const float*)d_in[46];
    const float* ec0_w = (const float*)d_in[47]; const float* ec0_b = (const float*)d_in[48];
    const float* ec1_w = (const float*)d_in[49]; const float* ec1_b = (const float*)d_in[50];

    float* out = (float*)d_out;

    char* wsb = (char*)d_ws;
    size_t off = 0;
    auto alloc = [&](size_t nbytes) -> void* {
        void* p = (void*)(wsb + off);
        off += (nbytes + 255) / 256 * 256;
        return p;
    };
    float* x0    = (float*)alloc(1024 * 256 * 4);
    float* tgt   = (float*)alloc(1024 * 256 * 4);
    float* nqkv  = (float*)alloc(1024 * 768 * 4);
    float* t1    = (float*)alloc(1024 * 256 * 4);
    float* nemb  = (float*)alloc(1024 * 256 * 4);
    float* bnsums= (float*)alloc(512 * 4);
    float* crO   = (float*)alloc(2 * 1024 * 4);
    float* memb  = (float*)alloc(1028 * 256 * 4);
    float* KV    = (float*)alloc(1028 * 512 * 4);
    ushort* Sb   = (ushort*)alloc(8 * 65536 * 2);
    float* Vt    = (float*)alloc(8 * 32768 * 4);
    float* etgt  = (float*)alloc((size_t)LEB * 256 * 4);
    float* eqkv  = (float*)alloc((size_t)LEB * 768 * 4);
    float* et1   = (float*)alloc((size_t)LEB * 256 * 4);
    int* grp   = (int*)alloc(LE * 4);
    int* idxt  = (int*)alloc(LE * 4);
    ushort* wpk = (ushort*)alloc((size_t)TOTFRAG * 512 * 2);

    PackArgs pa;
    pa.src[0] = nd_qkv_w;              pa.src[1] = nd_qkv_w + 768 * 256;
    pa.src[2] = nd_so_w;               pa.src[3] = nd_so_w + 65536;
    pa.src[4] = nd_ff1_w;              pa.src[5] = nd_ff1_w + 65536;
    pa.src[6] = nd_ff2_w;              pa.src[7] = nd_ff2_w + 65536;
    pa.src[8] = ed_qkv_w;              pa.src[9] = ed_cqkv_w;
    pa.src[10] = ed_so_w;              pa.src[11] = ed_co_w;
    pa.src[12] = ed_ff1_w;             pa.src[13] = ed_ff2_w;
    int fs[NPACK + 1] = {0, 384, 768, 896, 1024, 1152, 1280, 1408, 1536, 1920, 2304, 2432, 2560, 2688, 2816};
    for (int i = 0; i <= NPACK; i++) pa.fs[i] = fs[i];
    auto wp = [&](int i) -> const ushort* { return wpk + (size_t)fs[i] * 512; };

    k_init<<<13, 256, 0, stream>>>(out, bnsums, grp, idxt);
    k_prep<<<(TOTFRAG * 64 + 255) / 256, 256, 0, stream>>>(pa, wpk);

    // node input: projection + BN + SELU + PE
    k_gemm<<<dim3(4, 16), dim3(16, 16), 0, stream>>>(atom_x, Wp, bp, x0, 1024, 256, 54, 0);
    k_bn_part<<<64, 256, 0, stream>>>(x0, bnsums);
    k_bn_selu_pe<<<1024, 256, 0, stream>>>(x0, bnsums, bn_g, bn_b, atom_i, tgt);

    // both layers' cross-attn constant
    k_cross2<<<dim3(4, 2), 256, 0, stream>>>(zin, nd_cqkv_w, nd_cqkv_b, nd_co_w, nd_co_b, crO);

    // node decoder: 2 layers (4 dispatches each)
    for (int l = 0; l < 2; l++) {
        k_gemm_w<<<dim3(3, 16), 256, 0, stream>>>(tgt, wp(l), nd_qkv_b + l * 768,
                                                  nqkv, Vt, 1024, 768, 3, 0);
        k_attn_qks<<<dim3(4, 8), 256, 0, stream>>>(nqkv, Sb);
        k_attn_pvt<<<dim3(4, 8), 256, 0, stream>>>(Sb, Vt, t1);
        k_node_mega<<<32, 128, 0, stream>>>(
            t1, tgt, crO + l * 1024,
            wp(2 + l), nd_so_b + l * 256,
            nd_ln_g + (l * 3 + 0) * 256, nd_ln_b + (l * 3 + 0) * 256,
            nd_ln_g + (l * 3 + 1) * 256, nd_ln_b + (l * 3 + 1) * 256,
            wp(4 + l), nd_ff1_b + l * 256,
            wp(6 + l), nd_ff2_b + l * 256,
            nd_ln_g + (l * 3 + 2) * 256, nd_ln_b + (l * 3 + 2) * 256,
            nd_fn_g, nd_fn_b,
            (l == 0) ? tgt : nemb, 1024, (l == 1) ? 1 : 0);
    }

    // node losses
    k_ce_node<<<128, 256, 0, stream>>>(nemb, nc0_w, nc0_b, nc1_w, nc1_b, nc2_w, nc2_b,
                                       atom_y, 1024, 1.f / 1024.f, out);

    // edge path
    k_gather_mem<<<LEB + 1028, 256, 0, stream>>>(zin, nemb, idxt, etgt, memb);
    k_gemm_w<<<dim3(2, 17), 256, 0, stream>>>(memb, wp(9) + 128 * 512, ed_cqkv_b + 256,
                                              KV, nullptr, 1028, 512, 0, 0);
    k_gemm_w<<<dim3(3, 188), 256, 0, stream>>>(etgt, wp(8), ed_qkv_b,
                                               eqkv, nullptr, LEB, 768, 0, 0);
    k_edge_self_attn<<<dim3(255, 4), 256, 0, stream>>>(eqkv, et1);
    k_edge_mega<<<(LEB + 31) / 32, 128, 0, stream>>>(
        et1, etgt,
        wp(10), ed_so_b, ed_ln_g, ed_ln_b,
        wp(9), ed_cqkv_b, KV, grp,
        wp(11), ed_co_b, ed_ln_g + 256, ed_ln_b + 256,
        wp(12), ed_ff1_b,
        wp(13), ed_ff2_b, ed_ln_g + 512, ed_ln_b + 512,
        ed_fn_g, ed_fn_b,
        bond_y, ec0_w, ec0_b, ec1_w, ec1_b,
        out, 1.f / (float)LEB, LEB);
}

// Round 10
// 511.562 us; speedup vs baseline: 1.1740x; 1.1630x over previous
//
#include <hip/hip_runtime.h>
#include <math.h>

#define SS 256
#define BB 4
#define HH 256
#define LE 2994
#define LEB (LE*BB)
#define SCALE 0.08838834764831845f  // 1/sqrt(128)

typedef __attribute__((ext_vector_type(8))) short bf16x8;
typedef __attribute__((ext_vector_type(4))) float f32x4;

__device__ inline ushort f2b(float f) {   // fp32 -> bf16 RNE
    unsigned u = __float_as_uint(f);
    u += 0x7FFFu + ((u >> 16) & 1u);
    return (ushort)(u >> 16);
}

__device__ inline float qred(float x) {   // sum across 16 lanes of a quarter-wave (broadcast)
    x += __shfl_xor(x, 1); x += __shfl_xor(x, 2);
    x += __shfl_xor(x, 4); x += __shfl_xor(x, 8);
    return x;
}

// ---------------- init ----------------

__global__ void k_init(float* __restrict__ out, float* __restrict__ bnsums,
                       int* __restrict__ grp, int* __restrict__ idxt) {
    int bid = blockIdx.x, t = threadIdx.x;
    if (bid == 0) {
        if (t == 0) out[0] = 0.f;
        bnsums[t] = 0.f; bnsums[256 + t] = 0.f;
        return;
    }
    int e = (bid - 1) * 256 + t;
    if (e >= LE) return;
    int g, pos;
    if (e < 78) {
        g = (int)((1.0f + sqrtf(8.0f * (float)e + 1.0f)) * 0.5f);
        while (g * (g - 1) / 2 > e) g--;
        while ((g + 1) * g / 2 <= e) g++;
        pos = e - g * (g - 1) / 2;
        idxt[e] = pos;
    } else {
        int r = e - 78;
        g = 13 + r / 12;
        pos = r % 12;
        idxt[e] = g - 12 + pos;
    }
    grp[e] = g;
}

// ---------------- weight pre-pack ----------------

#define NPACK 14
#define TOTFRAG 2816
struct PackArgs { const float* src[NPACK]; int fs[NPACK + 1]; };

__global__ __launch_bounds__(256) void k_prep(PackArgs pa, ushort* __restrict__ dst) {
    int wid = (blockIdx.x * 256 + threadIdx.x) >> 6;
    int lane = threadIdx.x & 63;
    if (wid >= TOTFRAG) return;
    int i = 0;
    while (pa.fs[i + 1] <= wid) i++;
    int f = wid - pa.fs[i];
    int tn = f >> 3, tk = f & 7;
    int q = lane >> 4, p = lane & 15;
    const float* s = pa.src[i] + (size_t)(tn * 16 + p) * 256 + tk * 32 + q * 8;
    float4 a0 = *(const float4*)s, a1 = *(const float4*)(s + 4);
    uint4 o = make_uint4(f2b(a0.x) | ((unsigned)f2b(a0.y) << 16),
                         f2b(a0.z) | ((unsigned)f2b(a0.w) << 16),
                         f2b(a1.x) | ((unsigned)f2b(a1.y) << 16),
                         f2b(a1.z) | ((unsigned)f2b(a1.w) << 16));
    *(uint4*)&dst[(size_t)wid * 512 + lane * 8] = o;
}

// ---------------- plain bf16 GEMM with packed W (modes 0/3), 64-row x 256-col tiles ----------------

__global__ __launch_bounds__(256) void k_gemm_w(
    const float* __restrict__ A, const ushort* __restrict__ Wp,
    const float* __restrict__ bias, float* __restrict__ C, float* __restrict__ Vt,
    int M, int N, int mode, int relu)
{
    __shared__ ushort As[32 * 512];
    int tid = threadIdx.x;
    int w = tid >> 6, lane = tid & 63;
    int q = lane >> 4, p = lane & 15;
    int m0 = blockIdx.y * 64, n0 = blockIdx.x * 256;

    {
        int r = tid >> 2;
        int cbase = (tid & 3) * 64;
        int gm = m0 + r;
        const float* Ar = A + (size_t)gm * 256 + cbase;
        bool ok = gm < M;
        #pragma unroll
        for (int j = 0; j < 8; j++) {
            int c = cbase + j * 8;
            float4 a0, a1;
            if (ok) { a0 = *(const float4*)(Ar + j * 8); a1 = *(const float4*)(Ar + j * 8 + 4); }
            else { a0 = make_float4(0.f, 0.f, 0.f, 0.f); a1 = a0; }
            uint4 o = make_uint4(f2b(a0.x) | ((unsigned)f2b(a0.y) << 16),
                                 f2b(a0.z) | ((unsigned)f2b(a0.w) << 16),
                                 f2b(a1.x) | ((unsigned)f2b(a1.y) << 16),
                                 f2b(a1.z) | ((unsigned)f2b(a1.w) << 16));
            int frag = (r >> 4) * 8 + (c >> 5);
            int fl = ((c >> 3) & 3) * 16 + (r & 15);
            *(uint4*)&As[frag * 512 + fl * 8] = o;
        }
    }
    __syncthreads();

    f32x4 acc[4][4];
    #pragma unroll
    for (int i = 0; i < 4; i++)
        #pragma unroll
        for (int j = 0; j < 4; j++) acc[i][j] = (f32x4){0.f, 0.f, 0.f, 0.f};

    int nw = n0 + w * 64;
    const ushort* Wb = Wp + (size_t)(nw >> 4) * 4096;

    #pragma unroll
    for (int kt = 0; kt < 8; kt++) {
        bf16x8 afr[4], wfr[4];
        #pragma unroll
        for (int mt = 0; mt < 4; mt++)
            afr[mt] = *(const bf16x8*)&As[(mt * 8 + kt) * 512 + lane * 8];
        #pragma unroll
        for (int nt = 0; nt < 4; nt++)
            wfr[nt] = *(const bf16x8*)&Wb[(size_t)(nt * 8 + kt) * 512 + lane * 8];
        #pragma unroll
        for (int mt = 0; mt < 4; mt++)
            #pragma unroll
            for (int nt = 0; nt < 4; nt++)
                acc[mt][nt] = __builtin_amdgcn_mfma_f32_16x16x32_bf16(afr[mt], wfr[nt], acc[mt][nt], 0, 0, 0);
    }

    float bi[4]; int col[4];
    #pragma unroll
    for (int nt = 0; nt < 4; nt++) { col[nt] = nw + nt * 16 + p; bi[nt] = bias[col[nt]]; }
    #pragma unroll
    for (int mt = 0; mt < 4; mt++)
        #pragma unroll
        for (int reg = 0; reg < 4; reg++) {
            int grow = m0 + mt * 16 + q * 4 + reg;
            if (grow >= M) continue;
            #pragma unroll
            for (int nt = 0; nt < 4; nt++) {
                float v = acc[mt][nt][reg] + bi[nt];
                if (relu) v = fmaxf(v, 0.f);
                if (mode == 3) {
                    if (col[nt] < 512) {
                        C[(size_t)grow * 768 + col[nt]] = v;
                    } else {
                        int hh = (col[nt] - 512) >> 7, dh = (col[nt] - 512) & 127;
                        int zz = (grow & 3) * 2 + hh;
                        Vt[(size_t)zz * 32768 + (size_t)dh * 256 + (grow >> 2)] = v;
                    }
                } else {
                    C[(size_t)grow * N + col[nt]] = v;
                }
            }
        }
}

// ---------------- 32-row / 4-wave pipeline building blocks ----------------
// Wave w handles cols w*64 + nt*16 + p (nt<4); rows mt*16 + q*4 + reg (mt<2).

__device__ inline void stageA_256(const float* __restrict__ A, int M, int m0, int tid,
                                  ushort* __restrict__ As) {
    int r = tid >> 3;
    int cbase = (tid & 7) * 32;
    int gm = m0 + r;
    const float* Ar = A + (size_t)gm * 256 + cbase;
    bool ok = gm < M;
    #pragma unroll
    for (int j = 0; j < 4; j++) {
        int c = cbase + j * 8;
        float4 a0, a1;
        if (ok) { a0 = *(const float4*)(Ar + j * 8); a1 = *(const float4*)(Ar + j * 8 + 4); }
        else { a0 = make_float4(0.f, 0.f, 0.f, 0.f); a1 = a0; }
        uint4 o = make_uint4(f2b(a0.x) | ((unsigned)f2b(a0.y) << 16),
                             f2b(a0.z) | ((unsigned)f2b(a0.w) << 16),
                             f2b(a1.x) | ((unsigned)f2b(a1.y) << 16),
                             f2b(a1.z) | ((unsigned)f2b(a1.w) << 16));
        int frag = (r >> 4) * 8 + (c >> 5);
        int fl = ((c >> 3) & 3) * 16 + (r & 15);
        *(uint4*)&As[frag * 512 + fl * 8] = o;
    }
    __syncthreads();
}

__device__ inline void gemm_pass4(const ushort* __restrict__ As, const ushort* __restrict__ Wq,
                                  int w, int lane, f32x4 (&acc)[2][4]) {
    #pragma unroll
    for (int mt = 0; mt < 2; mt++)
        #pragma unroll
        for (int nt = 0; nt < 4; nt++) acc[mt][nt] = (f32x4){0.f, 0.f, 0.f, 0.f};
    #pragma unroll
    for (int kt = 0; kt < 8; kt++) {
        bf16x8 a0 = *(const bf16x8*)&As[kt * 512 + lane * 8];
        bf16x8 a1 = *(const bf16x8*)&As[(8 + kt) * 512 + lane * 8];
        #pragma unroll
        for (int nt = 0; nt < 4; nt++) {
            bf16x8 wf = *(const bf16x8*)&Wq[(size_t)((w * 4 + nt) * 8 + kt) * 512 + lane * 8];
            acc[0][nt] = __builtin_amdgcn_mfma_f32_16x16x32_bf16(a0, wf, acc[0][nt], 0, 0, 0);
            acc[1][nt] = __builtin_amdgcn_mfma_f32_16x16x32_bf16(a1, wf, acc[1][nt], 0, 0, 0);
        }
    }
}

__device__ inline void stage_acc4(const f32x4 (&acc)[2][4], ushort* __restrict__ As,
                                  int w, int q, int p) {
    __syncthreads();   // all waves done reading As from previous pass
    #pragma unroll
    for (int mt = 0; mt < 2; mt++)
        #pragma unroll
        for (int nt = 0; nt < 4; nt++)
            #pragma unroll
            for (int reg = 0; reg < 4; reg++)
                As[(mt * 8 + w * 2 + (nt >> 1)) * 512 +
                   (((nt * 2 + (p >> 3)) & 3) * 16 + q * 4 + reg) * 8 + (p & 7)] =
                    f2b(acc[mt][nt][reg]);
    __syncthreads();
}

__device__ inline void block_ln4(f32x4 (&acc)[2][4], float* __restrict__ red,
                                 int tid, int w, int q, int p,
                                 const float* __restrict__ g, const float* __restrict__ b) {
    float gg[4], bb[4];
    #pragma unroll
    for (int nt = 0; nt < 4; nt++) { int col = w * 64 + nt * 16 + p; gg[nt] = g[col]; bb[nt] = b[col]; }
    #pragma unroll
    for (int mt = 0; mt < 2; mt++)
        #pragma unroll
        for (int reg = 0; reg < 4; reg++) {
            float s = acc[mt][0][reg] + acc[mt][1][reg] + acc[mt][2][reg] + acc[mt][3][reg];
            s = qred(s);
            if (p == 0) red[w * 32 + mt * 16 + q * 4 + reg] = s;
        }
    __syncthreads();
    if (tid < 32) red[128 + tid] = (red[tid] + red[32 + tid] + red[64 + tid] + red[96 + tid]) * (1.f / 256.f);
    __syncthreads();
    #pragma unroll
    for (int mt = 0; mt < 2; mt++)
        #pragma unroll
        for (int reg = 0; reg < 4; reg++) {
            int lr = mt * 16 + q * 4 + reg;
            float mean = red[128 + lr];
            float sq = 0.f;
            #pragma unroll
            for (int nt = 0; nt < 4; nt++) {
                acc[mt][nt][reg] -= mean;
                sq += acc[mt][nt][reg] * acc[mt][nt][reg];
            }
            sq = qred(sq);
            if (p == 0) red[w * 32 + lr] = sq;
        }
    __syncthreads();
    if (tid < 32) red[128 + tid] = rsqrtf((red[tid] + red[32 + tid] + red[64 + tid] + red[96 + tid]) * (1.f / 256.f) + 1e-5f);
    __syncthreads();
    #pragma unroll
    for (int mt = 0; mt < 2; mt++)
        #pragma unroll
        for (int reg = 0; reg < 4; reg++) {
            float rstd = red[128 + mt * 16 + q * 4 + reg];
            #pragma unroll
            for (int nt = 0; nt < 4; nt++)
                acc[mt][nt][reg] = acc[mt][nt][reg] * rstd * gg[nt] + bb[nt];
        }
    __syncthreads();
}

// ---------------- node mega: so+LN, +crO+LN, ff1, ff2+LN(+final LN) ----------------

__global__ __launch_bounds__(256) void k_node_mega(
    const float* __restrict__ t1, const float* __restrict__ tgt,
    const float* __restrict__ crO,
    const ushort* __restrict__ Wso, const float* __restrict__ so_b,
    const float* __restrict__ ln0g, const float* __restrict__ ln0b,
    const float* __restrict__ ln1g, const float* __restrict__ ln1b,
    const ushort* __restrict__ Wff1, const float* __restrict__ ff1_b,
    const ushort* __restrict__ Wff2, const float* __restrict__ ff2_b,
    const float* __restrict__ ln2g, const float* __restrict__ ln2b,
    const float* __restrict__ fng, const float* __restrict__ fnb,
    float* __restrict__ outp, int M, int finalln)
{
    __shared__ ushort As[16 * 512];
    __shared__ float red[160];
    int tid = threadIdx.x;
    int w = tid >> 6, lane = tid & 63, q = lane >> 4, p = lane & 15;
    int m0 = blockIdx.x * 32;

    float x[2][4][4];
    f32x4 acc[2][4];

    stageA_256(t1, M, m0, tid, As);
    #pragma unroll
    for (int mt = 0; mt < 2; mt++)
        #pragma unroll
        for (int reg = 0; reg < 4; reg++) {
            int row = m0 + mt * 16 + q * 4 + reg;
            bool ok = row < M;
            #pragma unroll
            for (int nt = 0; nt < 4; nt++)
                x[mt][nt][reg] = ok ? tgt[(size_t)row * 256 + w * 64 + nt * 16 + p] : 0.f;
        }

    // pass 1: self-out + residual + LN
    gemm_pass4(As, Wso, w, lane, acc);
    {
        float bi[4];
        #pragma unroll
        for (int nt = 0; nt < 4; nt++) bi[nt] = so_b[w * 64 + nt * 16 + p];
        #pragma unroll
        for (int mt = 0; mt < 2; mt++)
            #pragma unroll
            for (int nt = 0; nt < 4; nt++)
                #pragma unroll
                for (int reg = 0; reg < 4; reg++)
                    acc[mt][nt][reg] += bi[nt] + x[mt][nt][reg];
    }
    block_ln4(acc, red, tid, w, q, p, ln0g, ln0b);

    // + crO (broadcast over batch) + LN
    #pragma unroll
    for (int mt = 0; mt < 2; mt++)
        #pragma unroll
        for (int reg = 0; reg < 4; reg++) {
            int row = m0 + mt * 16 + q * 4 + reg;
            int b = row & 3;
            #pragma unroll
            for (int nt = 0; nt < 4; nt++)
                acc[mt][nt][reg] += crO[b * 256 + w * 64 + nt * 16 + p];
        }
    block_ln4(acc, red, tid, w, q, p, ln1g, ln1b);

    // save residual for ff
    #pragma unroll
    for (int mt = 0; mt < 2; mt++)
        #pragma unroll
        for (int nt = 0; nt < 4; nt++)
            #pragma unroll
            for (int reg = 0; reg < 4; reg++)
                x[mt][nt][reg] = acc[mt][nt][reg];

    // pass 2: ff1 + relu
    stage_acc4(acc, As, w, q, p);
    gemm_pass4(As, Wff1, w, lane, acc);
    {
        float bi[4];
        #pragma unroll
        for (int nt = 0; nt < 4; nt++) bi[nt] = ff1_b[w * 64 + nt * 16 + p];
        #pragma unroll
        for (int mt = 0; mt < 2; mt++)
            #pragma unroll
            for (int nt = 0; nt < 4; nt++)
                #pragma unroll
                for (int reg = 0; reg < 4; reg++)
                    acc[mt][nt][reg] = fmaxf(acc[mt][nt][reg] + bi[nt], 0.f);
    }

    // pass 3: ff2 + residual + LN (+final LN)
    stage_acc4(acc, As, w, q, p);
    gemm_pass4(As, Wff2, w, lane, acc);
    {
        float bi[4];
        #pragma unroll
        for (int nt = 0; nt < 4; nt++) bi[nt] = ff2_b[w * 64 + nt * 16 + p];
        #pragma unroll
        for (int mt = 0; mt < 2; mt++)
            #pragma unroll
            for (int nt = 0; nt < 4; nt++)
                #pragma unroll
                for (int reg = 0; reg < 4; reg++)
                    acc[mt][nt][reg] += bi[nt] + x[mt][nt][reg];
    }
    block_ln4(acc, red, tid, w, q, p, ln2g, ln2b);
    if (finalln) block_ln4(acc, red, tid, w, q, p, fng, fnb);

    #pragma unroll
    for (int mt = 0; mt < 2; mt++)
        #pragma unroll
        for (int reg = 0; reg < 4; reg++) {
            int row = m0 + mt * 16 + q * 4 + reg;
            if (row >= M) continue;
            #pragma unroll
            for (int nt = 0; nt < 4; nt++)
                outp[(size_t)row * 256 + w * 64 + nt * 16 + p] = acc[mt][nt][reg];
        }
}

// ---------------- edge mega: so+LN, crossQ+2key-attn, co+LN, ff1, ff2+LN+finalLN+CE ----------------

__global__ __launch_bounds__(256) void k_edge_mega(
    const float* __restrict__ et1, const float* __restrict__ etgt,
    const ushort* __restrict__ Wso, const float* __restrict__ so_b,
    const float* __restrict__ ln0g, const float* __restrict__ ln0b,
    const ushort* __restrict__ Wcq, const float* __restrict__ cq_b,
    const float* __restrict__ KV, const int* __restrict__ grp,
    const ushort* __restrict__ Wco, const float* __restrict__ co_b,
    const float* __restrict__ ln1g, const float* __restrict__ ln1b,
    const ushort* __restrict__ Wff1, const float* __restrict__ ff1_b,
    const ushort* __restrict__ Wff2, const float* __restrict__ ff2_b,
    const float* __restrict__ ln2g, const float* __restrict__ ln2b,
    const float* __restrict__ fng, const float* __restrict__ fnb,
    const int* __restrict__ ydata,
    const float* __restrict__ cw0, const float* __restrict__ cb0,
    const float* __restrict__ cw1, const float* __restrict__ cb1,
    float* __restrict__ lossOut, float invM, int M)
{
    __shared__ ushort As[16 * 512];
    __shared__ float red[1152];
    int tid = threadIdx.x;
    int w = tid >> 6, lane = tid & 63, q = lane >> 4, p = lane & 15;
    int m0 = blockIdx.x * 32;

    float x[2][4][4];
    f32x4 acc[2][4];

    stageA_256(et1, M, m0, tid, As);
    #pragma unroll
    for (int mt = 0; mt < 2; mt++)
        #pragma unroll
        for (int reg = 0; reg < 4; reg++) {
            int row = m0 + mt * 16 + q * 4 + reg;
            bool ok = row < M;
            #pragma unroll
            for (int nt = 0; nt < 4; nt++)
                x[mt][nt][reg] = ok ? etgt[(size_t)row * 256 + w * 64 + nt * 16 + p] : 0.f;
        }

    // pass 1: self-out + residual + LN  -> x (tgt1)
    gemm_pass4(As, Wso, w, lane, acc);
    {
        float bi[4];
        #pragma unroll
        for (int nt = 0; nt < 4; nt++) bi[nt] = so_b[w * 64 + nt * 16 + p];
        #pragma unroll
        for (int mt = 0; mt < 2; mt++)
            #pragma unroll
            for (int nt = 0; nt < 4; nt++)
                #pragma unroll
                for (int reg = 0; reg < 4; reg++)
                    acc[mt][nt][reg] += bi[nt] + x[mt][nt][reg];
    }
    block_ln4(acc, red, tid, w, q, p, ln0g, ln0b);
    #pragma unroll
    for (int mt = 0; mt < 2; mt++)
        #pragma unroll
        for (int nt = 0; nt < 4; nt++)
            #pragma unroll
            for (int reg = 0; reg < 4; reg++)
                x[mt][nt][reg] = acc[mt][nt][reg];

    // pass 2: cross q projection + 2-key attention. head h = w>>1; dim d = (w&1)*64 + nt*16 + p.
    stage_acc4(acc, As, w, q, p);
    gemm_pass4(As, Wcq, w, lane, acc);
    {
        int h = w >> 1;
        float bi[4];
        #pragma unroll
        for (int nt = 0; nt < 4; nt++) bi[nt] = cq_b[w * 64 + nt * 16 + p];
        #pragma unroll
        for (int mt = 0; mt < 2; mt++)
            #pragma unroll
            for (int reg = 0; reg < 4; reg++) {
                int lr = mt * 16 + q * 4 + reg;
                int row = m0 + lr;
                bool ok = row < M;
                int b = row & 3;
                int g = ok ? grp[row >> 2] : 0;
                const float* K0 = KV + (size_t)b * 512 + h * 128;
                const float* K1 = KV + ((size_t)(g + 1) * 4 + b) * 512 + h * 128;
                float s0 = 0.f, s1 = 0.f;
                #pragma unroll
                for (int nt = 0; nt < 4; nt++) {
                    float qv = acc[mt][nt][reg] + bi[nt];
                    int d = (w & 1) * 64 + nt * 16 + p;
                    s0 += qv * K0[d]; s1 += qv * K1[d];
                }
                s0 = qred(s0); s1 = qred(s1);
                if (p == 0) { red[(w * 32 + lr) * 2 + 0] = s0; red[(w * 32 + lr) * 2 + 1] = s1; }
            }
        __syncthreads();
        if (tid < 64) {
            int hh = tid >> 5, lr = tid & 31;
            float p0 = (red[((hh * 2) * 32 + lr) * 2 + 0] + red[((hh * 2 + 1) * 32 + lr) * 2 + 0]) * SCALE;
            float p1 = (red[((hh * 2) * 32 + lr) * 2 + 1] + red[((hh * 2 + 1) * 32 + lr) * 2 + 1]) * SCALE;
            float mx = fmaxf(p0, p1);
            float e0 = __expf(p0 - mx), e1 = __expf(p1 - mx);
            float inv = 1.f / (e0 + e1);
            red[256 + (hh * 32 + lr) * 2 + 0] = e0 * inv;
            red[256 + (hh * 32 + lr) * 2 + 1] = e1 * inv;
        }
        __syncthreads();
        #pragma unroll
        for (int mt = 0; mt < 2; mt++)
            #pragma unroll
            for (int reg = 0; reg < 4; reg++) {
                int lr = mt * 16 + q * 4 + reg;
                int row = m0 + lr;
                bool ok = row < M;
                int b = row & 3;
                int g = ok ? grp[row >> 2] : 0;
                float e0 = red[256 + (h * 32 + lr) * 2 + 0];
                float e1 = red[256 + (h * 32 + lr) * 2 + 1];
                const float* V0 = KV + (size_t)b * 512 + 256 + h * 128;
                const float* V1 = KV + ((size_t)(g + 1) * 4 + b) * 512 + 256 + h * 128;
                #pragma unroll
                for (int nt = 0; nt < 4; nt++) {
                    int d = (w & 1) * 64 + nt * 16 + p;
                    acc[mt][nt][reg] = e0 * V0[d] + e1 * V1[d];
                }
            }
        __syncthreads();
    }

    // pass 3: cross-out + residual + LN -> x (tgt2)
    stage_acc4(acc, As, w, q, p);
    gemm_pass4(As, Wco, w, lane, acc);
    {
        float bi[4];
        #pragma unroll
        for (int nt = 0; nt < 4; nt++) bi[nt] = co_b[w * 64 + nt * 16 + p];
        #pragma unroll
        for (int mt = 0; mt < 2; mt++)
            #pragma unroll
            for (int nt = 0; nt < 4; nt++)
                #pragma unroll
                for (int reg = 0; reg < 4; reg++)
                    acc[mt][nt][reg] += bi[nt] + x[mt][nt][reg];
    }
    block_ln4(acc, red, tid, w, q, p, ln1g, ln1b);
    #pragma unroll
    for (int mt = 0; mt < 2; mt++)
        #pragma unroll
        for (int nt = 0; nt < 4; nt++)
            #pragma unroll
            for (int reg = 0; reg < 4; reg++)
                x[mt][nt][reg] = acc[mt][nt][reg];

    // pass 4: ff1 + relu
    stage_acc4(acc, As, w, q, p);
    gemm_pass4(As, Wff1, w, lane, acc);
    {
        float bi[4];
        #pragma unroll
        for (int nt = 0; nt < 4; nt++) bi[nt] = ff1_b[w * 64 + nt * 16 + p];
        #pragma unroll
        for (int mt = 0; mt < 2; mt++)
            #pragma unroll
            for (int nt = 0; nt < 4; nt++)
                #pragma unroll
                for (int reg = 0; reg < 4; reg++)
                    acc[mt][nt][reg] = fmaxf(acc[mt][nt][reg] + bi[nt], 0.f);
    }

    // pass 5: ff2 + residual + LN + final LN
    stage_acc4(acc, As, w, q, p);
    gemm_pass4(As, Wff2, w, lane, acc);
    {
        float bi[4];
        #pragma unroll
        for (int nt = 0; nt < 4; nt++) bi[nt] = ff2_b[w * 64 + nt * 16 + p];
        #pragma unroll
        for (int mt = 0; mt < 2; mt++)
            #pragma unroll
            for (int nt = 0; nt < 4; nt++)
                #pragma unroll
                for (int reg = 0; reg < 4; reg++)
                    acc[mt][nt][reg] += bi[nt] + x[mt][nt][reg];
    }
    block_ln4(acc, red, tid, w, q, p, ln2g, ln2b);
    block_ln4(acc, red, tid, w, q, p, fng, fnb);

    // CE epilogue (9 classes: 5 + 4), one atomic per block
    #pragma unroll
    for (int c = 0; c < 9; c++) {
        const float* wc = (c < 5) ? (cw0 + (size_t)c * 256) : (cw1 + (size_t)(c - 5) * 256);
        float wv[4];
        #pragma unroll
        for (int nt = 0; nt < 4; nt++) wv[nt] = wc[w * 64 + nt * 16 + p];
        #pragma unroll
        for (int mt = 0; mt < 2; mt++)
            #pragma unroll
            for (int reg = 0; reg < 4; reg++) {
                float s = acc[mt][0][reg] * wv[0] + acc[mt][1][reg] * wv[1]
                        + acc[mt][2][reg] * wv[2] + acc[mt][3][reg] * wv[3];
                s = qred(s);
                if (p == 0) red[(c * 4 + w) * 32 + mt * 16 + q * 4 + reg] = s;
            }
    }
    __syncthreads();
    if (tid < 32) {
        float local = 0.f;
        int grow = m0 + tid;
        if (grow < M) {
            int y0 = ydata[(size_t)grow * 2 + 0], y1 = ydata[(size_t)grow * 2 + 1];
            float lg[9];
            #pragma unroll
            for (int c = 0; c < 9; c++)
                lg[c] = red[(c * 4 + 0) * 32 + tid] + red[(c * 4 + 1) * 32 + tid]
                      + red[(c * 4 + 2) * 32 + tid] + red[(c * 4 + 3) * 32 + tid]
                      + ((c < 5) ? cb0[c] : cb1[c - 5]);
            float mA = -1e30f, mB = -1e30f, tA = 0.f, tB = 0.f;
            #pragma unroll
            for (int c = 0; c < 5; c++) { mA = fmaxf(mA, lg[c]); if (c == y0) tA = lg[c]; }
            #pragma unroll
            for (int c = 0; c < 4; c++) { mB = fmaxf(mB, lg[5 + c]); if (c == y1) tB = lg[5 + c]; }
            float sA = 0.f, sB = 0.f;
            #pragma unroll
            for (int c = 0; c < 5; c++) sA += __expf(lg[c] - mA);
            #pragma unroll
            for (int c = 0; c < 4; c++) sB += __expf(lg[5 + c] - mB);
            local = (mA + logf(sA) - tA) + (mB + logf(sB) - tB);
        }
        for (int o = 16; o; o >>= 1) local += __shfl_down(local, o);
        if (tid == 0) atomicAdd(lossOut, local * invM);
    }
}

// ---------------- fused QK^T + softmax -> bf16 P ----------------

__global__ __launch_bounds__(256) void k_attn_qks(
    const float* __restrict__ qkv, ushort* __restrict__ P)
{
    __shared__ ushort Qs[64 * 32];
    __shared__ ushort Ks[256 * 32];
    int tid = threadIdx.x;
    int wave = tid >> 6, lane = tid & 63;
    int q = lane >> 4, p = lane & 15;
    int m0 = blockIdx.x * 64;
    int z = blockIdx.y, b = z >> 1, h = z & 1;
    size_t qoff = (size_t)b * 768 + h * 128;

    f32x4 acc[16];
    #pragma unroll
    for (int i = 0; i < 16; i++) acc[i] = (f32x4){0.f, 0.f, 0.f, 0.f};

    int sra = tid >> 2, sca = (tid & 3) << 3;
    const float* Arow = qkv + (size_t)(m0 + sra) * 3072 + qoff + sca;
    const float* Wrow = qkv + (size_t)tid * 3072 + qoff + 256;
    ushort* asd = &Qs[sra * 32 + sca];
    ushort* wsd = &Ks[tid * 32];

    for (int k0 = 0; k0 < 128; k0 += 32) {
        float4 a0 = *(const float4*)(Arow + k0);
        float4 a1 = *(const float4*)(Arow + k0 + 4);
        float av[8] = {a0.x, a0.y, a0.z, a0.w, a1.x, a1.y, a1.z, a1.w};
        float wv[32];
        #pragma unroll
        for (int i = 0; i < 8; i++) {
            float4 w4 = *(const float4*)(Wrow + k0 + i * 4);
            wv[i*4+0] = w4.x; wv[i*4+1] = w4.y; wv[i*4+2] = w4.z; wv[i*4+3] = w4.w;
        }
        unsigned au[4], wu[16];
        #pragma unroll
        for (int i = 0; i < 4; i++) au[i] = (unsigned)f2b(av[2*i]) | ((unsigned)f2b(av[2*i+1]) << 16);
        #pragma unroll
        for (int i = 0; i < 16; i++) wu[i] = (unsigned)f2b(wv[2*i]) | ((unsigned)f2b(wv[2*i+1]) << 16);
        __syncthreads();
        ((uint4*)asd)[0] = make_uint4(au[0], au[1], au[2], au[3]);
        ((uint4*)wsd)[0] = make_uint4(wu[0], wu[1], wu[2], wu[3]);
        ((uint4*)(wsd + 8))[0] = make_uint4(wu[4], wu[5], wu[6], wu[7]);
        ((uint4*)(wsd + 16))[0] = make_uint4(wu[8], wu[9], wu[10], wu[11]);
        ((uint4*)(wsd + 24))[0] = make_uint4(wu[12], wu[13], wu[14], wu[15]);
        __syncthreads();

        bf16x8 af = *(const bf16x8*)&Qs[(wave * 16 + p) * 32 + q * 8];
        #pragma unroll
        for (int nt = 0; nt < 16; nt++) {
            bf16x8 bf = *(const bf16x8*)&Ks[(nt * 16 + p) * 32 + q * 8];
            acc[nt] = __builtin_amdgcn_mfma_f32_16x16x32_bf16(af, bf, acc[nt], 0, 0, 0);
        }
    }

    ushort* Pz = P + (size_t)z * 65536;
    #pragma unroll
    for (int reg = 0; reg < 4; reg++) {
        int row = m0 + wave * 16 + q * 4 + reg;
        float v[16]; float mx = -1e30f;
        #pragma unroll
        for (int nt = 0; nt < 16; nt++) {
            int colk = nt * 16 + p;
            float val = (colk <= row) ? acc[nt][reg] * SCALE : -1e30f;
            v[nt] = val; mx = fmaxf(mx, val);
        }
        mx = fmaxf(mx, __shfl_xor(mx, 1)); mx = fmaxf(mx, __shfl_xor(mx, 2));
        mx = fmaxf(mx, __shfl_xor(mx, 4)); mx = fmaxf(mx, __shfl_xor(mx, 8));
        float s = 0.f;
        #pragma unroll
        for (int nt = 0; nt < 16; nt++) {
            int colk = nt * 16 + p;
            float e = (colk <= row) ? __expf(v[nt] - mx) : 0.f;
            v[nt] = e; s += e;
        }
        s += __shfl_xor(s, 1); s += __shfl_xor(s, 2); s += __shfl_xor(s, 4); s += __shfl_xor(s, 8);
        float inv = 1.f / s;
        #pragma unroll
        for (int nt = 0; nt < 16; nt++)
            Pz[(size_t)row * 256 + nt * 16 + p] = f2b(v[nt] * inv);
    }
}

// ---------------- PV: O = P @ V ----------------

__global__ __launch_bounds__(256) void k_attn_pvt(
    const ushort* __restrict__ P, const float* __restrict__ Vt,
    float* __restrict__ out)
{
    __shared__ ushort As[64 * 32];
    __shared__ ushort Bs[128 * 32];
    int tid = threadIdx.x;
    int wave = tid >> 6, lane = tid & 63;
    int q = lane >> 4, p = lane & 15;
    int m0 = blockIdx.x * 64;
    int z = blockIdx.y, b = z >> 1, h = z & 1;

    f32x4 acc[8];
    #pragma unroll
    for (int i = 0; i < 8; i++) acc[i] = (f32x4){0.f, 0.f, 0.f, 0.f};

    int sra = tid >> 2, sca = (tid & 3) << 3;
    const ushort* Prow = P + (size_t)z * 65536 + (size_t)(m0 + sra) * 256 + sca;
    int srb = tid >> 1, scb = (tid & 1) << 4;
    const float* Vrow = Vt + (size_t)z * 32768 + (size_t)srb * 256 + scb;
    ushort* asd = &As[sra * 32 + sca];
    ushort* wsd = &Bs[srb * 32 + scb];

    for (int k0 = 0; k0 < 256; k0 += 32) {
        uint4 pa = *(const uint4*)(Prow + k0);
        float wv[16];
        #pragma unroll
        for (int i = 0; i < 4; i++) {
            float4 w4 = *(const float4*)(Vrow + k0 + i * 4);
            wv[i*4+0] = w4.x; wv[i*4+1] = w4.y; wv[i*4+2] = w4.z; wv[i*4+3] = w4.w;
        }
        unsigned wu[8];
        #pragma unroll
        for (int i = 0; i < 8; i++) wu[i] = (unsigned)f2b(wv[2*i]) | ((unsigned)f2b(wv[2*i+1]) << 16);
        __syncthreads();
        ((uint4*)asd)[0] = pa;
        ((uint4*)wsd)[0] = make_uint4(wu[0], wu[1], wu[2], wu[3]);
        ((uint4*)(wsd + 8))[0] = make_uint4(wu[4], wu[5], wu[6], wu[7]);
        __syncthreads();

        bf16x8 af = *(const bf16x8*)&As[(wave * 16 + p) * 32 + q * 8];
        #pragma unroll
        for (int nt = 0; nt < 8; nt++) {
            bf16x8 bf = *(const bf16x8*)&Bs[(nt * 16 + p) * 32 + q * 8];
            acc[nt] = __builtin_amdgcn_mfma_f32_16x16x32_bf16(af, bf, acc[nt], 0, 0, 0);
        }
    }

    #pragma unroll
    for (int reg = 0; reg < 4; reg++) {
        int s = m0 + wave * 16 + q * 4 + reg;
        #pragma unroll
        for (int nt = 0; nt < 8; nt++) {
            int dh = nt * 16 + p;
            out[(size_t)s * 1024 + (size_t)b * 256 + h * 128 + dh] = acc[nt][reg];
        }
    }
}

// ---------------- generic fp32 GEMM (input projection K=54 only) ----------------

__global__ __launch_bounds__(256) void k_gemm(
    const float* __restrict__ A, const float* __restrict__ W,
    const float* __restrict__ bias, float* __restrict__ C,
    int M, int N, int K, int relu)
{
    __shared__ __align__(16) float As[16][68];
    __shared__ __align__(16) float Ws[16][68];
    int tx = threadIdx.x, ty = threadIdx.y;
    int tid = ty * 16 + tx;
    int m0 = blockIdx.y * 64, n0 = blockIdx.x * 64;
    float acc[4][4] = {{0.f}};
    int r  = tid >> 2;
    int kk = (tid & 3) << 2;
    for (int k0 = 0; k0 < K; k0 += 16) {
        float4 av = make_float4(0.f, 0.f, 0.f, 0.f);
        float4 wv = make_float4(0.f, 0.f, 0.f, 0.f);
        int gm = m0 + r, gk = k0 + kk;
        if (gm < M) {
            float tv[4];
            for (int i = 0; i < 4; i++) tv[i] = (gk + i < K) ? A[(size_t)gm * K + gk + i] : 0.f;
            av = make_float4(tv[0], tv[1], tv[2], tv[3]);
        }
        int gn = n0 + r;
        if (gn < N) {
            float tv[4];
            for (int i = 0; i < 4; i++) tv[i] = (gk + i < K) ? W[(size_t)gn * K + gk + i] : 0.f;
            wv = make_float4(tv[0], tv[1], tv[2], tv[3]);
        }
        As[kk + 0][r] = av.x; As[kk + 1][r] = av.y; As[kk + 2][r] = av.z; As[kk + 3][r] = av.w;
        Ws[kk + 0][r] = wv.x; Ws[kk + 1][r] = wv.y; Ws[kk + 2][r] = wv.z; Ws[kk + 3][r] = wv.w;
        __syncthreads();
        #pragma unroll
        for (int k = 0; k < 16; k++) {
            float4 a4 = *(const float4*)&As[k][ty << 2];
            float4 b4 = *(const float4*)&Ws[k][tx << 2];
            float a[4] = {a4.x, a4.y, a4.z, a4.w};
            float b[4] = {b4.x, b4.y, b4.z, b4.w};
            #pragma unroll
            for (int i = 0; i < 4; i++)
                #pragma unroll
                for (int j = 0; j < 4; j++)
                    acc[i][j] = fmaf(a[i], b[j], acc[i][j]);
        }
        __syncthreads();
    }
    #pragma unroll
    for (int i = 0; i < 4; i++) {
        int gm = m0 + (ty << 2) + i;
        if (gm >= M) continue;
        #pragma unroll
        for (int j = 0; j < 4; j++) {
            int gn = n0 + (tx << 2) + j;
            if (gn >= N) continue;
            float v = acc[i][j] + bias[gn];
            if (relu) v = fmaxf(v, 0.f);
            C[(size_t)gm * N + gn] = v;
        }
    }
}

// ---------------- BatchNorm partial sums ----------------

__global__ __launch_bounds__(256) void k_bn_part(const float* __restrict__ x, float* __restrict__ sums) {
    int t = threadIdx.x;
    int r0 = blockIdx.x * 16;
    float s = 0.f, s2 = 0.f;
    for (int r = r0; r < r0 + 16; r++) {
        float v = x[(size_t)r * 256 + t];
        s += v; s2 += v * v;
    }
    atomicAdd(&sums[t], s);
    atomicAdd(&sums[256 + t], s2);
}

// ---------------- BN-finalize + SELU + positional encoding ----------------

__global__ __launch_bounds__(256) void k_bn_selu_pe(
    const float* __restrict__ x0, const float* __restrict__ sums,
    const float* __restrict__ g, const float* __restrict__ b,
    const int* __restrict__ atom_i, float* __restrict__ out)
{
    int row = blockIdx.x, t = threadIdx.x;
    float m = sums[t] * (1.f / 1024.f);
    float var = sums[256 + t] * (1.f / 1024.f) - m * m;
    float rstd = rsqrtf(var + 1e-5f);
    float v = x0[(size_t)row * 256 + t];
    v = (v - m) * rstd * g[t] + b[t];
    const float SC = 1.0507009873554805f, AL = 1.6732632423543772f;
    v = SC * (v > 0.f ? v : AL * expm1f(v));
    float pos = (float)atom_i[row];
    float freq = expf(-(float)t * (9.210340371976184f / 256.f));
    float ang = pos * freq;
    float pe = (t & 1) ? cosf(ang) : sinf(ang);
    out[(size_t)row * 256 + t] = v + pe;
}

// ---------------- both-layer node cross-attn constant ----------------

__global__ __launch_bounds__(256) void k_cross2(
    const float* __restrict__ z, const float* __restrict__ cqkv_w, const float* __restrict__ cqkv_b,
    const float* __restrict__ co_w, const float* __restrict__ co_b, float* __restrict__ crO)
{
    int m = blockIdx.x, l = blockIdx.y;
    int t = threadIdx.x;
    __shared__ float zs[256], ct[256];
    zs[t] = z[m * 256 + t];
    __syncthreads();
    const float* wv = cqkv_w + (size_t)l * 768 * 256 + 512 * 256 + (size_t)t * 256;
    float a = cqkv_b[l * 768 + 512 + t];
    for (int d = 0; d < 256; d += 4) {
        float4 w4 = *(const float4*)(wv + d);
        a += zs[d] * w4.x + zs[d+1] * w4.y + zs[d+2] * w4.z + zs[d+3] * w4.w;
    }
    ct[t] = a;
    __syncthreads();
    const float* ow = co_w + (size_t)l * 65536 + (size_t)t * 256;
    float o = co_b[l * 256 + t];
    for (int d = 0; d < 256; d += 4) {
        float4 w4 = *(const float4*)(ow + d);
        o += ct[d] * w4.x + ct[d+1] * w4.y + ct[d+2] * w4.z + ct[d+3] * w4.w;
    }
    crO[l * 1024 + m * 256 + t] = o;
}

// ---------------- edge group self-attention ----------------

__global__ __launch_bounds__(256) void k_edge_self_attn(
    const float* __restrict__ qkv, float* __restrict__ out)
{
    int g = blockIdx.x + 1;
    int b = blockIdx.y;
    int gs = min(g, 12);
    int base = (g <= 13) ? g * (g - 1) / 2 : 78 + (g - 13) * 12;
    int h = threadIdx.x >> 7;
    int t = threadIdx.x & 127;
    __shared__ float qs[2][12][128], ks[2][12][128], vs[2][12][128];
    __shared__ float ps[2][12][12];
    for (int i = 0; i < gs; i++) {
        size_t row = ((size_t)(base + i) * BB + b) * 768 + h * 128 + t;
        qs[h][i][t] = qkv[row];
        ks[h][i][t] = qkv[row + 256];
        vs[h][i][t] = qkv[row + 512];
    }
    __syncthreads();
    for (int p = t; p < gs * gs; p += 128) {
        int i = p / gs, j = p - i * gs;
        float acc = 0.f;
        for (int d = 0; d < 128; d++) acc = fmaf(qs[h][i][d], ks[h][j][d], acc);
        ps[h][i][j] = acc * SCALE;
    }
    __syncthreads();
    if (t < gs) {
        float m = -1e30f;
        for (int j = 0; j < gs; j++) m = fmaxf(m, ps[h][t][j]);
        float e[12]; float s = 0.f;
        for (int j = 0; j < gs; j++) { e[j] = expf(ps[h][t][j] - m); s += e[j]; }
        float inv = 1.f / s;
        for (int j = 0; j < gs; j++) ps[h][t][j] = e[j] * inv;
    }
    __syncthreads();
    for (int i = 0; i < gs; i++) {
        float acc = 0.f;
        for (int j = 0; j < gs; j++) acc = fmaf(ps[h][i][j], vs[h][j][t], acc);
        out[((size_t)(base + i) * BB + b) * 256 + h * 128 + t] = acc;
    }
}

// ---------------- gather + build_mem fused ----------------

__global__ __launch_bounds__(256) void k_gather_mem(
    const float* __restrict__ z, const float* __restrict__ nemb,
    const int* __restrict__ idxt, float* __restrict__ etgt, float* __restrict__ memb)
{
    int r = blockIdx.x, t = threadIdx.x;
    if (r < LEB) {
        int e = r >> 2, b = r & 3;
        etgt[(size_t)r * 256 + t] = nemb[((size_t)idxt[e] * 4 + b) * 256 + t];
    } else {
        int rm = r - LEB;
        int m = rm >> 2, b = rm & 3;
        memb[(size_t)rm * 256 + t] = (m == 0) ? z[(size_t)b * 256 + t]
                                              : nemb[((size_t)(m - 1) * 4 + b) * 256 + t];
    }
}

// ---------------- fused node cross-entropy (no dynamic-indexed arrays) ----------------

__global__ __launch_bounds__(256) void k_ce_node(
    const float* __restrict__ emb,
    const float* __restrict__ w0, const float* __restrict__ b0,
    const float* __restrict__ w1, const float* __restrict__ b1,
    const float* __restrict__ w2, const float* __restrict__ b2,
    const int* __restrict__ y, int M, float invM, float* __restrict__ lossOut)
{
    int wave = threadIdx.x >> 6, lane = threadIdx.x & 63;
    int wid = blockIdx.x * 4 + wave;
    float local = 0.f;
    for (int r = wid; r < M; r += gridDim.x * 4) {
        float4 x = ((const float4*)(emb + (size_t)r * 256))[lane];
        float acc[54];
        #pragma unroll
        for (int c = 0; c < 40; c++) {
            float4 wv = ((const float4*)(w0 + (size_t)c * 256))[lane];
            acc[c] = x.x * wv.x + x.y * wv.y + x.z * wv.z + x.w * wv.w;
        }
        #pragma unroll
        for (int c = 0; c < 8; c++) {
            float4 wv = ((const float4*)(w1 + (size_t)c * 256))[lane];
            acc[40 + c] = x.x * wv.x + x.y * wv.y + x.z * wv.z + x.w * wv.w;
        }
        #pragma unroll
        for (int c = 0; c < 6; c++) {
            float4 wv = ((const float4*)(w2 + (size_t)c * 256))[lane];
            acc[48 + c] = x.x * wv.x + x.y * wv.y + x.z * wv.z + x.w * wv.w;
        }
        #pragma unroll
        for (int c = 0; c < 54; c++)
            for (int o = 32; o; o >>= 1) acc[c] += __shfl_down(acc[c], o);
        if (lane == 0) {
            int y0 = y[(size_t)r * 3 + 0], y1 = y[(size_t)r * 3 + 1], y2 = y[(size_t)r * 3 + 2];
            float m0v = -1e30f, m1v = -1e30f, m2v = -1e30f;
            float t0 = 0.f, t1v = 0.f, t2v = 0.f;
            #pragma unroll
            for (int c = 0; c < 40; c++) {
                float v = acc[c] + b0[c];
                acc[c] = v; m0v = fmaxf(m0v, v);
                if (c == y0) t0 = v;
            }
            #pragma unroll
            for (int c = 0; c < 8; c++) {
                float v = acc[40 + c] + b1[c];
                acc[40 + c] = v; m1v = fmaxf(m1v, v);
                if (c == y1) t1v = v;
            }
            #pragma unroll
            for (int c = 0; c < 6; c++) {
                float v = acc[48 + c] + b2[c];
                acc[48 + c] = v; m2v = fmaxf(m2v, v);
                if (c == y2) t2v = v;
            }
            float s0 = 0.f, s1 = 0.f, s2 = 0.f;
            #pragma unroll
            for (int c = 0; c < 40; c++) s0 += __expf(acc[c] - m0v);
            #pragma unroll
            for (int c = 0; c < 8; c++)  s1 += __expf(acc[40 + c] - m1v);
            #pragma unroll
            for (int c = 0; c < 6; c++)  s2 += __expf(acc[48 + c] - m2v);
            local += (m0v + logf(s0) - t0) + (m1v + logf(s1) - t1v) + (m2v + logf(s2) - t2v);
        }
    }
    __shared__ float ls[4];
    if (lane == 0) ls[wave] = local;
    __syncthreads();
    if (threadIdx.x == 0)
        atomicAdd(lossOut, (ls[0] + ls[1] + ls[2] + ls[3]) * invM);
}

// ---------------- host ----------------

extern "C" void kernel_launch(void* const* d_in, const int* in_sizes, int n_in,
                              void* d_out, int out_size, void* d_ws, size_t ws_size,
                              hipStream_t stream)
{
    (void)in_sizes; (void)n_in; (void)out_size; (void)ws_size;
    const float* zin      = (const float*)d_in[0];
    const int*   atom_i   = (const int*)d_in[1];
    const float* atom_x   = (const float*)d_in[2];
    const int*   atom_y   = (const int*)d_in[3];
    const int*   bond_y   = (const int*)d_in[4];
    const float* Wp       = (const float*)d_in[5];
    const float* bp       = (const float*)d_in[6];
    const float* bn_g     = (const float*)d_in[7];
    const float* bn_b     = (const float*)d_in[8];
    const float* nd_qkv_w = (const float*)d_in[9];
    const float* nd_qkv_b = (const float*)d_in[10];
    const float* nd_so_w  = (const float*)d_in[11];
    const float* nd_so_b  = (const float*)d_in[12];
    const float* nd_cqkv_w= (const float*)d_in[13];
    const float* nd_cqkv_b= (const float*)d_in[14];
    const float* nd_co_w  = (const float*)d_in[15];
    const float* nd_co_b  = (const float*)d_in[16];
    const float* nd_ff1_w = (const float*)d_in[17];
    const float* nd_ff1_b = (const float*)d_in[18];
    const float* nd_ff2_w = (const float*)d_in[19];
    const float* nd_ff2_b = (const float*)d_in[20];
    const float* nd_ln_g  = (const float*)d_in[21];
    const float* nd_ln_b  = (const float*)d_in[22];
    const float* nd_fn_g  = (const float*)d_in[23];
    const float* nd_fn_b  = (const float*)d_in[24];
    const float* ed_qkv_w = (const float*)d_in[25];
    const float* ed_qkv_b = (const float*)d_in[26];
    const float* ed_so_w  = (const float*)d_in[27];
    const float* ed_so_b  = (const float*)d_in[28];
    const float* ed_cqkv_w= (const float*)d_in[29];
    const float* ed_cqkv_b= (const float*)d_in[30];
    const float* ed_co_w  = (const float*)d_in[31];
    const float* ed_co_b  = (const float*)d_in[32];
    const float* ed_ff1_w = (const float*)d_in[33];
    const float* ed_ff1_b = (const float*)d_in[34];
    const float* ed_ff2_w = (const float*)d_in[35];
    const float* ed_ff2_b = (const float*)d_in[36];
    const float* ed_ln_g  = (const float*)d_in[37];
    const float* ed_ln_b  = (const float*)d_in[38];
    const float* ed_fn_g  = (const float*)d_in[39];
    const float* ed_fn_b  = (const float*)d_in[40];
    const float* nc0_w = (const float*)d_in[41]; const float* nc0_b = (const float*)d_in[42];
    const float* nc1_w = (const float*)d_in[43]; const float* nc1_b = (const float*)d_in[44];
    const float* nc2_w = (const float*)d_in[45]; const float* nc2_b = (const float*)d_in[46];
    const float* ec0_w = (const float*)d_in[47]; const float* ec0_b = (const float*)d_in[48];
    const float* ec1_w = (const float*)d_in[49]; const float* ec1_b = (const float*)d_in[50];

    float* out = (float*)d_out;

    char* wsb = (char*)d_ws;
    size_t off = 0;
    auto alloc = [&](size_t nbytes) -> void* {
        void* p = (void*)(wsb + off);
        off += (nbytes + 255) / 256 * 256;
        return p;
    };
    float* x0    = (float*)alloc(1024 * 256 * 4);
    float* tgt   = (float*)alloc(1024 * 256 * 4);
    float* nqkv  = (float*)alloc(1024 * 768 * 4);
    float* t1    = (float*)alloc(1024 * 256 * 4);
    float* nemb  = (float*)alloc(1024 * 256 * 4);
    float* bnsums= (float*)alloc(512 * 4);
    float* crO   = (float*)alloc(2 * 1024 * 4);
    float* memb  = (float*)alloc(1028 * 256 * 4);
    float* KV    = (float*)alloc(1028 * 512 * 4);
    ushort* Sb   = (ushort*)alloc(8 * 65536 * 2);
    float* Vt    = (float*)alloc(8 * 32768 * 4);
    float* etgt  = (float*)alloc((size_t)LEB * 256 * 4);
    float* eqkv  = (float*)alloc((size_t)LEB * 768 * 4);
    float* et1   = (float*)alloc((size_t)LEB * 256 * 4);
    int* grp   = (int*)alloc(LE * 4);
    int* idxt  = (int*)alloc(LE * 4);
    ushort* wpk = (ushort*)alloc((size_t)TOTFRAG * 512 * 2);

    PackArgs pa;
    pa.src[0] = nd_qkv_w;              pa.src[1] = nd_qkv_w + 768 * 256;
    pa.src[2] = nd_so_w;               pa.src[3] = nd_so_w + 65536;
    pa.src[4] = nd_ff1_w;              pa.src[5] = nd_ff1_w + 65536;
    pa.src[6] = nd_ff2_w;              pa.src[7] = nd_ff2_w + 65536;
    pa.src[8] = ed_qkv_w;              pa.src[9] = ed_cqkv_w;
    pa.src[10] = ed_so_w;              pa.src[11] = ed_co_w;
    pa.src[12] = ed_ff1_w;             pa.src[13] = ed_ff2_w;
    int fs[NPACK + 1] = {0, 384, 768, 896, 1024, 1152, 1280, 1408, 1536, 1920, 2304, 2432, 2560, 2688, 2816};
    for (int i = 0; i <= NPACK; i++) pa.fs[i] = fs[i];
    auto wp = [&](int i) -> const ushort* { return wpk + (size_t)fs[i] * 512; };

    k_init<<<13, 256, 0, stream>>>(out, bnsums, grp, idxt);
    k_prep<<<(TOTFRAG * 64 + 255) / 256, 256, 0, stream>>>(pa, wpk);

    // node input: projection + BN + SELU + PE
    k_gemm<<<dim3(4, 16), dim3(16, 16), 0, stream>>>(atom_x, Wp, bp, x0, 1024, 256, 54, 0);
    k_bn_part<<<64, 256, 0, stream>>>(x0, bnsums);
    k_bn_selu_pe<<<1024, 256, 0, stream>>>(x0, bnsums, bn_g, bn_b, atom_i, tgt);

    // both layers' cross-attn constant
    k_cross2<<<dim3(4, 2), 256, 0, stream>>>(zin, nd_cqkv_w, nd_cqkv_b, nd_co_w, nd_co_b, crO);

    // node decoder: 2 layers (4 dispatches each)
    for (int l = 0; l < 2; l++) {
        k_gemm_w<<<dim3(3, 8), 256, 0, stream>>>(tgt, wp(l), nd_qkv_b + l * 768,
                                                 nqkv, Vt, 1024, 768, 3, 0);
        k_attn_qks<<<dim3(4, 8), 256, 0, stream>>>(nqkv, Sb);
        k_attn_pvt<<<dim3(4, 8), 256, 0, stream>>>(Sb, Vt, t1);
        k_node_mega<<<32, 256, 0, stream>>>(
            t1, tgt, crO + l * 1024,
            wp(2 + l), nd_so_b + l * 256,
            nd_ln_g + (l * 3 + 0) * 256, nd_ln_b + (l * 3 + 0) * 256,
            nd_ln_g + (l * 3 + 1) * 256, nd_ln_b + (l * 3 + 1) * 256,
            wp(4 + l), nd_ff1_b + l * 256,
            wp(6 + l), nd_ff2_b + l * 256,
            nd_ln_g + (l * 3 + 2) * 256, nd_ln_b + (l * 3 + 2) * 256,
            nd_fn_g, nd_fn_b,
            (l == 0) ? tgt : nemb, 1024, (l == 1) ? 1 : 0);
    }

    // node losses
    k_ce_node<<<128, 256, 0, stream>>>(nemb, nc0_w, nc0_b, nc1_w, nc1_b, nc2_w, nc2_b,
                                       atom_y, 1024, 1.f / 1024.f, out);

    // edge path
    k_gather_mem<<<LEB + 1028, 256, 0, stream>>>(zin, nemb, idxt, etgt, memb);
    k_gemm_w<<<dim3(2, 17), 256, 0, stream>>>(memb, wp(9) + 128 * 512, ed_cqkv_b + 256,
                                              KV, nullptr, 1028, 512, 0, 0);
    k_gemm_w<<<dim3(3, 188), 256, 0, stream>>>(etgt, wp(8), ed_qkv_b,
                                               eqkv, nullptr, LEB, 768, 0, 0);
    k_edge_self_attn<<<dim3(255, 4), 256, 0, stream>>>(eqkv, et1);
    k_edge_mega<<<(LEB + 31) / 32, 256, 0, stream>>>(
        et1, etgt,
        wp(10), ed_so_b, ed_ln_g, ed_ln_b,
        wp(9), ed_cqkv_b, KV, grp,
        wp(11), ed_co_b, ed_ln_g + 256, ed_ln_b + 256,
        wp(12), ed_ff1_b,
        wp(13), ed_ff2_b, ed_ln_g + 512, ed_ln_b + 512,
        ed_fn_g, ed_fn_b,
        bond_y, ec0_w, ec0_b, ec1_w, ec1_b,
        out, 1.f / (float)LEB, LEB);
}

// Round 11
// 452.050 us; speedup vs baseline: 1.3285x; 1.1316x over previous
//
#include <hip/hip_runtime.h>
#include <math.h>

#define SS 256
#define BB 4
#define HH 256
#define LE 2994
#define LEB (LE*BB)
#define SCALE 0.08838834764831845f  // 1/sqrt(128)

typedef __attribute__((ext_vector_type(8))) short bf16x8;
typedef __attribute__((ext_vector_type(4))) float f32x4;

__device__ inline ushort f2b(float f) {   // fp32 -> bf16 RNE
    unsigned u = __float_as_uint(f);
    u += 0x7FFFu + ((u >> 16) & 1u);
    return (ushort)(u >> 16);
}

__device__ inline float qred(float x) {   // sum across 16 lanes of a quarter-wave (broadcast)
    x += __shfl_xor(x, 1); x += __shfl_xor(x, 2);
    x += __shfl_xor(x, 4); x += __shfl_xor(x, 8);
    return x;
}

// ---------------- init ----------------

__global__ void k_init(float* __restrict__ out, float* __restrict__ bnsums,
                       int* __restrict__ grp, int* __restrict__ idxt) {
    int bid = blockIdx.x, t = threadIdx.x;
    if (bid == 0) {
        if (t == 0) out[0] = 0.f;
        bnsums[t] = 0.f; bnsums[256 + t] = 0.f;
        return;
    }
    int e = (bid - 1) * 256 + t;
    if (e >= LE) return;
    int g, pos;
    if (e < 78) {
        g = (int)((1.0f + sqrtf(8.0f * (float)e + 1.0f)) * 0.5f);
        while (g * (g - 1) / 2 > e) g--;
        while ((g + 1) * g / 2 <= e) g++;
        pos = e - g * (g - 1) / 2;
        idxt[e] = pos;
    } else {
        int r = e - 78;
        g = 13 + r / 12;
        pos = r % 12;
        idxt[e] = g - 12 + pos;
    }
    grp[e] = g;
}

// ---------------- weight pre-pack ----------------

#define NPACK 14
#define TOTFRAG 2816
struct PackArgs { const float* src[NPACK]; int fs[NPACK + 1]; };

__global__ __launch_bounds__(256) void k_prep(PackArgs pa, ushort* __restrict__ dst) {
    int wid = (blockIdx.x * 256 + threadIdx.x) >> 6;
    int lane = threadIdx.x & 63;
    if (wid >= TOTFRAG) return;
    int i = 0;
    while (pa.fs[i + 1] <= wid) i++;
    int f = wid - pa.fs[i];
    int tn = f >> 3, tk = f & 7;
    int q = lane >> 4, p = lane & 15;
    const float* s = pa.src[i] + (size_t)(tn * 16 + p) * 256 + tk * 32 + q * 8;
    float4 a0 = *(const float4*)s, a1 = *(const float4*)(s + 4);
    uint4 o = make_uint4(f2b(a0.x) | ((unsigned)f2b(a0.y) << 16),
                         f2b(a0.z) | ((unsigned)f2b(a0.w) << 16),
                         f2b(a1.x) | ((unsigned)f2b(a1.y) << 16),
                         f2b(a1.z) | ((unsigned)f2b(a1.w) << 16));
    *(uint4*)&dst[(size_t)wid * 512 + lane * 8] = o;
}

// ---------------- plain bf16 GEMM with packed W (modes 0/3), 64-row x 256-col tiles ----------------

__global__ __launch_bounds__(256) void k_gemm_w(
    const float* __restrict__ A, const ushort* __restrict__ Wp,
    const float* __restrict__ bias, float* __restrict__ C, float* __restrict__ Vt,
    int M, int N, int mode, int relu)
{
    __shared__ ushort As[32 * 512];
    int tid = threadIdx.x;
    int w = tid >> 6, lane = tid & 63;
    int q = lane >> 4, p = lane & 15;
    int m0 = blockIdx.y * 64, n0 = blockIdx.x * 256;

    {
        int r = tid >> 2;
        int cbase = (tid & 3) * 64;
        int gm = m0 + r;
        const float* Ar = A + (size_t)gm * 256 + cbase;
        bool ok = gm < M;
        #pragma unroll
        for (int j = 0; j < 8; j++) {
            int c = cbase + j * 8;
            float4 a0, a1;
            if (ok) { a0 = *(const float4*)(Ar + j * 8); a1 = *(const float4*)(Ar + j * 8 + 4); }
            else { a0 = make_float4(0.f, 0.f, 0.f, 0.f); a1 = a0; }
            uint4 o = make_uint4(f2b(a0.x) | ((unsigned)f2b(a0.y) << 16),
                                 f2b(a0.z) | ((unsigned)f2b(a0.w) << 16),
                                 f2b(a1.x) | ((unsigned)f2b(a1.y) << 16),
                                 f2b(a1.z) | ((unsigned)f2b(a1.w) << 16));
            int frag = (r >> 4) * 8 + (c >> 5);
            int fl = ((c >> 3) & 3) * 16 + (r & 15);
            *(uint4*)&As[frag * 512 + fl * 8] = o;
        }
    }
    __syncthreads();

    f32x4 acc[4][4];
    #pragma unroll
    for (int i = 0; i < 4; i++)
        #pragma unroll
        for (int j = 0; j < 4; j++) acc[i][j] = (f32x4){0.f, 0.f, 0.f, 0.f};

    int nw = n0 + w * 64;
    const ushort* Wb = Wp + (size_t)(nw >> 4) * 4096;

    #pragma unroll
    for (int kt = 0; kt < 8; kt++) {
        bf16x8 afr[4], wfr[4];
        #pragma unroll
        for (int mt = 0; mt < 4; mt++)
            afr[mt] = *(const bf16x8*)&As[(mt * 8 + kt) * 512 + lane * 8];
        #pragma unroll
        for (int nt = 0; nt < 4; nt++)
            wfr[nt] = *(const bf16x8*)&Wb[(size_t)(nt * 8 + kt) * 512 + lane * 8];
        #pragma unroll
        for (int mt = 0; mt < 4; mt++)
            #pragma unroll
            for (int nt = 0; nt < 4; nt++)
                acc[mt][nt] = __builtin_amdgcn_mfma_f32_16x16x32_bf16(afr[mt], wfr[nt], acc[mt][nt], 0, 0, 0);
    }

    float bi[4]; int col[4];
    #pragma unroll
    for (int nt = 0; nt < 4; nt++) { col[nt] = nw + nt * 16 + p; bi[nt] = bias[col[nt]]; }
    #pragma unroll
    for (int mt = 0; mt < 4; mt++)
        #pragma unroll
        for (int reg = 0; reg < 4; reg++) {
            int grow = m0 + mt * 16 + q * 4 + reg;
            if (grow >= M) continue;
            #pragma unroll
            for (int nt = 0; nt < 4; nt++) {
                float v = acc[mt][nt][reg] + bi[nt];
                if (relu) v = fmaxf(v, 0.f);
                if (mode == 3) {
                    if (col[nt] < 512) {
                        C[(size_t)grow * 768 + col[nt]] = v;
                    } else {
                        int hh = (col[nt] - 512) >> 7, dh = (col[nt] - 512) & 127;
                        int zz = (grow & 3) * 2 + hh;
                        Vt[(size_t)zz * 32768 + (size_t)dh * 256 + (grow >> 2)] = v;
                    }
                } else {
                    C[(size_t)grow * N + col[nt]] = v;
                }
            }
        }
}

// ---------------- 16-row / 4-wave pipeline building blocks ----------------
// Wave w handles cols w*64 + nt*16 + p (nt<4); rows q*4 + reg.

__device__ inline void stageA_16(const float* __restrict__ A, int M, int m0, int tid,
                                 ushort* __restrict__ As) {
    int r = tid >> 4;
    int cbase = (tid & 15) * 16;
    int gm = m0 + r;
    const float* Ar = A + (size_t)gm * 256 + cbase;
    bool ok = gm < M;
    #pragma unroll
    for (int j = 0; j < 2; j++) {
        int c = cbase + j * 8;
        float4 a0, a1;
        if (ok) { a0 = *(const float4*)(Ar + j * 8); a1 = *(const float4*)(Ar + j * 8 + 4); }
        else { a0 = make_float4(0.f, 0.f, 0.f, 0.f); a1 = a0; }
        uint4 o = make_uint4(f2b(a0.x) | ((unsigned)f2b(a0.y) << 16),
                             f2b(a0.z) | ((unsigned)f2b(a0.w) << 16),
                             f2b(a1.x) | ((unsigned)f2b(a1.y) << 16),
                             f2b(a1.z) | ((unsigned)f2b(a1.w) << 16));
        int frag = c >> 5;
        int fl = ((c >> 3) & 3) * 16 + r;
        *(uint4*)&As[frag * 512 + fl * 8] = o;
    }
    __syncthreads();
}

__device__ inline void gemm_pass16(const ushort* __restrict__ As, const ushort* __restrict__ Wq,
                                   int w, int lane, f32x4 (&acc)[4]) {
    #pragma unroll
    for (int nt = 0; nt < 4; nt++) acc[nt] = (f32x4){0.f, 0.f, 0.f, 0.f};
    #pragma unroll
    for (int kt = 0; kt < 8; kt++) {
        bf16x8 a0 = *(const bf16x8*)&As[kt * 512 + lane * 8];
        #pragma unroll
        for (int nt = 0; nt < 4; nt++) {
            bf16x8 wf = *(const bf16x8*)&Wq[(size_t)((w * 4 + nt) * 8 + kt) * 512 + lane * 8];
            acc[nt] = __builtin_amdgcn_mfma_f32_16x16x32_bf16(a0, wf, acc[nt], 0, 0, 0);
        }
    }
}

__device__ inline void stage_acc16(const f32x4 (&acc)[4], ushort* __restrict__ As,
                                   int w, int q, int p) {
    __syncthreads();
    #pragma unroll
    for (int nt = 0; nt < 4; nt++)
        #pragma unroll
        for (int reg = 0; reg < 4; reg++)
            As[(w * 2 + (nt >> 1)) * 512 +
               (((nt * 2 + (p >> 3)) & 3) * 16 + q * 4 + reg) * 8 + (p & 7)] =
                f2b(acc[nt][reg]);
    __syncthreads();
}

__device__ inline void block_ln16(f32x4 (&acc)[4], float* __restrict__ red,
                                  int tid, int w, int q, int p,
                                  const float* __restrict__ g, const float* __restrict__ b) {
    float gg[4], bb[4];
    #pragma unroll
    for (int nt = 0; nt < 4; nt++) { int col = w * 64 + nt * 16 + p; gg[nt] = g[col]; bb[nt] = b[col]; }
    #pragma unroll
    for (int reg = 0; reg < 4; reg++) {
        float s = acc[0][reg] + acc[1][reg] + acc[2][reg] + acc[3][reg];
        s = qred(s);
        if (p == 0) red[w * 16 + q * 4 + reg] = s;
    }
    __syncthreads();
    if (tid < 16) red[64 + tid] = (red[tid] + red[16 + tid] + red[32 + tid] + red[48 + tid]) * (1.f / 256.f);
    __syncthreads();
    #pragma unroll
    for (int reg = 0; reg < 4; reg++) {
        int lr = q * 4 + reg;
        float mean = red[64 + lr];
        float sq = 0.f;
        #pragma unroll
        for (int nt = 0; nt < 4; nt++) {
            acc[nt][reg] -= mean;
            sq += acc[nt][reg] * acc[nt][reg];
        }
        sq = qred(sq);
        if (p == 0) red[w * 16 + lr] = sq;
    }
    __syncthreads();
    if (tid < 16) red[64 + tid] = rsqrtf((red[tid] + red[16 + tid] + red[32 + tid] + red[48 + tid]) * (1.f / 256.f) + 1e-5f);
    __syncthreads();
    #pragma unroll
    for (int reg = 0; reg < 4; reg++) {
        float rstd = red[64 + q * 4 + reg];
        #pragma unroll
        for (int nt = 0; nt < 4; nt++)
            acc[nt][reg] = acc[nt][reg] * rstd * gg[nt] + bb[nt];
    }
    __syncthreads();
}

// ---------------- node mega: so+LN, +crO+LN, ff1, ff2+LN(+final LN) — 16 rows/block ----------------

__global__ __launch_bounds__(256) void k_node_mega(
    const float* __restrict__ t1, const float* __restrict__ tgt,
    const float* __restrict__ crO,
    const ushort* __restrict__ Wso, const float* __restrict__ so_b,
    const float* __restrict__ ln0g, const float* __restrict__ ln0b,
    const float* __restrict__ ln1g, const float* __restrict__ ln1b,
    const ushort* __restrict__ Wff1, const float* __restrict__ ff1_b,
    const ushort* __restrict__ Wff2, const float* __restrict__ ff2_b,
    const float* __restrict__ ln2g, const float* __restrict__ ln2b,
    const float* __restrict__ fng, const float* __restrict__ fnb,
    float* __restrict__ outp, int M, int finalln)
{
    __shared__ ushort As[8 * 512];
    __shared__ float red[128];
    int tid = threadIdx.x;
    int w = tid >> 6, lane = tid & 63, q = lane >> 4, p = lane & 15;
    int m0 = blockIdx.x * 16;

    float x[4][4];
    f32x4 acc[4];

    stageA_16(t1, M, m0, tid, As);
    #pragma unroll
    for (int reg = 0; reg < 4; reg++) {
        int row = m0 + q * 4 + reg;
        bool ok = row < M;
        #pragma unroll
        for (int nt = 0; nt < 4; nt++)
            x[nt][reg] = ok ? tgt[(size_t)row * 256 + w * 64 + nt * 16 + p] : 0.f;
    }

    // pass 1: self-out + residual + LN
    gemm_pass16(As, Wso, w, lane, acc);
    {
        float bi[4];
        #pragma unroll
        for (int nt = 0; nt < 4; nt++) bi[nt] = so_b[w * 64 + nt * 16 + p];
        #pragma unroll
        for (int nt = 0; nt < 4; nt++)
            #pragma unroll
            for (int reg = 0; reg < 4; reg++)
                acc[nt][reg] += bi[nt] + x[nt][reg];
    }
    block_ln16(acc, red, tid, w, q, p, ln0g, ln0b);

    // + crO (broadcast over batch) + LN
    #pragma unroll
    for (int reg = 0; reg < 4; reg++) {
        int row = m0 + q * 4 + reg;
        int b = row & 3;
        #pragma unroll
        for (int nt = 0; nt < 4; nt++)
            acc[nt][reg] += crO[b * 256 + w * 64 + nt * 16 + p];
    }
    block_ln16(acc, red, tid, w, q, p, ln1g, ln1b);

    // save residual for ff
    #pragma unroll
    for (int nt = 0; nt < 4; nt++)
        #pragma unroll
        for (int reg = 0; reg < 4; reg++)
            x[nt][reg] = acc[nt][reg];

    // pass 2: ff1 + relu
    stage_acc16(acc, As, w, q, p);
    gemm_pass16(As, Wff1, w, lane, acc);
    {
        float bi[4];
        #pragma unroll
        for (int nt = 0; nt < 4; nt++) bi[nt] = ff1_b[w * 64 + nt * 16 + p];
        #pragma unroll
        for (int nt = 0; nt < 4; nt++)
            #pragma unroll
            for (int reg = 0; reg < 4; reg++)
                acc[nt][reg] = fmaxf(acc[nt][reg] + bi[nt], 0.f);
    }

    // pass 3: ff2 + residual + LN (+final LN)
    stage_acc16(acc, As, w, q, p);
    gemm_pass16(As, Wff2, w, lane, acc);
    {
        float bi[4];
        #pragma unroll
        for (int nt = 0; nt < 4; nt++) bi[nt] = ff2_b[w * 64 + nt * 16 + p];
        #pragma unroll
        for (int nt = 0; nt < 4; nt++)
            #pragma unroll
            for (int reg = 0; reg < 4; reg++)
                acc[nt][reg] += bi[nt] + x[nt][reg];
    }
    block_ln16(acc, red, tid, w, q, p, ln2g, ln2b);
    if (finalln) block_ln16(acc, red, tid, w, q, p, fng, fnb);

    #pragma unroll
    for (int reg = 0; reg < 4; reg++) {
        int row = m0 + q * 4 + reg;
        if (row >= M) continue;
        #pragma unroll
        for (int nt = 0; nt < 4; nt++)
            outp[(size_t)row * 256 + w * 64 + nt * 16 + p] = acc[nt][reg];
    }
}

// ---------------- edge mega: so+LN, crossQ+2key-attn, co+LN, ff1, ff2+LN+finalLN+CE — 16 rows/block ----------------

__global__ __launch_bounds__(256) void k_edge_mega(
    const float* __restrict__ et1, const float* __restrict__ etgt,
    const ushort* __restrict__ Wso, const float* __restrict__ so_b,
    const float* __restrict__ ln0g, const float* __restrict__ ln0b,
    const ushort* __restrict__ Wcq, const float* __restrict__ cq_b,
    const float* __restrict__ KV, const int* __restrict__ grp,
    const ushort* __restrict__ Wco, const float* __restrict__ co_b,
    const float* __restrict__ ln1g, const float* __restrict__ ln1b,
    const ushort* __restrict__ Wff1, const float* __restrict__ ff1_b,
    const ushort* __restrict__ Wff2, const float* __restrict__ ff2_b,
    const float* __restrict__ ln2g, const float* __restrict__ ln2b,
    const float* __restrict__ fng, const float* __restrict__ fnb,
    const int* __restrict__ ydata,
    const float* __restrict__ cw0, const float* __restrict__ cb0,
    const float* __restrict__ cw1, const float* __restrict__ cb1,
    float* __restrict__ lossOut, float invM, int M)
{
    __shared__ ushort As[8 * 512];
    __shared__ float red[640];
    int tid = threadIdx.x;
    int w = tid >> 6, lane = tid & 63, q = lane >> 4, p = lane & 15;
    int m0 = blockIdx.x * 16;

    float x[4][4];
    f32x4 acc[4];

    stageA_16(et1, M, m0, tid, As);
    #pragma unroll
    for (int reg = 0; reg < 4; reg++) {
        int row = m0 + q * 4 + reg;
        bool ok = row < M;
        #pragma unroll
        for (int nt = 0; nt < 4; nt++)
            x[nt][reg] = ok ? etgt[(size_t)row * 256 + w * 64 + nt * 16 + p] : 0.f;
    }

    // pass 1: self-out + residual + LN  -> x (tgt1)
    gemm_pass16(As, Wso, w, lane, acc);
    {
        float bi[4];
        #pragma unroll
        for (int nt = 0; nt < 4; nt++) bi[nt] = so_b[w * 64 + nt * 16 + p];
        #pragma unroll
        for (int nt = 0; nt < 4; nt++)
            #pragma unroll
            for (int reg = 0; reg < 4; reg++)
                acc[nt][reg] += bi[nt] + x[nt][reg];
    }
    block_ln16(acc, red, tid, w, q, p, ln0g, ln0b);
    #pragma unroll
    for (int nt = 0; nt < 4; nt++)
        #pragma unroll
        for (int reg = 0; reg < 4; reg++)
            x[nt][reg] = acc[nt][reg];

    // pass 2: cross q projection + 2-key attention. head h = w>>1; dim d = (w&1)*64 + nt*16 + p.
    stage_acc16(acc, As, w, q, p);
    gemm_pass16(As, Wcq, w, lane, acc);
    {
        int h = w >> 1;
        float bi[4];
        #pragma unroll
        for (int nt = 0; nt < 4; nt++) bi[nt] = cq_b[w * 64 + nt * 16 + p];
        #pragma unroll
        for (int reg = 0; reg < 4; reg++) {
            int lr = q * 4 + reg;
            int row = m0 + lr;
            bool ok = row < M;
            int b = row & 3;
            int g = ok ? grp[row >> 2] : 0;
            const float* K0 = KV + (size_t)b * 512 + h * 128;
            const float* K1 = KV + ((size_t)(g + 1) * 4 + b) * 512 + h * 128;
            float s0 = 0.f, s1 = 0.f;
            #pragma unroll
            for (int nt = 0; nt < 4; nt++) {
                float qv = acc[nt][reg] + bi[nt];
                int d = (w & 1) * 64 + nt * 16 + p;
                s0 += qv * K0[d]; s1 += qv * K1[d];
            }
            s0 = qred(s0); s1 = qred(s1);
            if (p == 0) { red[(w * 16 + lr) * 2 + 0] = s0; red[(w * 16 + lr) * 2 + 1] = s1; }
        }
        __syncthreads();
        if (tid < 32) {
            int hh = tid >> 4, lr = tid & 15;
            float p0 = (red[((hh * 2) * 16 + lr) * 2 + 0] + red[((hh * 2 + 1) * 16 + lr) * 2 + 0]) * SCALE;
            float p1 = (red[((hh * 2) * 16 + lr) * 2 + 1] + red[((hh * 2 + 1) * 16 + lr) * 2 + 1]) * SCALE;
            float mx = fmaxf(p0, p1);
            float e0 = __expf(p0 - mx), e1 = __expf(p1 - mx);
            float inv = 1.f / (e0 + e1);
            red[128 + (hh * 16 + lr) * 2 + 0] = e0 * inv;
            red[128 + (hh * 16 + lr) * 2 + 1] = e1 * inv;
        }
        __syncthreads();
        #pragma unroll
        for (int reg = 0; reg < 4; reg++) {
            int lr = q * 4 + reg;
            int row = m0 + lr;
            bool ok = row < M;
            int b = row & 3;
            int g = ok ? grp[row >> 2] : 0;
            float e0 = red[128 + (h * 16 + lr) * 2 + 0];
            float e1 = red[128 + (h * 16 + lr) * 2 + 1];
            const float* V0 = KV + (size_t)b * 512 + 256 + h * 128;
            const float* V1 = KV + ((size_t)(g + 1) * 4 + b) * 512 + 256 + h * 128;
            #pragma unroll
            for (int nt = 0; nt < 4; nt++) {
                int d = (w & 1) * 64 + nt * 16 + p;
                acc[nt][reg] = e0 * V0[d] + e1 * V1[d];
            }
        }
        __syncthreads();
    }

    // pass 3: cross-out + residual + LN -> x (tgt2)
    stage_acc16(acc, As, w, q, p);
    gemm_pass16(As, Wco, w, lane, acc);
    {
        float bi[4];
        #pragma unroll
        for (int nt = 0; nt < 4; nt++) bi[nt] = co_b[w * 64 + nt * 16 + p];
        #pragma unroll
        for (int nt = 0; nt < 4; nt++)
            #pragma unroll
            for (int reg = 0; reg < 4; reg++)
                acc[nt][reg] += bi[nt] + x[nt][reg];
    }
    block_ln16(acc, red, tid, w, q, p, ln1g, ln1b);
    #pragma unroll
    for (int nt = 0; nt < 4; nt++)
        #pragma unroll
        for (int reg = 0; reg < 4; reg++)
            x[nt][reg] = acc[nt][reg];

    // pass 4: ff1 + relu
    stage_acc16(acc, As, w, q, p);
    gemm_pass16(As, Wff1, w, lane, acc);
    {
        float bi[4];
        #pragma unroll
        for (int nt = 0; nt < 4; nt++) bi[nt] = ff1_b[w * 64 + nt * 16 + p];
        #pragma unroll
        for (int nt = 0; nt < 4; nt++)
            #pragma unroll
            for (int reg = 0; reg < 4; reg++)
                acc[nt][reg] = fmaxf(acc[nt][reg] + bi[nt], 0.f);
    }

    // pass 5: ff2 + residual + LN + final LN
    stage_acc16(acc, As, w, q, p);
    gemm_pass16(As, Wff2, w, lane, acc);
    {
        float bi[4];
        #pragma unroll
        for (int nt = 0; nt < 4; nt++) bi[nt] = ff2_b[w * 64 + nt * 16 + p];
        #pragma unroll
        for (int nt = 0; nt < 4; nt++)
            #pragma unroll
            for (int reg = 0; reg < 4; reg++)
                acc[nt][reg] += bi[nt] + x[nt][reg];
    }
    block_ln16(acc, red, tid, w, q, p, ln2g, ln2b);
    block_ln16(acc, red, tid, w, q, p, fng, fnb);

    // CE epilogue (9 classes: 5 + 4), one atomic per block
    #pragma unroll
    for (int c = 0; c < 9; c++) {
        const float* wc = (c < 5) ? (cw0 + (size_t)c * 256) : (cw1 + (size_t)(c - 5) * 256);
        float wv[4];
        #pragma unroll
        for (int nt = 0; nt < 4; nt++) wv[nt] = wc[w * 64 + nt * 16 + p];
        #pragma unroll
        for (int reg = 0; reg < 4; reg++) {
            float s = acc[0][reg] * wv[0] + acc[1][reg] * wv[1]
                    + acc[2][reg] * wv[2] + acc[3][reg] * wv[3];
            s = qred(s);
            if (p == 0) red[(c * 4 + w) * 16 + q * 4 + reg] = s;
        }
    }
    __syncthreads();
    if (tid < 16) {
        float local = 0.f;
        int grow = m0 + tid;
        if (grow < M) {
            int y0 = ydata[(size_t)grow * 2 + 0], y1 = ydata[(size_t)grow * 2 + 1];
            float lg[9];
            #pragma unroll
            for (int c = 0; c < 9; c++)
                lg[c] = red[(c * 4 + 0) * 16 + tid] + red[(c * 4 + 1) * 16 + tid]
                      + red[(c * 4 + 2) * 16 + tid] + red[(c * 4 + 3) * 16 + tid]
                      + ((c < 5) ? cb0[c] : cb1[c - 5]);
            float mA = -1e30f, mB = -1e30f, tA = 0.f, tB = 0.f;
            #pragma unroll
            for (int c = 0; c < 5; c++) { mA = fmaxf(mA, lg[c]); if (c == y0) tA = lg[c]; }
            #pragma unroll
            for (int c = 0; c < 4; c++) { mB = fmaxf(mB, lg[5 + c]); if (c == y1) tB = lg[5 + c]; }
            float sA = 0.f, sB = 0.f;
            #pragma unroll
            for (int c = 0; c < 5; c++) sA += __expf(lg[c] - mA);
            #pragma unroll
            for (int c = 0; c < 4; c++) sB += __expf(lg[5 + c] - mB);
            local = (mA + logf(sA) - tA) + (mB + logf(sB) - tB);
        }
        for (int o = 8; o; o >>= 1) local += __shfl_down(local, o);
        if (tid == 0) atomicAdd(lossOut, local * invM);
    }
}

// ---------------- fused QK^T + softmax -> bf16 P ----------------

__global__ __launch_bounds__(256) void k_attn_qks(
    const float* __restrict__ qkv, ushort* __restrict__ P)
{
    __shared__ ushort Qs[64 * 32];
    __shared__ ushort Ks[256 * 32];
    int tid = threadIdx.x;
    int wave = tid >> 6, lane = tid & 63;
    int q = lane >> 4, p = lane & 15;
    int m0 = blockIdx.x * 64;
    int z = blockIdx.y, b = z >> 1, h = z & 1;
    size_t qoff = (size_t)b * 768 + h * 128;

    f32x4 acc[16];
    #pragma unroll
    for (int i = 0; i < 16; i++) acc[i] = (f32x4){0.f, 0.f, 0.f, 0.f};

    int sra = tid >> 2, sca = (tid & 3) << 3;
    const float* Arow = qkv + (size_t)(m0 + sra) * 3072 + qoff + sca;
    const float* Wrow = qkv + (size_t)tid * 3072 + qoff + 256;
    ushort* asd = &Qs[sra * 32 + sca];
    ushort* wsd = &Ks[tid * 32];

    for (int k0 = 0; k0 < 128; k0 += 32) {
        float4 a0 = *(const float4*)(Arow + k0);
        float4 a1 = *(const float4*)(Arow + k0 + 4);
        float av[8] = {a0.x, a0.y, a0.z, a0.w, a1.x, a1.y, a1.z, a1.w};
        float wv[32];
        #pragma unroll
        for (int i = 0; i < 8; i++) {
            float4 w4 = *(const float4*)(Wrow + k0 + i * 4);
            wv[i*4+0] = w4.x; wv[i*4+1] = w4.y; wv[i*4+2] = w4.z; wv[i*4+3] = w4.w;
        }
        unsigned au[4], wu[16];
        #pragma unroll
        for (int i = 0; i < 4; i++) au[i] = (unsigned)f2b(av[2*i]) | ((unsigned)f2b(av[2*i+1]) << 16);
        #pragma unroll
        for (int i = 0; i < 16; i++) wu[i] = (unsigned)f2b(wv[2*i]) | ((unsigned)f2b(wv[2*i+1]) << 16);
        __syncthreads();
        ((uint4*)asd)[0] = make_uint4(au[0], au[1], au[2], au[3]);
        ((uint4*)wsd)[0] = make_uint4(wu[0], wu[1], wu[2], wu[3]);
        ((uint4*)(wsd + 8))[0] = make_uint4(wu[4], wu[5], wu[6], wu[7]);
        ((uint4*)(wsd + 16))[0] = make_uint4(wu[8], wu[9], wu[10], wu[11]);
        ((uint4*)(wsd + 24))[0] = make_uint4(wu[12], wu[13], wu[14], wu[15]);
        __syncthreads();

        bf16x8 af = *(const bf16x8*)&Qs[(wave * 16 + p) * 32 + q * 8];
        #pragma unroll
        for (int nt = 0; nt < 16; nt++) {
            bf16x8 bf = *(const bf16x8*)&Ks[(nt * 16 + p) * 32 + q * 8];
            acc[nt] = __builtin_amdgcn_mfma_f32_16x16x32_bf16(af, bf, acc[nt], 0, 0, 0);
        }
    }

    ushort* Pz = P + (size_t)z * 65536;
    #pragma unroll
    for (int reg = 0; reg < 4; reg++) {
        int row = m0 + wave * 16 + q * 4 + reg;
        float v[16]; float mx = -1e30f;
        #pragma unroll
        for (int nt = 0; nt < 16; nt++) {
            int colk = nt * 16 + p;
            float val = (colk <= row) ? acc[nt][reg] * SCALE : -1e30f;
            v[nt] = val; mx = fmaxf(mx, val);
        }
        mx = fmaxf(mx, __shfl_xor(mx, 1)); mx = fmaxf(mx, __shfl_xor(mx, 2));
        mx = fmaxf(mx, __shfl_xor(mx, 4)); mx = fmaxf(mx, __shfl_xor(mx, 8));
        float s = 0.f;
        #pragma unroll
        for (int nt = 0; nt < 16; nt++) {
            int colk = nt * 16 + p;
            float e = (colk <= row) ? __expf(v[nt] - mx) : 0.f;
            v[nt] = e; s += e;
        }
        s += __shfl_xor(s, 1); s += __shfl_xor(s, 2); s += __shfl_xor(s, 4); s += __shfl_xor(s, 8);
        float inv = 1.f / s;
        #pragma unroll
        for (int nt = 0; nt < 16; nt++)
            Pz[(size_t)row * 256 + nt * 16 + p] = f2b(v[nt] * inv);
    }
}

// ---------------- PV: O = P @ V ----------------

__global__ __launch_bounds__(256) void k_attn_pvt(
    const ushort* __restrict__ P, const float* __restrict__ Vt,
    float* __restrict__ out)
{
    __shared__ ushort As[64 * 32];
    __shared__ ushort Bs[128 * 32];
    int tid = threadIdx.x;
    int wave = tid >> 6, lane = tid & 63;
    int q = lane >> 4, p = lane & 15;
    int m0 = blockIdx.x * 64;
    int z = blockIdx.y, b = z >> 1, h = z & 1;

    f32x4 acc[8];
    #pragma unroll
    for (int i = 0; i < 8; i++) acc[i] = (f32x4){0.f, 0.f, 0.f, 0.f};

    int sra = tid >> 2, sca = (tid & 3) << 3;
    const ushort* Prow = P + (size_t)z * 65536 + (size_t)(m0 + sra) * 256 + sca;
    int srb = tid >> 1, scb = (tid & 1) << 4;
    const float* Vrow = Vt + (size_t)z * 32768 + (size_t)srb * 256 + scb;
    ushort* asd = &As[sra * 32 + sca];
    ushort* wsd = &Bs[srb * 32 + scb];

    for (int k0 = 0; k0 < 256; k0 += 32) {
        uint4 pa = *(const uint4*)(Prow + k0);
        float wv[16];
        #pragma unroll
        for (int i = 0; i < 4; i++) {
            float4 w4 = *(const float4*)(Vrow + k0 + i * 4);
            wv[i*4+0] = w4.x; wv[i*4+1] = w4.y; wv[i*4+2] = w4.z; wv[i*4+3] = w4.w;
        }
        unsigned wu[8];
        #pragma unroll
        for (int i = 0; i < 8; i++) wu[i] = (unsigned)f2b(wv[2*i]) | ((unsigned)f2b(wv[2*i+1]) << 16);
        __syncthreads();
        ((uint4*)asd)[0] = pa;
        ((uint4*)wsd)[0] = make_uint4(wu[0], wu[1], wu[2], wu[3]);
        ((uint4*)(wsd + 8))[0] = make_uint4(wu[4], wu[5], wu[6], wu[7]);
        __syncthreads();

        bf16x8 af = *(const bf16x8*)&As[(wave * 16 + p) * 32 + q * 8];
        #pragma unroll
        for (int nt = 0; nt < 8; nt++) {
            bf16x8 bf = *(const bf16x8*)&Bs[(nt * 16 + p) * 32 + q * 8];
            acc[nt] = __builtin_amdgcn_mfma_f32_16x16x32_bf16(af, bf, acc[nt], 0, 0, 0);
        }
    }

    #pragma unroll
    for (int reg = 0; reg < 4; reg++) {
        int s = m0 + wave * 16 + q * 4 + reg;
        #pragma unroll
        for (int nt = 0; nt < 8; nt++) {
            int dh = nt * 16 + p;
            out[(size_t)s * 1024 + (size_t)b * 256 + h * 128 + dh] = acc[nt][reg];
        }
    }
}

// ---------------- generic fp32 GEMM (input projection K=54 only) ----------------

__global__ __launch_bounds__(256) void k_gemm(
    const float* __restrict__ A, const float* __restrict__ W,
    const float* __restrict__ bias, float* __restrict__ C,
    int M, int N, int K, int relu)
{
    __shared__ __align__(16) float As[16][68];
    __shared__ __align__(16) float Ws[16][68];
    int tx = threadIdx.x, ty = threadIdx.y;
    int tid = ty * 16 + tx;
    int m0 = blockIdx.y * 64, n0 = blockIdx.x * 64;
    float acc[4][4] = {{0.f}};
    int r  = tid >> 2;
    int kk = (tid & 3) << 2;
    for (int k0 = 0; k0 < K; k0 += 16) {
        float4 av = make_float4(0.f, 0.f, 0.f, 0.f);
        float4 wv = make_float4(0.f, 0.f, 0.f, 0.f);
        int gm = m0 + r, gk = k0 + kk;
        if (gm < M) {
            float tv[4];
            for (int i = 0; i < 4; i++) tv[i] = (gk + i < K) ? A[(size_t)gm * K + gk + i] : 0.f;
            av = make_float4(tv[0], tv[1], tv[2], tv[3]);
        }
        int gn = n0 + r;
        if (gn < N) {
            float tv[4];
            for (int i = 0; i < 4; i++) tv[i] = (gk + i < K) ? W[(size_t)gn * K + gk + i] : 0.f;
            wv = make_float4(tv[0], tv[1], tv[2], tv[3]);
        }
        As[kk + 0][r] = av.x; As[kk + 1][r] = av.y; As[kk + 2][r] = av.z; As[kk + 3][r] = av.w;
        Ws[kk + 0][r] = wv.x; Ws[kk + 1][r] = wv.y; Ws[kk + 2][r] = wv.z; Ws[kk + 3][r] = wv.w;
        __syncthreads();
        #pragma unroll
        for (int k = 0; k < 16; k++) {
            float4 a4 = *(const float4*)&As[k][ty << 2];
            float4 b4 = *(const float4*)&Ws[k][tx << 2];
            float a[4] = {a4.x, a4.y, a4.z, a4.w};
            float b[4] = {b4.x, b4.y, b4.z, b4.w};
            #pragma unroll
            for (int i = 0; i < 4; i++)
                #pragma unroll
                for (int j = 0; j < 4; j++)
                    acc[i][j] = fmaf(a[i], b[j], acc[i][j]);
        }
        __syncthreads();
    }
    #pragma unroll
    for (int i = 0; i < 4; i++) {
        int gm = m0 + (ty << 2) + i;
        if (gm >= M) continue;
        #pragma unroll
        for (int j = 0; j < 4; j++) {
            int gn = n0 + (tx << 2) + j;
            if (gn >= N) continue;
            float v = acc[i][j] + bias[gn];
            if (relu) v = fmaxf(v, 0.f);
            C[(size_t)gm * N + gn] = v;
        }
    }
}

// ---------------- BatchNorm partial sums ----------------

__global__ __launch_bounds__(256) void k_bn_part(const float* __restrict__ x, float* __restrict__ sums) {
    int t = threadIdx.x;
    int r0 = blockIdx.x * 16;
    float s = 0.f, s2 = 0.f;
    for (int r = r0; r < r0 + 16; r++) {
        float v = x[(size_t)r * 256 + t];
        s += v; s2 += v * v;
    }
    atomicAdd(&sums[t], s);
    atomicAdd(&sums[256 + t], s2);
}

// ---------------- BN-finalize + SELU + positional encoding ----------------

__global__ __launch_bounds__(256) void k_bn_selu_pe(
    const float* __restrict__ x0, const float* __restrict__ sums,
    const float* __restrict__ g, const float* __restrict__ b,
    const int* __restrict__ atom_i, float* __restrict__ out)
{
    int row = blockIdx.x, t = threadIdx.x;
    float m = sums[t] * (1.f / 1024.f);
    float var = sums[256 + t] * (1.f / 1024.f) - m * m;
    float rstd = rsqrtf(var + 1e-5f);
    float v = x0[(size_t)row * 256 + t];
    v = (v - m) * rstd * g[t] + b[t];
    const float SC = 1.0507009873554805f, AL = 1.6732632423543772f;
    v = SC * (v > 0.f ? v : AL * expm1f(v));
    float pos = (float)atom_i[row];
    float freq = expf(-(float)t * (9.210340371976184f / 256.f));
    float ang = pos * freq;
    float pe = (t & 1) ? cosf(ang) : sinf(ang);
    out[(size_t)row * 256 + t] = v + pe;
}

// ---------------- both-layer node cross-attn constant ----------------

__global__ __launch_bounds__(256) void k_cross2(
    const float* __restrict__ z, const float* __restrict__ cqkv_w, const float* __restrict__ cqkv_b,
    const float* __restrict__ co_w, const float* __restrict__ co_b, float* __restrict__ crO)
{
    int m = blockIdx.x, l = blockIdx.y;
    int t = threadIdx.x;
    __shared__ float zs[256], ct[256];
    zs[t] = z[m * 256 + t];
    __syncthreads();
    const float* wv = cqkv_w + (size_t)l * 768 * 256 + 512 * 256 + (size_t)t * 256;
    float a = cqkv_b[l * 768 + 512 + t];
    for (int d = 0; d < 256; d += 4) {
        float4 w4 = *(const float4*)(wv + d);
        a += zs[d] * w4.x + zs[d+1] * w4.y + zs[d+2] * w4.z + zs[d+3] * w4.w;
    }
    ct[t] = a;
    __syncthreads();
    const float* ow = co_w + (size_t)l * 65536 + (size_t)t * 256;
    float o = co_b[l * 256 + t];
    for (int d = 0; d < 256; d += 4) {
        float4 w4 = *(const float4*)(ow + d);
        o += ct[d] * w4.x + ct[d+1] * w4.y + ct[d+2] * w4.z + ct[d+3] * w4.w;
    }
    crO[l * 1024 + m * 256 + t] = o;
}

// ---------------- edge group self-attention ----------------

__global__ __launch_bounds__(256) void k_edge_self_attn(
    const float* __restrict__ qkv, float* __restrict__ out)
{
    int g = blockIdx.x + 1;
    int b = blockIdx.y;
    int gs = min(g, 12);
    int base = (g <= 13) ? g * (g - 1) / 2 : 78 + (g - 13) * 12;
    int h = threadIdx.x >> 7;
    int t = threadIdx.x & 127;
    __shared__ float qs[2][12][128], ks[2][12][128], vs[2][12][128];
    __shared__ float ps[2][12][12];
    for (int i = 0; i < gs; i++) {
        size_t row = ((size_t)(base + i) * BB + b) * 768 + h * 128 + t;
        qs[h][i][t] = qkv[row];
        ks[h][i][t] = qkv[row + 256];
        vs[h][i][t] = qkv[row + 512];
    }
    __syncthreads();
    for (int p = t; p < gs * gs; p += 128) {
        int i = p / gs, j = p - i * gs;
        float acc = 0.f;
        for (int d = 0; d < 128; d++) acc = fmaf(qs[h][i][d], ks[h][j][d], acc);
        ps[h][i][j] = acc * SCALE;
    }
    __syncthreads();
    if (t < gs) {
        float m = -1e30f;
        for (int j = 0; j < gs; j++) m = fmaxf(m, ps[h][t][j]);
        float e[12]; float s = 0.f;
        for (int j = 0; j < gs; j++) { e[j] = expf(ps[h][t][j] - m); s += e[j]; }
        float inv = 1.f / s;
        for (int j = 0; j < gs; j++) ps[h][t][j] = e[j] * inv;
    }
    __syncthreads();
    for (int i = 0; i < gs; i++) {
        float acc = 0.f;
        for (int j = 0; j < gs; j++) acc = fmaf(ps[h][i][j], vs[h][j][t], acc);
        out[((size_t)(base + i) * BB + b) * 256 + h * 128 + t] = acc;
    }
}

// ---------------- gather + build_mem fused ----------------

__global__ __launch_bounds__(256) void k_gather_mem(
    const float* __restrict__ z, const float* __restrict__ nemb,
    const int* __restrict__ idxt, float* __restrict__ etgt, float* __restrict__ memb)
{
    int r = blockIdx.x, t = threadIdx.x;
    if (r < LEB) {
        int e = r >> 2, b = r & 3;
        etgt[(size_t)r * 256 + t] = nemb[((size_t)idxt[e] * 4 + b) * 256 + t];
    } else {
        int rm = r - LEB;
        int m = rm >> 2, b = rm & 3;
        memb[(size_t)rm * 256 + t] = (m == 0) ? z[(size_t)b * 256 + t]
                                              : nemb[((size_t)(m - 1) * 4 + b) * 256 + t];
    }
}

// ---------------- fused node cross-entropy (no dynamic-indexed arrays) ----------------

__global__ __launch_bounds__(256) void k_ce_node(
    const float* __restrict__ emb,
    const float* __restrict__ w0, const float* __restrict__ b0,
    const float* __restrict__ w1, const float* __restrict__ b1,
    const float* __restrict__ w2, const float* __restrict__ b2,
    const int* __restrict__ y, int M, float invM, float* __restrict__ lossOut)
{
    int wave = threadIdx.x >> 6, lane = threadIdx.x & 63;
    int wid = blockIdx.x * 4 + wave;
    float local = 0.f;
    for (int r = wid; r < M; r += gridDim.x * 4) {
        float4 x = ((const float4*)(emb + (size_t)r * 256))[lane];
        float acc[54];
        #pragma unroll
        for (int c = 0; c < 40; c++) {
            float4 wv = ((const float4*)(w0 + (size_t)c * 256))[lane];
            acc[c] = x.x * wv.x + x.y * wv.y + x.z * wv.z + x.w * wv.w;
        }
        #pragma unroll
        for (int c = 0; c < 8; c++) {
            float4 wv = ((const float4*)(w1 + (size_t)c * 256))[lane];
            acc[40 + c] = x.x * wv.x + x.y * wv.y + x.z * wv.z + x.w * wv.w;
        }
        #pragma unroll
        for (int c = 0; c < 6; c++) {
            float4 wv = ((const float4*)(w2 + (size_t)c * 256))[lane];
            acc[48 + c] = x.x * wv.x + x.y * wv.y + x.z * wv.z + x.w * wv.w;
        }
        #pragma unroll
        for (int c = 0; c < 54; c++)
            for (int o = 32; o; o >>= 1) acc[c] += __shfl_down(acc[c], o);
        if (lane == 0) {
            int y0 = y[(size_t)r * 3 + 0], y1 = y[(size_t)r * 3 + 1], y2 = y[(size_t)r * 3 + 2];
            float m0v = -1e30f, m1v = -1e30f, m2v = -1e30f;
            float t0 = 0.f, t1v = 0.f, t2v = 0.f;
            #pragma unroll
            for (int c = 0; c < 40; c++) {
                float v = acc[c] + b0[c];
                acc[c] = v; m0v = fmaxf(m0v, v);
                if (c == y0) t0 = v;
            }
            #pragma unroll
            for (int c = 0; c < 8; c++) {
                float v = acc[40 + c] + b1[c];
                acc[40 + c] = v; m1v = fmaxf(m1v, v);
                if (c == y1) t1v = v;
            }
            #pragma unroll
            for (int c = 0; c < 6; c++) {
                float v = acc[48 + c] + b2[c];
                acc[48 + c] = v; m2v = fmaxf(m2v, v);
                if (c == y2) t2v = v;
            }
            float s0 = 0.f, s1 = 0.f, s2 = 0.f;
            #pragma unroll
            for (int c = 0; c < 40; c++) s0 += __expf(acc[c] - m0v);
            #pragma unroll
            for (int c = 0; c < 8; c++)  s1 += __expf(acc[40 + c] - m1v);
            #pragma unroll
            for (int c = 0; c < 6; c++)  s2 += __expf(acc[48 + c] - m2v);
            local += (m0v + logf(s0) - t0) + (m1v + logf(s1) - t1v) + (m2v + logf(s2) - t2v);
        }
    }
    __shared__ float ls[4];
    if (lane == 0) ls[wave] = local;
    __syncthreads();
    if (threadIdx.x == 0)
        atomicAdd(lossOut, (ls[0] + ls[1] + ls[2] + ls[3]) * invM);
}

// ---------------- host ----------------

extern "C" void kernel_launch(void* const* d_in, const int* in_sizes, int n_in,
                              void* d_out, int out_size, void* d_ws, size_t ws_size,
                              hipStream_t stream)
{
    (void)in_sizes; (void)n_in; (void)out_size; (void)ws_size;
    const float* zin      = (const float*)d_in[0];
    const int*   atom_i   = (const int*)d_in[1];
    const float* atom_x   = (const float*)d_in[2];
    const int*   atom_y   = (const int*)d_in[3];
    const int*   bond_y   = (const int*)d_in[4];
    const float* Wp       = (const float*)d_in[5];
    const float* bp       = (const float*)d_in[6];
    const float* bn_g     = (const float*)d_in[7];
    const float* bn_b     = (const float*)d_in[8];
    const float* nd_qkv_w = (const float*)d_in[9];
    const float* nd_qkv_b = (const float*)d_in[10];
    const float* nd_so_w  = (const float*)d_in[11];
    const float* nd_so_b  = (const float*)d_in[12];
    const float* nd_cqkv_w= (const float*)d_in[13];
    const float* nd_cqkv_b= (const float*)d_in[14];
    const float* nd_co_w  = (const float*)d_in[15];
    const float* nd_co_b  = (const float*)d_in[16];
    const float* nd_ff1_w = (const float*)d_in[17];
    const float* nd_ff1_b = (const float*)d_in[18];
    const float* nd_ff2_w = (const float*)d_in[19];
    const float* nd_ff2_b = (const float*)d_in[20];
    const float* nd_ln_g  = (const float*)d_in[21];
    const float* nd_ln_b  = (const float*)d_in[22];
    const float* nd_fn_g  = (const float*)d_in[23];
    const float* nd_fn_b  = (const float*)d_in[24];
    const float* ed_qkv_w = (const float*)d_in[25];
    const float* ed_qkv_b = (const float*)d_in[26];
    const float* ed_so_w  = (const float*)d_in[27];
    const float* ed_so_b  = (const float*)d_in[28];
    const float* ed_cqkv_w= (const float*)d_in[29];
    const float* ed_cqkv_b= (const float*)d_in[30];
    const float* ed_co_w  = (const float*)d_in[31];
    const float* ed_co_b  = (const float*)d_in[32];
    const float* ed_ff1_w = (const float*)d_in[33];
    const float* ed_ff1_b = (const float*)d_in[34];
    const float* ed_ff2_w = (const float*)d_in[35];
    const float* ed_ff2_b = (const float*)d_in[36];
    const float* ed_ln_g  = (const float*)d_in[37];
    const float* ed_ln_b  = (const float*)d_in[38];
    const float* ed_fn_g  = (const float*)d_in[39];
    const float* ed_fn_b  = (const float*)d_in[40];
    const float* nc0_w = (const float*)d_in[41]; const float* nc0_b = (const float*)d_in[42];
    const float* nc1_w = (const float*)d_in[43]; const float* nc1_b = (const float*)d_in[44];
    const float* nc2_w = (const float*)d_in[45]; const float* nc2_b = (const float*)d_in[46];
    const float* ec0_w = (const float*)d_in[47]; const float* ec0_b = (const float*)d_in[48];
    const float* ec1_w = (const float*)d_in[49]; const float* ec1_b = (const float*)d_in[50];

    float* out = (float*)d_out;

    char* wsb = (char*)d_ws;
    size_t off = 0;
    auto alloc = [&](size_t nbytes) -> void* {
        void* p = (void*)(wsb + off);
        off += (nbytes + 255) / 256 * 256;
        return p;
    };
    float* x0    = (float*)alloc(1024 * 256 * 4);
    float* tgt   = (float*)alloc(1024 * 256 * 4);
    float* nqkv  = (float*)alloc(1024 * 768 * 4);
    float* t1    = (float*)alloc(1024 * 256 * 4);
    float* nemb  = (float*)alloc(1024 * 256 * 4);
    float* bnsums= (float*)alloc(512 * 4);
    float* crO   = (float*)alloc(2 * 1024 * 4);
    float* memb  = (float*)alloc(1028 * 256 * 4);
    float* KV    = (float*)alloc(1028 * 512 * 4);
    ushort* Sb   = (ushort*)alloc(8 * 65536 * 2);
    float* Vt    = (float*)alloc(8 * 32768 * 4);
    float* etgt  = (float*)alloc((size_t)LEB * 256 * 4);
    float* eqkv  = (float*)alloc((size_t)LEB * 768 * 4);
    float* et1   = (float*)alloc((size_t)LEB * 256 * 4);
    int* grp   = (int*)alloc(LE * 4);
    int* idxt  = (int*)alloc(LE * 4);
    ushort* wpk = (ushort*)alloc((size_t)TOTFRAG * 512 * 2);

    PackArgs pa;
    pa.src[0] = nd_qkv_w;              pa.src[1] = nd_qkv_w + 768 * 256;
    pa.src[2] = nd_so_w;               pa.src[3] = nd_so_w + 65536;
    pa.src[4] = nd_ff1_w;              pa.src[5] = nd_ff1_w + 65536;
    pa.src[6] = nd_ff2_w;              pa.src[7] = nd_ff2_w + 65536;
    pa.src[8] = ed_qkv_w;              pa.src[9] = ed_cqkv_w;
    pa.src[10] = ed_so_w;              pa.src[11] = ed_co_w;
    pa.src[12] = ed_ff1_w;             pa.src[13] = ed_ff2_w;
    int fs[NPACK + 1] = {0, 384, 768, 896, 1024, 1152, 1280, 1408, 1536, 1920, 2304, 2432, 2560, 2688, 2816};
    for (int i = 0; i <= NPACK; i++) pa.fs[i] = fs[i];
    auto wp = [&](int i) -> const ushort* { return wpk + (size_t)fs[i] * 512; };

    k_init<<<13, 256, 0, stream>>>(out, bnsums, grp, idxt);
    k_prep<<<(TOTFRAG * 64 + 255) / 256, 256, 0, stream>>>(pa, wpk);

    // node input: projection + BN + SELU + PE
    k_gemm<<<dim3(4, 16), dim3(16, 16), 0, stream>>>(atom_x, Wp, bp, x0, 1024, 256, 54, 0);
    k_bn_part<<<64, 256, 0, stream>>>(x0, bnsums);
    k_bn_selu_pe<<<1024, 256, 0, stream>>>(x0, bnsums, bn_g, bn_b, atom_i, tgt);

    // both layers' cross-attn constant
    k_cross2<<<dim3(4, 2), 256, 0, stream>>>(zin, nd_cqkv_w, nd_cqkv_b, nd_co_w, nd_co_b, crO);

    // node decoder: 2 layers (4 dispatches each)
    for (int l = 0; l < 2; l++) {
        k_gemm_w<<<dim3(3, 8), 256, 0, stream>>>(tgt, wp(l), nd_qkv_b + l * 768,
                                                 nqkv, Vt, 1024, 768, 3, 0);
        k_attn_qks<<<dim3(4, 8), 256, 0, stream>>>(nqkv, Sb);
        k_attn_pvt<<<dim3(4, 8), 256, 0, stream>>>(Sb, Vt, t1);
        k_node_mega<<<64, 256, 0, stream>>>(
            t1, tgt, crO + l * 1024,
            wp(2 + l), nd_so_b + l * 256,
            nd_ln_g + (l * 3 + 0) * 256, nd_ln_b + (l * 3 + 0) * 256,
            nd_ln_g + (l * 3 + 1) * 256, nd_ln_b + (l * 3 + 1) * 256,
            wp(4 + l), nd_ff1_b + l * 256,
            wp(6 + l), nd_ff2_b + l * 256,
            nd_ln_g + (l * 3 + 2) * 256, nd_ln_b + (l * 3 + 2) * 256,
            nd_fn_g, nd_fn_b,
            (l == 0) ? tgt : nemb, 1024, (l == 1) ? 1 : 0);
    }

    // node losses
    k_ce_node<<<128, 256, 0, stream>>>(nemb, nc0_w, nc0_b, nc1_w, nc1_b, nc2_w, nc2_b,
                                       atom_y, 1024, 1.f / 1024.f, out);

    // edge path
    k_gather_mem<<<LEB + 1028, 256, 0, stream>>>(zin, nemb, idxt, etgt, memb);
    k_gemm_w<<<dim3(2, 17), 256, 0, stream>>>(memb, wp(9) + 128 * 512, ed_cqkv_b + 256,
                                              KV, nullptr, 1028, 512, 0, 0);
    k_gemm_w<<<dim3(3, 188), 256, 0, stream>>>(etgt, wp(8), ed_qkv_b,
                                               eqkv, nullptr, LEB, 768, 0, 0);
    k_edge_self_attn<<<dim3(255, 4), 256, 0, stream>>>(eqkv, et1);
    k_edge_mega<<<(LEB + 15) / 16, 256, 0, stream>>>(
        et1, etgt,
        wp(10), ed_so_b, ed_ln_g, ed_ln_b,
        wp(9), ed_cqkv_b, KV, grp,
        wp(11), ed_co_b, ed_ln_g + 256, ed_ln_b + 256,
        wp(12), ed_ff1_b,
        wp(13), ed_ff2_b, ed_ln_g + 512, ed_ln_b + 512,
        ed_fn_g, ed_fn_b,
        bond_y, ec0_w, ec0_b, ec1_w, ec1_b,
        out, 1.f / (float)LEB, LEB);
}